// Round 6
// baseline (1560.351 us; speedup 1.0000x reference)
//
#include <hip/hip_runtime.h>
#include <math.h>

#define NN 10000
#define EE 320000
#define TILE 32
#define NB ((EE + 7 * NN + TILE - 1) / TILE)   // 12188 blocks, 390016 padded slots

constexpr float INVS32  = 0.17677669529663687f;   // 1/sqrt(32)
constexpr float INVS160 = 0.07905694150420949f;   // 1/sqrt(160)
constexpr float INVS96  = 0.10206207261596575f;   // 1/sqrt(96)
constexpr float INVS3   = 0.5773502691896258f;    // 1/sqrt(3)
constexpr float INVS2   = 0.7071067811865476f;    // 1/sqrt(2)
constexpr float LN2     = 0.6931471805599453f;

typedef short bf16x8 __attribute__((ext_vector_type(8)));
typedef float f32x4  __attribute__((ext_vector_type(4)));
typedef float f32x8  __attribute__((ext_vector_type(8)));

__device__ __forceinline__ float sspf(float v) {
  return fmaxf(v, 0.f) + log1pf(expf(-fabsf(v))) - LN2;
}
__device__ __forceinline__ ushort f2bf(float f) {
  union { float f; unsigned u; } v; v.f = f;
  unsigned r = v.u + 0x7FFF + ((v.u >> 16) & 1);   // RNE
  return (ushort)(r >> 16);
}
__device__ __forceinline__ unsigned pk(float a, float b) {
  return (unsigned)f2bf(a) | ((unsigned)f2bf(b) << 16);
}
// unpack 8 bf16 (16B aligned) -> f32x8 (register vector, static indices only)
__device__ __forceinline__ f32x8 cvt8v(const ushort* p) {
  uint4 u = *(const uint4*)p;
  f32x8 f;
  f[0] = __uint_as_float(u.x << 16); f[1] = __uint_as_float(u.x & 0xFFFF0000u);
  f[2] = __uint_as_float(u.y << 16); f[3] = __uint_as_float(u.y & 0xFFFF0000u);
  f[4] = __uint_as_float(u.z << 16); f[5] = __uint_as_float(u.z & 0xFFFF0000u);
  f[6] = __uint_as_float(u.w << 16); f[7] = __uint_as_float(u.w & 0xFFFF0000u);
  return f;
}

// ---------------- sort-by-dst kernels (runs padded to multiples of 8) ----------------
__global__ void hist_k(const int* __restrict__ ei, int* __restrict__ cnt) {
  int e = blockIdx.x * 256 + threadIdx.x;
  if (e < EE) atomicAdd(&cnt[ei[e]], 1);
}

__global__ __launch_bounds__(1024) void scan_k(const int* __restrict__ cnt,
                                               int* __restrict__ cursor) {
  __shared__ int s[1024];
  const int t = threadIdx.x;
  int loc[10];
  int sum = 0;
#pragma unroll
  for (int jj = 0; jj < 10; ++jj) {
    int idx = t * 10 + jj;
    int c = (idx < NN) ? ((cnt[idx] + 7) & ~7) : 0;   // 8-padded run length
    loc[jj] = sum;
    sum += c;
  }
  s[t] = sum;
  __syncthreads();
  for (int d = 1; d < 1024; d <<= 1) {
    int v = (t >= d) ? s[t - d] : 0;
    __syncthreads();
    s[t] += v;
    __syncthreads();
  }
  const int excl = (t > 0) ? s[t - 1] : 0;
#pragma unroll
  for (int jj = 0; jj < 10; ++jj) {
    int idx = t * 10 + jj;
    if (idx < NN) cursor[idx] = excl + loc[jj];
  }
}

__global__ void scat_k(const int* __restrict__ ei, int* __restrict__ cursor,
                       int* __restrict__ order8) {
  int e = blockIdx.x * 256 + threadIdx.x;
  if (e < EE) {
    int p = atomicAdd(&cursor[ei[e]], 1);
    order8[p] = e;
  }
}

// ---------------- weight transforms: F2T/L2T bf16 (scale folded), WO*T f32 ----------------
__global__ void prep_t_k(const float* __restrict__ F2, const float* __restrict__ L2,
                         const float* __restrict__ WO0, const float* __restrict__ WO1,
                         const float* __restrict__ WO2,
                         ushort* __restrict__ F2Tb, ushort* __restrict__ L2Tb,
                         float* __restrict__ WO0T, float* __restrict__ WO1T,
                         float* __restrict__ WO2T) {
  int i = blockIdx.x * 256 + threadIdx.x;
  if (i < 7168) {                         // F2T/L2T: [c][k] bf16
    int c = i >> 5, k = i & 31;
    float sc = (c < 64)  ? (1.f / 32.f)
             : (c < 128) ? (INVS3 / 32.f)
             : (c < 160) ? (1.f / 32.f)
             : (c < 192) ? (INVS3 / 32.f)
                         : (INVS2 / 32.f);
    F2Tb[i] = f2bf(F2[k * 224 + c] * sc);
    L2Tb[i] = f2bf(L2[k * 224 + c]);
  } else if (i < 7168 + 12288) {          // WO0T [128][96], scale folded
    int j = i - 7168; int k = j / 96, u = j - k * 96;
    WO0T[j] = WO0[u * 128 + k] * INVS96;
  } else if (i < 7168 + 12288 + 6144) {   // WO1T [64][96]
    int j = i - 7168 - 12288; int v = j / 96, u = j - v * 96;
    WO1T[j] = WO1[u * 64 + v] * INVS96;
  } else if (i < 7168 + 12288 + 6144 + 1024) {  // WO2T [32][32]
    int j = i - 7168 - 12288 - 6144; int v = j >> 5, u = j & 31;
    WO2T[j] = WO2[u * 32 + v] * INVS32;
  }
}

// ---------------- node-level precompute (4-partial ILP dots) ----------------
__global__ __launch_bounds__(256) void node_prep_k(
    const float* __restrict__ x,
    const float* __restrict__ W0p, const float* __restrict__ b0p,
    const float* __restrict__ W1p,
    const float* __restrict__ W0n, const float* __restrict__ b0n,
    const float* __restrict__ W1n,
    const float* __restrict__ G1, const float* __restrict__ g1b,
    const float* __restrict__ G2, const float* __restrict__ g2b,
    const float* __restrict__ L1,
    float* __restrict__ p1w, float* __restrict__ x0nw, float* __restrict__ x1nw,
    float* __restrict__ Aw, float* __restrict__ Bw)
{
  const int wv   = threadIdx.x >> 6;
  const int lane = threadIdx.x & 63;
  const int n    = blockIdx.x * 4 + wv;
  const bool nv  = (n < NN);

  __shared__ float sX[4][160];
  __shared__ float sP0[4][64];
  __shared__ float sF0[4][96];
  __shared__ float sH1[4][96];
  __shared__ float sG[4][96];

  if (nv) {
    sX[wv][lane]      = x[n * 160 + lane];
    sX[wv][lane + 64] = x[n * 160 + lane + 64];
    if (lane < 32) sX[wv][lane + 128] = x[n * 160 + lane + 128];
  }
  __syncthreads();

  if (nv) {
    {
      float d0 = 0.f, d1 = 0.f, d2 = 0.f, d3 = 0.f;
      for (int i = 0; i < 64; i += 4) {
        d0 = fmaf(sX[wv][i],     W0p[i * 64 + lane],       d0);
        d1 = fmaf(sX[wv][i + 1], W0p[(i + 1) * 64 + lane], d1);
        d2 = fmaf(sX[wv][i + 2], W0p[(i + 2) * 64 + lane], d2);
        d3 = fmaf(sX[wv][i + 3], W0p[(i + 3) * 64 + lane], d3);
      }
      sP0[wv][lane] = ((d0 + d1) + (d2 + d3)) * 0.125f + b0p[lane];
      sF0[wv][lane] = sX[wv][lane];
    }
    for (int o = lane; o < 96; o += 64) {
      const int v = o / 3, i_ = o % 3;
      float d0 = 0.f, d1 = 0.f;
      for (int u = 0; u < 32; u += 2) {
        d0 = fmaf(sX[wv][64 + u * 3 + i_],       W1p[u * 32 + v],       d0);
        d1 = fmaf(sX[wv][64 + (u + 1) * 3 + i_], W1p[(u + 1) * 32 + v], d1);
      }
      p1w[n * 96 + o] = (d0 + d1) * INVS32;
    }
    if (lane < 32) {
      float s2 = 1e-12f;
#pragma unroll
      for (int i = 0; i < 3; ++i) { float t = sX[wv][64 + lane * 3 + i]; s2 += t * t; }
      sF0[wv][64 + lane] = sqrtf(s2);
    }
  }
  __syncthreads();

  if (nv) for (int o = lane; o < 96; o += 64) {
    float d0 = g1b[o], d1 = 0.f, d2 = 0.f, d3 = 0.f;
    for (int i = 0; i < 96; i += 4) {
      d0 = fmaf(sF0[wv][i],     G1[i * 96 + o],       d0);
      d1 = fmaf(sF0[wv][i + 1], G1[(i + 1) * 96 + o], d1);
      d2 = fmaf(sF0[wv][i + 2], G1[(i + 2) * 96 + o], d2);
      d3 = fmaf(sF0[wv][i + 3], G1[(i + 3) * 96 + o], d3);
    }
    float d = (d0 + d1) + (d2 + d3);
    sH1[wv][o] = d / (1.f + expf(-d));
  }
  __syncthreads();

  if (nv) for (int o = lane; o < 96; o += 64) {
    float d0 = g2b[o], d1 = 0.f, d2 = 0.f, d3 = 0.f;
    for (int i = 0; i < 96; i += 4) {
      d0 = fmaf(sH1[wv][i],     G2[i * 96 + o],       d0);
      d1 = fmaf(sH1[wv][i + 1], G2[(i + 1) * 96 + o], d1);
      d2 = fmaf(sH1[wv][i + 2], G2[(i + 2) * 96 + o], d2);
      d3 = fmaf(sH1[wv][i + 3], G2[(i + 3) * 96 + o], d3);
    }
    sG[wv][o] = (d0 + d1) + (d2 + d3);
  }
  __syncthreads();

  if (nv) {
    {
      float d0 = 0.f, d1 = 0.f, d2 = 0.f, d3 = 0.f;
      for (int i = 0; i < 64; i += 4) {
        d0 = fmaf(sG[wv][i],     W0n[i * 64 + lane],       d0);
        d1 = fmaf(sG[wv][i + 1], W0n[(i + 1) * 64 + lane], d1);
        d2 = fmaf(sG[wv][i + 2], W0n[(i + 2) * 64 + lane], d2);
        d3 = fmaf(sG[wv][i + 3], W0n[(i + 3) * 64 + lane], d3);
      }
      x0nw[n * 64 + lane] = ((d0 + d1) + (d2 + d3)) * 0.125f + b0n[lane];
    }
    for (int o = lane; o < 96; o += 64) {
      const int v = o / 3, i_ = o % 3;
      float d0 = 0.f, d1 = 0.f;
      for (int u = 0; u < 32; u += 2) {
        d0 = fmaf(sX[wv][64 + u * 3 + i_] * sG[wv][64 + u],
                  W1n[u * 32 + v], d0);
        d1 = fmaf(sX[wv][64 + (u + 1) * 3 + i_] * sG[wv][64 + u + 1],
                  W1n[(u + 1) * 32 + v], d1);
      }
      x1nw[n * 96 + o] = (d0 + d1) * INVS32;
    }
    if (lane < 32) {
      float a0 = 0.f, a1 = 0.f, b0 = 0.f, b1 = 0.f;
      for (int i = 0; i < 64; i += 2) {
        a0 = fmaf(sP0[wv][i],     L1[i * 32 + lane],         a0);
        a1 = fmaf(sP0[wv][i + 1], L1[(i + 1) * 32 + lane],   a1);
        b0 = fmaf(sP0[wv][i],     L1[(64 + i) * 32 + lane],  b0);
        b1 = fmaf(sP0[wv][i + 1], L1[(65 + i) * 32 + lane],  b1);
      }
      Aw[n * 32 + lane] = (a0 + a1) * INVS160;
      Bw[n * 32 + lane] = (b0 + b1) * INVS160;
    }
  }
}

// ---- decode channel k -> mode + LDS element offsets (scalars only) ----
// xT rows: 0..63 = x0 channels, 64..159 = x1 flat (3u+i). Row stride 40 ushorts.
__device__ __forceinline__ void decode_ch(int k, int& mode, int& wo,
                                          int& xaO, int& xbO, int& saO, int& sbO) {
  xbO = 0; sbO = 0;
  if (k < 64) {
    mode = 0; wo = k * 36; xaO = k * 40; saO = 0;
  } else if (k < 96) {
    const int c = k - 64;
    mode = 1; wo = (160 + c) * 36; xaO = (64 + 3 * c) * 40; saO = 40;
  } else if (k < 288) {
    const int kk = k - 96; const int u = kk / 3; const int i = kk - 3 * u;
    mode = 0; wo = (64 + u) * 36; xaO = u * 40; saO = (1 + i) * 40;
  } else if (k < 384) {
    const int kk = k - 288; const int u = kk / 3; const int i = kk - 3 * u;
    mode = 0; wo = (128 + u) * 36; xaO = (64 + 3 * u + i) * 40; saO = 0;
  } else {
    const int kk = k - 384; const int u = kk / 3; const int i = kk - 3 * u;
    const int i1 = (i + 1) % 3, i2 = (i + 2) % 3;
    mode = 2; wo = (192 + u) * 36;
    xaO = (64 + 3 * u + i1) * 40; xbO = (64 + 3 * u + i2) * 40;
    saO = (1 + i2) * 40;          sbO = (1 + i1) * 40;
  }
}

__device__ __forceinline__ float acc8(int mode, const float* wRow,
                                      const ushort* xT, int xaO, int xbO,
                                      const ushort* shT, int saO, int sbO,
                                      int q0, float a) {
  f32x4 wA = *(const f32x4*)(wRow + q0);
  f32x4 wB = *(const f32x4*)(wRow + q0 + 4);
  if (mode == 0) {
    f32x8 xv = cvt8v(xT + xaO + q0);
    f32x8 sv = cvt8v(shT + saO + q0);
    a = fmaf(wA[0] * xv[0], sv[0], a); a = fmaf(wA[1] * xv[1], sv[1], a);
    a = fmaf(wA[2] * xv[2], sv[2], a); a = fmaf(wA[3] * xv[3], sv[3], a);
    a = fmaf(wB[0] * xv[4], sv[4], a); a = fmaf(wB[1] * xv[5], sv[5], a);
    a = fmaf(wB[2] * xv[6], sv[6], a); a = fmaf(wB[3] * xv[7], sv[7], a);
  } else if (mode == 1) {
    f32x8 x0 = cvt8v(xT + xaO + q0);
    f32x8 x1 = cvt8v(xT + xaO + 40 + q0);
    f32x8 x2 = cvt8v(xT + xaO + 80 + q0);
    f32x8 s1 = cvt8v(shT + saO + q0);
    f32x8 s2 = cvt8v(shT + saO + 40 + q0);
    f32x8 s3 = cvt8v(shT + saO + 80 + q0);
    float d0 = fmaf(x2[0], s3[0], fmaf(x1[0], s2[0], x0[0] * s1[0]));
    float d1 = fmaf(x2[1], s3[1], fmaf(x1[1], s2[1], x0[1] * s1[1]));
    float d2 = fmaf(x2[2], s3[2], fmaf(x1[2], s2[2], x0[2] * s1[2]));
    float d3 = fmaf(x2[3], s3[3], fmaf(x1[3], s2[3], x0[3] * s1[3]));
    float d4 = fmaf(x2[4], s3[4], fmaf(x1[4], s2[4], x0[4] * s1[4]));
    float d5 = fmaf(x2[5], s3[5], fmaf(x1[5], s2[5], x0[5] * s1[5]));
    float d6 = fmaf(x2[6], s3[6], fmaf(x1[6], s2[6], x0[6] * s1[6]));
    float d7 = fmaf(x2[7], s3[7], fmaf(x1[7], s2[7], x0[7] * s1[7]));
    a = fmaf(wA[0], d0, a); a = fmaf(wA[1], d1, a);
    a = fmaf(wA[2], d2, a); a = fmaf(wA[3], d3, a);
    a = fmaf(wB[0], d4, a); a = fmaf(wB[1], d5, a);
    a = fmaf(wB[2], d6, a); a = fmaf(wB[3], d7, a);
  } else {
    f32x8 xa = cvt8v(xT + xaO + q0);
    f32x8 xb = cvt8v(xT + xbO + q0);
    f32x8 sa = cvt8v(shT + saO + q0);
    f32x8 sb = cvt8v(shT + sbO + q0);
    float c0 = fmaf(xa[0], sa[0], -(xb[0] * sb[0]));
    float c1 = fmaf(xa[1], sa[1], -(xb[1] * sb[1]));
    float c2 = fmaf(xa[2], sa[2], -(xb[2] * sb[2]));
    float c3 = fmaf(xa[3], sa[3], -(xb[3] * sb[3]));
    float c4 = fmaf(xa[4], sa[4], -(xb[4] * sb[4]));
    float c5 = fmaf(xa[5], sa[5], -(xb[5] * sb[5]));
    float c6 = fmaf(xa[6], sa[6], -(xb[6] * sb[6]));
    float c7 = fmaf(xa[7], sa[7], -(xb[7] * sb[7]));
    a = fmaf(wA[0], c0, a); a = fmaf(wA[1], c1, a);
    a = fmaf(wA[2], c2, a); a = fmaf(wA[3], c3, a);
    a = fmaf(wB[0], c4, a); a = fmaf(wB[1], c5, a);
    a = fmaf(wB[2], c6, a); a = fmaf(wB[3], c7, a);
  }
  return a;
}

// ---------------- fused per-edge MLP (MFMA) + transposed scatter ----------------
__global__ __launch_bounds__(256, 3) void fused_edge_k(
    const float* __restrict__ edge_attr,
    const float* __restrict__ edge_sh,
    const int* __restrict__ ei,
    const float* __restrict__ F1, const float* __restrict__ L1,
    const ushort* __restrict__ F2Tb, const ushort* __restrict__ L2Tb,
    const float* __restrict__ p1w, const float* __restrict__ Aw,
    const float* __restrict__ Bw,
    const float* __restrict__ x0nw, const float* __restrict__ x1nw,
    const int* __restrict__ order8,
    float* __restrict__ o480)
{
  const int s0  = blockIdx.x * TILE;
  const int tid = threadIdx.x;

  if (order8[s0] < 0) return;   // wholly-padded block

  // sWT: f32 [224][36] (channel-major, rows 144B)
  __shared__ __align__(16) float sWT[224 * 36];                  // 32256 B
  float (*sEA)[36] = (float (*)[36])sWT;                         // union (dead after B)
  float (*sIP)[36] = (float (*)[36])(sWT + 32 * 36);
  __shared__ ushort sXT[160 * 40];   // bf16 channel-major: rows 0..63 x0, 64..159 x1
  __shared__ ushort sSHT[4 * 40];
  __shared__ ushort sHF[32 * 40];    // bf16 [edge][32+pad]
  __shared__ ushort sHL[32 * 40];
  __shared__ int    sDst[32];

  const int g = tid >> 3, l = tid & 7;   // 8 threads per edge slot
  const int eo  = order8[s0 + g];
  const bool valid = (eo >= 0);
  const int e   = valid ? eo : 0;
  const int dst = ei[e];
  const int src = ei[EE + e];
  if (l == 0) sDst[g] = valid ? dst : -1;

  // ---- phase A: stage (transposed bf16 for xs/sh; f32 for ea/ip) ----
  *(float4*)&sEA[g][l * 4] = *(const float4*)(edge_attr + (size_t)e * 32 + l * 4);
  if (l < 4) sSHT[l * 40 + g] = f2bf(edge_sh[(size_t)e * 4 + l]);
#pragma unroll
  for (int j = 0; j < 8; ++j)
    sXT[(l + 8 * j) * 40 + g] = f2bf(x0nw[(size_t)src * 64 + l + 8 * j]);
#pragma unroll
  for (int j = 0; j < 12; ++j)
    sXT[(64 + l + 8 * j) * 40 + g] = f2bf(x1nw[(size_t)src * 96 + l + 8 * j]);
  {
    const float4* pd = (const float4*)(p1w + (size_t)dst * 96 + l * 12);
    const float4* ps = (const float4*)(p1w + (size_t)src * 96 + l * 12);
    float dp[12], sp[12];
#pragma unroll
    for (int k = 0; k < 3; ++k) {
      float4 v = pd[k]; dp[4*k] = v.x; dp[4*k+1] = v.y; dp[4*k+2] = v.z; dp[4*k+3] = v.w;
      float4 u = ps[k]; sp[4*k] = u.x; sp[4*k+1] = u.y; sp[4*k+2] = u.z; sp[4*k+3] = u.w;
    }
#pragma unroll
    for (int vv = 0; vv < 4; ++vv) {
      const int b = 3 * vv;
      sIP[g][l * 4 + vv] =
        (dp[b] * sp[b] + dp[b+1] * sp[b+1] + dp[b+2] * sp[b+2]) * INVS3;
    }
  }
  __syncthreads();

  // ---- phase B: hidden layers -> bf16 LDS (zeroed for pad slots) ----
  {
    const bool vf = (sDst[g] >= 0);
    float hfa[4] = {0.f, 0.f, 0.f, 0.f};
    float hla[4] = {0.f, 0.f, 0.f, 0.f};
    for (int c = 0; c < 32; ++c) {
      const float eac = sEA[g][c];
      const float ipc = sIP[g][c];
      const float4 f  = *(const float4*)(F1 + c * 32 + l * 4);
      const float4 lc = *(const float4*)(L1 + (128 + c) * 32 + l * 4);
      hfa[0] = fmaf(eac, f.x, hfa[0]);  hfa[1] = fmaf(eac, f.y, hfa[1]);
      hfa[2] = fmaf(eac, f.z, hfa[2]);  hfa[3] = fmaf(eac, f.w, hfa[3]);
      hla[0] = fmaf(ipc, lc.x, hla[0]); hla[1] = fmaf(ipc, lc.y, hla[1]);
      hla[2] = fmaf(ipc, lc.z, hla[2]); hla[3] = fmaf(ipc, lc.w, hla[3]);
    }
    const float4 av = *(const float4*)(Aw + (size_t)dst * 32 + l * 4);
    const float4 bv = *(const float4*)(Bw + (size_t)src * 32 + l * 4);
    const float f0 = vf ? sspf(hfa[0] * INVS32) : 0.f;
    const float f1 = vf ? sspf(hfa[1] * INVS32) : 0.f;
    const float f2 = vf ? sspf(hfa[2] * INVS32) : 0.f;
    const float f3 = vf ? sspf(hfa[3] * INVS32) : 0.f;
    const float l0 = vf ? sspf(av.x + bv.x + hla[0] * INVS160) : 0.f;
    const float l1v = vf ? sspf(av.y + bv.y + hla[1] * INVS160) : 0.f;
    const float l2v = vf ? sspf(av.z + bv.z + hla[2] * INVS160) : 0.f;
    const float l3v = vf ? sspf(av.w + bv.w + hla[3] * INVS160) : 0.f;
    *(unsigned*)&sHF[g * 40 + l * 4 + 0] = pk(f0, f1);
    *(unsigned*)&sHF[g * 40 + l * 4 + 2] = pk(f2, f3);
    *(unsigned*)&sHL[g * 40 + l * 4 + 0] = pk(l0, l1v);
    *(unsigned*)&sHL[g * 40 + l * 4 + 2] = pk(l2v, l3v);
  }
  __syncthreads();

  // ---- phase C: MFMA w-GEMMs -> sWT f32 (scales folded in F2Tb) ----
  {
    const int wvi  = tid >> 6;
    const int lane = tid & 63;
    const int r = lane & 15;
    const int h = lane >> 4;
    bf16x8 aF0 = *(const bf16x8*)&sHF[r * 40 + h * 8];
    bf16x8 aF1 = *(const bf16x8*)&sHF[(16 + r) * 40 + h * 8];
    bf16x8 aL0 = *(const bf16x8*)&sHL[r * 40 + h * 8];
    bf16x8 aL1 = *(const bf16x8*)&sHL[(16 + r) * 40 + h * 8];
    const int ct0 = (wvi < 2) ? wvi * 4 : 8 + (wvi - 2) * 3;
    const int nct = (wvi < 2) ? 4 : 3;
    for (int t = 0; t < nct; ++t) {
      const int c = (ct0 + t) * 16 + r;
      bf16x8 bF = *(const bf16x8*)&F2Tb[c * 32 + h * 8];
      bf16x8 bL = *(const bf16x8*)&L2Tb[c * 32 + h * 8];
      f32x4 z = {0.f, 0.f, 0.f, 0.f};
      f32x4 wf0 = __builtin_amdgcn_mfma_f32_16x16x32_bf16(aF0, bF, z, 0, 0, 0);
      f32x4 wl0 = __builtin_amdgcn_mfma_f32_16x16x32_bf16(aL0, bL, z, 0, 0, 0);
      f32x4 wf1 = __builtin_amdgcn_mfma_f32_16x16x32_bf16(aF1, bF, z, 0, 0, 0);
      f32x4 wl1 = __builtin_amdgcn_mfma_f32_16x16x32_bf16(aL1, bL, z, 0, 0, 0);
#pragma unroll
      for (int i = 0; i < 4; ++i) {
        sWT[c * 36 + h * 4 + i]      = wf0[i] * wl0[i];
        sWT[c * 36 + 16 + h * 4 + i] = wf1[i] * wl1[i];
      }
    }
  }
  __syncthreads();

  // ---- phase D: vectorized 8-edge-subgroup accumulate + boundary flush ----
  {
    int m0, w0o, xa0, xb0, sa0, sb0;
    decode_ch(tid, m0, w0o, xa0, xb0, sa0, sb0);
    int m1 = -1, w1o = 0, xa1 = 0, xb1 = 0, sa1 = 0, sb1 = 0;
    if (tid < 224) decode_ch(tid + 256, m1, w1o, xa1, xb1, sa1, sb1);
    const float* wRow0 = sWT + w0o;
    const float* wRow1 = sWT + w1o;

    float acc0 = 0.f, acc1 = 0.f;
    for (int sg = 0; sg < 4; ++sg) {
      const int q0 = sg * 8;
      acc0 = acc8(m0, wRow0, sXT, xa0, xb0, sSHT, sa0, sb0, q0, acc0);
      if (m1 >= 0) acc1 = acc8(m1, wRow1, sXT, xa1, xb1, sSHT, sa1, sb1, q0, acc1);
      const int d = sDst[sg * 8];
      const bool fl = (sg == 3) || (sDst[sg * 8 + 8] != d);
      if (fl) {
        if (d >= 0) {
          float* dp = o480 + (size_t)d * 480;
          atomicAdd(dp + tid, acc0);
          if (m1 >= 0) atomicAdd(dp + tid + 256, acc1);
        }
        acc0 = 0.f; acc1 = 0.f;
      }
    }
  }
}

// ---------------- final output linears (transposed weights, 4-partial dots) ----------------
__global__ __launch_bounds__(256) void out_wo_k(
    const float* __restrict__ o480,
    const float* __restrict__ WO0T, const float* __restrict__ WO1T,
    const float* __restrict__ WO2T, const float* __restrict__ bO0,
    float* __restrict__ out)
{
  const int wv = threadIdx.x >> 6, lane = threadIdx.x & 63;
  const int n = blockIdx.x * 4 + wv;
  __shared__ float sO[4][480];
  if (n < NN) {
    const float4* src = (const float4*)(o480 + (size_t)n * 480);
    for (int idx = lane; idx < 120; idx += 64)
      *(float4*)&sO[wv][idx * 4] = src[idx];
  }
  __syncthreads();
  if (n >= NN) return;
  const float* so = sO[wv];
  for (int k = lane; k < 416; k += 64) {
    float y;
    if (k < 128) {
      const float4* wr4 = (const float4*)(WO0T + k * 96);
      float a0 = 0.f, a1 = 0.f, a2 = 0.f, a3 = 0.f;
#pragma unroll
      for (int ch = 0; ch < 24; ch += 4) {
        float4 w0 = wr4[ch], w1 = wr4[ch+1], w2 = wr4[ch+2], w3 = wr4[ch+3];
        a0 = fmaf(w0.x, so[ch*4+0], fmaf(w0.y, so[ch*4+1], fmaf(w0.z, so[ch*4+2], fmaf(w0.w, so[ch*4+3], a0))));
        a1 = fmaf(w1.x, so[ch*4+4], fmaf(w1.y, so[ch*4+5], fmaf(w1.z, so[ch*4+6], fmaf(w1.w, so[ch*4+7], a1))));
        a2 = fmaf(w2.x, so[ch*4+8], fmaf(w2.y, so[ch*4+9], fmaf(w2.z, so[ch*4+10], fmaf(w2.w, so[ch*4+11], a2))));
        a3 = fmaf(w3.x, so[ch*4+12], fmaf(w3.y, so[ch*4+13], fmaf(w3.z, so[ch*4+14], fmaf(w3.w, so[ch*4+15], a3))));
      }
      y = ((a0 + a1) + (a2 + a3)) + bO0[k];
    } else if (k < 320) {
      const int kk = k - 128; const int v = kk / 3; const int i = kk - 3 * v;
      const float* wr = WO1T + v * 96;
      const float* sb = so + 96 + i;
      float a0 = 0.f, a1 = 0.f, a2 = 0.f, a3 = 0.f;
#pragma unroll
      for (int u = 0; u < 96; u += 4) {
        a0 = fmaf(wr[u],     sb[u * 3],       a0);
        a1 = fmaf(wr[u + 1], sb[(u + 1) * 3], a1);
        a2 = fmaf(wr[u + 2], sb[(u + 2) * 3], a2);
        a3 = fmaf(wr[u + 3], sb[(u + 3) * 3], a3);
      }
      y = (a0 + a1) + (a2 + a3);
    } else {
      const int kk = k - 320; const int v = kk / 3; const int i = kk - 3 * v;
      const float* wr = WO2T + v * 32;
      const float* sb = so + 384 + i;
      float a0 = 0.f, a1 = 0.f, a2 = 0.f, a3 = 0.f;
#pragma unroll
      for (int u = 0; u < 32; u += 4) {
        a0 = fmaf(wr[u],     sb[u * 3],       a0);
        a1 = fmaf(wr[u + 1], sb[(u + 1) * 3], a1);
        a2 = fmaf(wr[u + 2], sb[(u + 2) * 3], a2);
        a3 = fmaf(wr[u + 3], sb[(u + 3) * 3], a3);
      }
      y = (a0 + a1) + (a2 + a3);
    }
    out[(size_t)n * 416 + k] = y;
  }
}

// ---------------- host ----------------
extern "C" void kernel_launch(void* const* d_in, const int* in_sizes, int n_in,
                              void* d_out, int out_size, void* d_ws, size_t ws_size,
                              hipStream_t stream) {
  const float* x         = (const float*)d_in[0];
  const float* edge_sh   = (const float*)d_in[1];
  const float* edge_attr = (const float*)d_in[2];
  const float* W0p       = (const float*)d_in[3];
  const float* b0p       = (const float*)d_in[4];
  const float* W1p       = (const float*)d_in[5];
  const float* W0n       = (const float*)d_in[6];
  const float* b0n       = (const float*)d_in[7];
  const float* W1n       = (const float*)d_in[8];
  const float* G1        = (const float*)d_in[9];
  const float* g1b       = (const float*)d_in[10];
  const float* G2        = (const float*)d_in[11];
  const float* g2b       = (const float*)d_in[12];
  const float* F1        = (const float*)d_in[13];
  const float* F2        = (const float*)d_in[14];
  const float* L1        = (const float*)d_in[15];
  const float* L2        = (const float*)d_in[16];
  const float* WO0       = (const float*)d_in[17];
  const float* bO0       = (const float*)d_in[18];
  const float* WO1       = (const float*)d_in[19];
  const float* WO2       = (const float*)d_in[20];
  const int*   ei        = (const int*)d_in[21];
  float* out = (float*)d_out;

  float* p1w  = (float*)d_ws;          // N*96
  float* x0nw = p1w  + NN * 96;        // N*64
  float* x1nw = x0nw + NN * 64;        // N*96
  float* Aw   = x1nw + NN * 96;        // N*32
  float* Bw   = Aw   + NN * 32;        // N*32
  float* o480 = Bw   + NN * 32;        // N*480
  int* cnt    = (int*)(o480 + (size_t)NN * 480);
  int* cursor = cnt    + NN;
  int* order8 = cursor + NN;           // NB*TILE padded slots
  uintptr_t p = (uintptr_t)(order8 + NB * TILE);
  p = (p + 15) & ~(uintptr_t)15;
  ushort* F2Tb = (ushort*)p;           // 224*32 bf16
  ushort* L2Tb = F2Tb + 224 * 32;
  uintptr_t p2 = (uintptr_t)(L2Tb + 224 * 32);
  p2 = (p2 + 15) & ~(uintptr_t)15;
  float* WO0T = (float*)p2;            // 128*96
  float* WO1T = WO0T + 128 * 96;       // 64*96
  float* WO2T = WO1T + 64 * 96;        // 32*32

  hipMemsetAsync(cnt, 0, NN * sizeof(int), stream);
  hipMemsetAsync(o480, 0, (size_t)NN * 480 * sizeof(float), stream);
  hipMemsetAsync(order8, 0xFF, (size_t)NB * TILE * sizeof(int), stream);
  prep_t_k<<<104, 256, 0, stream>>>(F2, L2, WO0, WO1, WO2,
                                    F2Tb, L2Tb, WO0T, WO1T, WO2T);
  hist_k<<<(EE + 255) / 256, 256, 0, stream>>>(ei, cnt);
  scan_k<<<1, 1024, 0, stream>>>(cnt, cursor);
  scat_k<<<(EE + 255) / 256, 256, 0, stream>>>(ei, cursor, order8);
  node_prep_k<<<(NN + 3) / 4, 256, 0, stream>>>(x, W0p, b0p, W1p, W0n, b0n, W1n,
                                                G1, g1b, G2, g2b, L1,
                                                p1w, x0nw, x1nw, Aw, Bw);
  fused_edge_k<<<NB, 256, 0, stream>>>(edge_attr, edge_sh, ei,
                                       F1, L1, F2Tb, L2Tb,
                                       p1w, Aw, Bw, x0nw, x1nw,
                                       order8, o480);
  out_wo_k<<<(NN + 3) / 4, 256, 0, stream>>>(o480, WO0T, WO1T, WO2T, bO0, out);
}

// Round 7
// 468.368 us; speedup vs baseline: 3.3315x; 3.3315x over previous
//
#include <hip/hip_runtime.h>
#include <math.h>

#define NN 10000
#define EE 320000
#define TILE 32

constexpr float INVS32  = 0.17677669529663687f;   // 1/sqrt(32)
constexpr float INVS160 = 0.07905694150420949f;   // 1/sqrt(160)
constexpr float INVS96  = 0.10206207261596575f;   // 1/sqrt(96)
constexpr float INVS3   = 0.5773502691896258f;    // 1/sqrt(3)
constexpr float INVS2   = 0.7071067811865476f;    // 1/sqrt(2)
constexpr float LN2     = 0.6931471805599453f;

typedef short bf16x8 __attribute__((ext_vector_type(8)));
typedef float f32x4  __attribute__((ext_vector_type(4)));

__device__ __forceinline__ float sspf(float v) {
  return fmaxf(v, 0.f) + log1pf(expf(-fabsf(v))) - LN2;
}
__device__ __forceinline__ ushort f2bf(float f) {
  union { float f; unsigned u; } v; v.f = f;
  unsigned r = v.u + 0x7FFF + ((v.u >> 16) & 1);   // RNE
  return (ushort)(r >> 16);
}
__device__ __forceinline__ float bf2f(ushort u) {
  return __uint_as_float(((unsigned)u) << 16);
}
__device__ __forceinline__ unsigned pk(float a, float b) {
  return (unsigned)f2bf(a) | ((unsigned)f2bf(b) << 16);
}

// ---------------- sort-by-dst kernels ----------------
__global__ void hist_k(const int* __restrict__ ei, int* __restrict__ cnt) {
  int e = blockIdx.x * 256 + threadIdx.x;
  if (e < EE) atomicAdd(&cnt[ei[e]], 1);
}

__global__ __launch_bounds__(1024) void scan_k(const int* __restrict__ cnt,
                                               int* __restrict__ cursor) {
  __shared__ int s[1024];
  const int t = threadIdx.x;
  int loc[10];
  int sum = 0;
#pragma unroll
  for (int jj = 0; jj < 10; ++jj) {
    int idx = t * 10 + jj;
    int c = (idx < NN) ? cnt[idx] : 0;
    loc[jj] = sum;
    sum += c;
  }
  s[t] = sum;
  __syncthreads();
  for (int d = 1; d < 1024; d <<= 1) {
    int v = (t >= d) ? s[t - d] : 0;
    __syncthreads();
    s[t] += v;
    __syncthreads();
  }
  const int excl = (t > 0) ? s[t - 1] : 0;
#pragma unroll
  for (int jj = 0; jj < 10; ++jj) {
    int idx = t * 10 + jj;
    if (idx < NN) cursor[idx] = excl + loc[jj];
  }
}

__global__ void scat_k(const int* __restrict__ ei, int* __restrict__ cursor,
                       int* __restrict__ order) {
  int e = blockIdx.x * 256 + threadIdx.x;
  if (e < EE) {
    int p = atomicAdd(&cursor[ei[e]], 1);
    order[p] = e;
  }
}

// ---------------- weight transforms: F2T/L2T bf16 (scale folded), WO*T f32 ----------------
__global__ void prep_t_k(const float* __restrict__ F2, const float* __restrict__ L2,
                         const float* __restrict__ WO0, const float* __restrict__ WO1,
                         const float* __restrict__ WO2,
                         ushort* __restrict__ F2Tb, ushort* __restrict__ L2Tb,
                         float* __restrict__ WO0T, float* __restrict__ WO1T,
                         float* __restrict__ WO2T) {
  int i = blockIdx.x * 256 + threadIdx.x;
  if (i < 7168) {                         // F2T/L2T: [c][k] bf16
    int c = i >> 5, k = i & 31;
    float sc = (c < 64)  ? (1.f / 32.f)
             : (c < 128) ? (INVS3 / 32.f)
             : (c < 160) ? (1.f / 32.f)
             : (c < 192) ? (INVS3 / 32.f)
                         : (INVS2 / 32.f);
    F2Tb[i] = f2bf(F2[k * 224 + c] * sc);
    L2Tb[i] = f2bf(L2[k * 224 + c]);
  } else if (i < 7168 + 12288) {          // WO0T [128][96], scale folded
    int j = i - 7168; int k = j / 96, u = j - k * 96;
    WO0T[j] = WO0[u * 128 + k] * INVS96;
  } else if (i < 7168 + 12288 + 6144) {   // WO1T [64][96]
    int j = i - 7168 - 12288; int v = j / 96, u = j - v * 96;
    WO1T[j] = WO1[u * 64 + v] * INVS96;
  } else if (i < 7168 + 12288 + 6144 + 1024) {  // WO2T [32][32]
    int j = i - 7168 - 12288 - 6144; int v = j >> 5, u = j & 31;
    WO2T[j] = WO2[u * 32 + v] * INVS32;
  }
}

// ---------------- node-level precompute (4-partial ILP dots) ----------------
__global__ __launch_bounds__(256) void node_prep_k(
    const float* __restrict__ x,
    const float* __restrict__ W0p, const float* __restrict__ b0p,
    const float* __restrict__ W1p,
    const float* __restrict__ W0n, const float* __restrict__ b0n,
    const float* __restrict__ W1n,
    const float* __restrict__ G1, const float* __restrict__ g1b,
    const float* __restrict__ G2, const float* __restrict__ g2b,
    const float* __restrict__ L1,
    float* __restrict__ p1w, float* __restrict__ x0nw, float* __restrict__ x1nw,
    float* __restrict__ Aw, float* __restrict__ Bw)
{
  const int wv   = threadIdx.x >> 6;
  const int lane = threadIdx.x & 63;
  const int n    = blockIdx.x * 4 + wv;
  const bool nv  = (n < NN);

  __shared__ float sX[4][160];
  __shared__ float sP0[4][64];
  __shared__ float sF0[4][96];
  __shared__ float sH1[4][96];
  __shared__ float sG[4][96];

  if (nv) {
    sX[wv][lane]      = x[n * 160 + lane];
    sX[wv][lane + 64] = x[n * 160 + lane + 64];
    if (lane < 32) sX[wv][lane + 128] = x[n * 160 + lane + 128];
  }
  __syncthreads();

  if (nv) {
    {
      float d0 = 0.f, d1 = 0.f, d2 = 0.f, d3 = 0.f;
      for (int i = 0; i < 64; i += 4) {
        d0 = fmaf(sX[wv][i],     W0p[i * 64 + lane],       d0);
        d1 = fmaf(sX[wv][i + 1], W0p[(i + 1) * 64 + lane], d1);
        d2 = fmaf(sX[wv][i + 2], W0p[(i + 2) * 64 + lane], d2);
        d3 = fmaf(sX[wv][i + 3], W0p[(i + 3) * 64 + lane], d3);
      }
      sP0[wv][lane] = ((d0 + d1) + (d2 + d3)) * 0.125f + b0p[lane];
      sF0[wv][lane] = sX[wv][lane];
    }
    for (int o = lane; o < 96; o += 64) {
      const int v = o / 3, i_ = o % 3;
      float d0 = 0.f, d1 = 0.f;
      for (int u = 0; u < 32; u += 2) {
        d0 = fmaf(sX[wv][64 + u * 3 + i_],       W1p[u * 32 + v],       d0);
        d1 = fmaf(sX[wv][64 + (u + 1) * 3 + i_], W1p[(u + 1) * 32 + v], d1);
      }
      p1w[n * 96 + o] = (d0 + d1) * INVS32;
    }
    if (lane < 32) {
      float s2 = 1e-12f;
#pragma unroll
      for (int i = 0; i < 3; ++i) { float t = sX[wv][64 + lane * 3 + i]; s2 += t * t; }
      sF0[wv][64 + lane] = sqrtf(s2);
    }
  }
  __syncthreads();

  if (nv) for (int o = lane; o < 96; o += 64) {
    float d0 = g1b[o], d1 = 0.f, d2 = 0.f, d3 = 0.f;
    for (int i = 0; i < 96; i += 4) {
      d0 = fmaf(sF0[wv][i],     G1[i * 96 + o],       d0);
      d1 = fmaf(sF0[wv][i + 1], G1[(i + 1) * 96 + o], d1);
      d2 = fmaf(sF0[wv][i + 2], G1[(i + 2) * 96 + o], d2);
      d3 = fmaf(sF0[wv][i + 3], G1[(i + 3) * 96 + o], d3);
    }
    float d = (d0 + d1) + (d2 + d3);
    sH1[wv][o] = d / (1.f + expf(-d));
  }
  __syncthreads();

  if (nv) for (int o = lane; o < 96; o += 64) {
    float d0 = g2b[o], d1 = 0.f, d2 = 0.f, d3 = 0.f;
    for (int i = 0; i < 96; i += 4) {
      d0 = fmaf(sH1[wv][i],     G2[i * 96 + o],       d0);
      d1 = fmaf(sH1[wv][i + 1], G2[(i + 1) * 96 + o], d1);
      d2 = fmaf(sH1[wv][i + 2], G2[(i + 2) * 96 + o], d2);
      d3 = fmaf(sH1[wv][i + 3], G2[(i + 3) * 96 + o], d3);
    }
    sG[wv][o] = (d0 + d1) + (d2 + d3);
  }
  __syncthreads();

  if (nv) {
    {
      float d0 = 0.f, d1 = 0.f, d2 = 0.f, d3 = 0.f;
      for (int i = 0; i < 64; i += 4) {
        d0 = fmaf(sG[wv][i],     W0n[i * 64 + lane],       d0);
        d1 = fmaf(sG[wv][i + 1], W0n[(i + 1) * 64 + lane], d1);
        d2 = fmaf(sG[wv][i + 2], W0n[(i + 2) * 64 + lane], d2);
        d3 = fmaf(sG[wv][i + 3], W0n[(i + 3) * 64 + lane], d3);
      }
      x0nw[n * 64 + lane] = ((d0 + d1) + (d2 + d3)) * 0.125f + b0n[lane];
    }
    for (int o = lane; o < 96; o += 64) {
      const int v = o / 3, i_ = o % 3;
      float d0 = 0.f, d1 = 0.f;
      for (int u = 0; u < 32; u += 2) {
        d0 = fmaf(sX[wv][64 + u * 3 + i_] * sG[wv][64 + u],
                  W1n[u * 32 + v], d0);
        d1 = fmaf(sX[wv][64 + (u + 1) * 3 + i_] * sG[wv][64 + u + 1],
                  W1n[(u + 1) * 32 + v], d1);
      }
      x1nw[n * 96 + o] = (d0 + d1) * INVS32;
    }
    if (lane < 32) {
      float a0 = 0.f, a1 = 0.f, b0 = 0.f, b1 = 0.f;
      for (int i = 0; i < 64; i += 2) {
        a0 = fmaf(sP0[wv][i],     L1[i * 32 + lane],         a0);
        a1 = fmaf(sP0[wv][i + 1], L1[(i + 1) * 32 + lane],   a1);
        b0 = fmaf(sP0[wv][i],     L1[(64 + i) * 32 + lane],  b0);
        b1 = fmaf(sP0[wv][i + 1], L1[(65 + i) * 32 + lane],  b1);
      }
      Aw[n * 32 + lane] = (a0 + a1) * INVS160;
      Bw[n * 32 + lane] = (b0 + b1) * INVS160;
    }
  }
}

// ---------------- fused per-edge MLP (MFMA) + scatter kernel (R4-proven) ----------------
__global__ __launch_bounds__(256, 4) void fused_edge_k(
    const float* __restrict__ edge_attr,
    const float* __restrict__ edge_sh,
    const int* __restrict__ ei,
    const float* __restrict__ F1, const float* __restrict__ L1,
    const ushort* __restrict__ F2Tb, const ushort* __restrict__ L2Tb,
    const float* __restrict__ p1w, const float* __restrict__ Aw,
    const float* __restrict__ Bw,
    const float* __restrict__ x0nw, const float* __restrict__ x1nw,
    const int* __restrict__ order,
    float* __restrict__ o480)
{
  const int s0  = blockIdx.x * TILE;
  const int tid = threadIdx.x;

  // union region: sW (bf16 32x224) overlaps sEA/sIP (f32 32x36, dead after B)
  __shared__ __align__(16) char uMem[32 * 224 * 2];          // 14336 B
  ushort (*sW)[224] = (ushort (*)[224])uMem;
  float  (*sEA)[36] = (float (*)[36])uMem;                   // 4608 B
  float  (*sIP)[36] = (float (*)[36])(uMem + 32 * 36 * 4);   // 4608 B

  __shared__ ushort sHF[32][40];    // bf16, 80B row stride (2-way banks)
  __shared__ ushort sHL[32][40];
  __shared__ ushort sXS0[32][64];   // bf16
  __shared__ ushort sXS1[32][96];   // bf16
  __shared__ float  sSH[32][4];
  __shared__ int    sDst[32];

  const int g = tid >> 3, l = tid & 7;   // 8 threads per edge
  const int e   = order[s0 + g];
  const int dst = ei[e];
  const int src = ei[EE + e];
  if (l == 0) sDst[g] = dst;

  // ---- phase A: stage per-edge data ----
  *(float4*)&sEA[g][l * 4] = *(const float4*)(edge_attr + (size_t)e * 32 + l * 4);
  if (l == 1) *(float4*)&sSH[g][0] = *(const float4*)(edge_sh + (size_t)e * 4);
  {
    const float4* a4 = (const float4*)(x0nw + (size_t)src * 64 + l * 8);
    float4 v0 = a4[0], v1 = a4[1];
    *(unsigned*)&sXS0[g][l * 8 + 0] = pk(v0.x, v0.y);
    *(unsigned*)&sXS0[g][l * 8 + 2] = pk(v0.z, v0.w);
    *(unsigned*)&sXS0[g][l * 8 + 4] = pk(v1.x, v1.y);
    *(unsigned*)&sXS0[g][l * 8 + 6] = pk(v1.z, v1.w);
    const float4* b4 = (const float4*)(x1nw + (size_t)src * 96 + l * 12);
    float4 w0 = b4[0], w1 = b4[1], w2 = b4[2];
    *(unsigned*)&sXS1[g][l * 12 + 0]  = pk(w0.x, w0.y);
    *(unsigned*)&sXS1[g][l * 12 + 2]  = pk(w0.z, w0.w);
    *(unsigned*)&sXS1[g][l * 12 + 4]  = pk(w1.x, w1.y);
    *(unsigned*)&sXS1[g][l * 12 + 6]  = pk(w1.z, w1.w);
    *(unsigned*)&sXS1[g][l * 12 + 8]  = pk(w2.x, w2.y);
    *(unsigned*)&sXS1[g][l * 12 + 10] = pk(w2.z, w2.w);
  }
  {
    const float4* pd = (const float4*)(p1w + (size_t)dst * 96 + l * 12);
    const float4* ps = (const float4*)(p1w + (size_t)src * 96 + l * 12);
    float dp[12], sp[12];
#pragma unroll
    for (int k = 0; k < 3; ++k) {
      float4 v = pd[k]; dp[4*k] = v.x; dp[4*k+1] = v.y; dp[4*k+2] = v.z; dp[4*k+3] = v.w;
      float4 u = ps[k]; sp[4*k] = u.x; sp[4*k+1] = u.y; sp[4*k+2] = u.z; sp[4*k+3] = u.w;
    }
#pragma unroll
    for (int vv = 0; vv < 4; ++vv) {
      const int b = 3 * vv;
      sIP[g][l * 4 + vv] =
        (dp[b] * sp[b] + dp[b+1] * sp[b+1] + dp[b+2] * sp[b+2]) * INVS3;
    }
  }
  __syncthreads();

  // ---- phase B: hidden layers -> bf16 LDS ----
  {
    float hfa[4] = {0.f, 0.f, 0.f, 0.f};
    float hla[4] = {0.f, 0.f, 0.f, 0.f};
    for (int c = 0; c < 32; ++c) {
      const float eac = sEA[g][c];
      const float ipc = sIP[g][c];
      const float4 f  = *(const float4*)(F1 + c * 32 + l * 4);
      const float4 lc = *(const float4*)(L1 + (128 + c) * 32 + l * 4);
      hfa[0] = fmaf(eac, f.x, hfa[0]);  hfa[1] = fmaf(eac, f.y, hfa[1]);
      hfa[2] = fmaf(eac, f.z, hfa[2]);  hfa[3] = fmaf(eac, f.w, hfa[3]);
      hla[0] = fmaf(ipc, lc.x, hla[0]); hla[1] = fmaf(ipc, lc.y, hla[1]);
      hla[2] = fmaf(ipc, lc.z, hla[2]); hla[3] = fmaf(ipc, lc.w, hla[3]);
    }
    const float4 av = *(const float4*)(Aw + (size_t)dst * 32 + l * 4);
    const float4 bv = *(const float4*)(Bw + (size_t)src * 32 + l * 4);
    const float f0 = sspf(hfa[0] * INVS32), f1 = sspf(hfa[1] * INVS32);
    const float f2 = sspf(hfa[2] * INVS32), f3 = sspf(hfa[3] * INVS32);
    const float l0 = sspf(av.x + bv.x + hla[0] * INVS160);
    const float l1v = sspf(av.y + bv.y + hla[1] * INVS160);
    const float l2v = sspf(av.z + bv.z + hla[2] * INVS160);
    const float l3v = sspf(av.w + bv.w + hla[3] * INVS160);
    *(unsigned*)&sHF[g][l * 4 + 0] = pk(f0, f1);
    *(unsigned*)&sHF[g][l * 4 + 2] = pk(f2, f3);
    *(unsigned*)&sHL[g][l * 4 + 0] = pk(l0, l1v);
    *(unsigned*)&sHL[g][l * 4 + 2] = pk(l2v, l3v);
  }
  __syncthreads();

  // ---- phase C: MFMA w-GEMMs: [32x32]@[32x224] x2, w = Wf.*Wl (bf16 out) ----
  {
    const int wv   = tid >> 6;
    const int lane = tid & 63;
    const int r = lane & 15;   // A row / B col within tile
    const int h = lane >> 4;   // k-offset h*8
    bf16x8 aF0 = *(const bf16x8*)&sHF[r][h * 8];
    bf16x8 aF1 = *(const bf16x8*)&sHF[16 + r][h * 8];
    bf16x8 aL0 = *(const bf16x8*)&sHL[r][h * 8];
    bf16x8 aL1 = *(const bf16x8*)&sHL[16 + r][h * 8];
    const int ct0 = (wv < 2) ? wv * 4 : 8 + (wv - 2) * 3;
    const int nct = (wv < 2) ? 4 : 3;
    for (int t = 0; t < nct; ++t) {
      const int ct = ct0 + t;
      const int c  = ct * 16 + r;
      bf16x8 bF = *(const bf16x8*)&F2Tb[c * 32 + h * 8];
      bf16x8 bL = *(const bf16x8*)&L2Tb[c * 32 + h * 8];
      f32x4 z = {0.f, 0.f, 0.f, 0.f};
      f32x4 wf0 = __builtin_amdgcn_mfma_f32_16x16x32_bf16(aF0, bF, z, 0, 0, 0);
      f32x4 wl0 = __builtin_amdgcn_mfma_f32_16x16x32_bf16(aL0, bL, z, 0, 0, 0);
      f32x4 wf1 = __builtin_amdgcn_mfma_f32_16x16x32_bf16(aF1, bF, z, 0, 0, 0);
      f32x4 wl1 = __builtin_amdgcn_mfma_f32_16x16x32_bf16(aL1, bL, z, 0, 0, 0);
#pragma unroll
      for (int i = 0; i < 4; ++i) {
        sW[h * 4 + i][c]      = f2bf(wf0[i] * wl0[i]);
        sW[16 + h * 4 + i][c] = f2bf(wf1[i] * wl1[i]);
      }
    }
  }
  __syncthreads();

  // ---- phase D: walk 32 sorted edges, accumulate, flush at dst boundaries ----
  {
    auto chan = [&](int q, int k) -> float {
      if (k < 64) {
        return bf2f(sW[q][k]) * bf2f(sXS0[q][k]) * sSH[q][0];
      } else if (k < 96) {
        const int c = k - 64;
        const float d = bf2f(sXS1[q][c*3+0]) * sSH[q][1]
                      + bf2f(sXS1[q][c*3+1]) * sSH[q][2]
                      + bf2f(sXS1[q][c*3+2]) * sSH[q][3];
        return bf2f(sW[q][160 + c]) * d;
      } else if (k < 288) {
        const int kk = k - 96; const int u = kk / 3; const int i = kk - 3 * u;
        return bf2f(sW[q][64 + u]) * bf2f(sXS0[q][u]) * sSH[q][1 + i];
      } else if (k < 384) {
        const int kk = k - 288; const int u = kk / 3; const int i = kk - 3 * u;
        return bf2f(sW[q][128 + u]) * bf2f(sXS1[q][u * 3 + i]) * sSH[q][0];
      } else {
        const int kk = k - 384; const int u = kk / 3; const int i = kk - 3 * u;
        const int i1 = (i + 1) % 3, i2 = (i + 2) % 3;
        const float cr = bf2f(sXS1[q][u * 3 + i1]) * sSH[q][1 + i2]
                       - bf2f(sXS1[q][u * 3 + i2]) * sSH[q][1 + i1];
        return bf2f(sW[q][192 + u]) * cr;
      }
    };

    float acc0 = 0.f, acc1 = 0.f;
    for (int q = 0; q < TILE; ++q) {
      acc0 += chan(q, tid);
      if (tid < 224) acc1 += chan(q, tid + 256);
      const bool boundary = (q == TILE - 1) || (sDst[q + 1] != sDst[q]);
      if (boundary) {
        float* dp = o480 + (size_t)sDst[q] * 480;
        atomicAdd(dp + tid, acc0);
        if (tid < 224) atomicAdd(dp + tid + 256, acc1);
        acc0 = 0.f; acc1 = 0.f;
      }
    }
  }
}

// ---------------- final output linears (transposed weights, 4-partial dots) ----------------
__global__ __launch_bounds__(256) void out_wo_k(
    const float* __restrict__ o480,
    const float* __restrict__ WO0T, const float* __restrict__ WO1T,
    const float* __restrict__ WO2T, const float* __restrict__ bO0,
    float* __restrict__ out)
{
  const int wv = threadIdx.x >> 6, lane = threadIdx.x & 63;
  const int n = blockIdx.x * 4 + wv;
  __shared__ float sO[4][480];
  if (n < NN) {
    const float4* src = (const float4*)(o480 + (size_t)n * 480);
    for (int idx = lane; idx < 120; idx += 64)
      *(float4*)&sO[wv][idx * 4] = src[idx];
  }
  __syncthreads();
  if (n >= NN) return;
  const float* so = sO[wv];
  for (int k = lane; k < 416; k += 64) {
    float y;
    if (k < 128) {
      const float4* wr4 = (const float4*)(WO0T + k * 96);
      float a0 = 0.f, a1 = 0.f, a2 = 0.f, a3 = 0.f;
#pragma unroll
      for (int ch = 0; ch < 24; ch += 4) {
        float4 w0 = wr4[ch], w1 = wr4[ch+1], w2 = wr4[ch+2], w3 = wr4[ch+3];
        a0 = fmaf(w0.x, so[ch*4+0], fmaf(w0.y, so[ch*4+1], fmaf(w0.z, so[ch*4+2], fmaf(w0.w, so[ch*4+3], a0))));
        a1 = fmaf(w1.x, so[ch*4+4], fmaf(w1.y, so[ch*4+5], fmaf(w1.z, so[ch*4+6], fmaf(w1.w, so[ch*4+7], a1))));
        a2 = fmaf(w2.x, so[ch*4+8], fmaf(w2.y, so[ch*4+9], fmaf(w2.z, so[ch*4+10], fmaf(w2.w, so[ch*4+11], a2))));
        a3 = fmaf(w3.x, so[ch*4+12], fmaf(w3.y, so[ch*4+13], fmaf(w3.z, so[ch*4+14], fmaf(w3.w, so[ch*4+15], a3))));
      }
      y = ((a0 + a1) + (a2 + a3)) + bO0[k];
    } else if (k < 320) {
      const int kk = k - 128; const int v = kk / 3; const int i = kk - 3 * v;
      const float* wr = WO1T + v * 96;
      const float* sb = so + 96 + i;
      float a0 = 0.f, a1 = 0.f, a2 = 0.f, a3 = 0.f;
#pragma unroll
      for (int u = 0; u < 96; u += 4) {
        a0 = fmaf(wr[u],     sb[u * 3],       a0);
        a1 = fmaf(wr[u + 1], sb[(u + 1) * 3], a1);
        a2 = fmaf(wr[u + 2], sb[(u + 2) * 3], a2);
        a3 = fmaf(wr[u + 3], sb[(u + 3) * 3], a3);
      }
      y = (a0 + a1) + (a2 + a3);
    } else {
      const int kk = k - 320; const int v = kk / 3; const int i = kk - 3 * v;
      const float* wr = WO2T + v * 32;
      const float* sb = so + 384 + i;
      float a0 = 0.f, a1 = 0.f, a2 = 0.f, a3 = 0.f;
#pragma unroll
      for (int u = 0; u < 32; u += 4) {
        a0 = fmaf(wr[u],     sb[u * 3],       a0);
        a1 = fmaf(wr[u + 1], sb[(u + 1) * 3], a1);
        a2 = fmaf(wr[u + 2], sb[(u + 2) * 3], a2);
        a3 = fmaf(wr[u + 3], sb[(u + 3) * 3], a3);
      }
      y = (a0 + a1) + (a2 + a3);
    }
    out[(size_t)n * 416 + k] = y;
  }
}

// ---------------- host ----------------
extern "C" void kernel_launch(void* const* d_in, const int* in_sizes, int n_in,
                              void* d_out, int out_size, void* d_ws, size_t ws_size,
                              hipStream_t stream) {
  const float* x         = (const float*)d_in[0];
  const float* edge_sh   = (const float*)d_in[1];
  const float* edge_attr = (const float*)d_in[2];
  const float* W0p       = (const float*)d_in[3];
  const float* b0p       = (const float*)d_in[4];
  const float* W1p       = (const float*)d_in[5];
  const float* W0n       = (const float*)d_in[6];
  const float* b0n       = (const float*)d_in[7];
  const float* W1n       = (const float*)d_in[8];
  const float* G1        = (const float*)d_in[9];
  const float* g1b       = (const float*)d_in[10];
  const float* G2        = (const float*)d_in[11];
  const float* g2b       = (const float*)d_in[12];
  const float* F1        = (const float*)d_in[13];
  const float* F2        = (const float*)d_in[14];
  const float* L1        = (const float*)d_in[15];
  const float* L2        = (const float*)d_in[16];
  const float* WO0       = (const float*)d_in[17];
  const float* bO0       = (const float*)d_in[18];
  const float* WO1       = (const float*)d_in[19];
  const float* WO2       = (const float*)d_in[20];
  const int*   ei        = (const int*)d_in[21];
  float* out = (float*)d_out;

  float* p1w  = (float*)d_ws;          // N*96
  float* x0nw = p1w  + NN * 96;        // N*64
  float* x1nw = x0nw + NN * 64;        // N*96
  float* Aw   = x1nw + NN * 96;        // N*32
  float* Bw   = Aw   + NN * 32;        // N*32
  float* o480 = Bw   + NN * 32;        // N*480
  int* cnt    = (int*)(o480 + (size_t)NN * 480);
  int* cursor = cnt    + NN;
  int* order  = cursor + NN;           // E
  uintptr_t p = (uintptr_t)(order + EE);
  p = (p + 15) & ~(uintptr_t)15;
  ushort* F2Tb = (ushort*)p;           // 224*32 bf16
  ushort* L2Tb = F2Tb + 224 * 32;
  uintptr_t p2 = (uintptr_t)(L2Tb + 224 * 32);
  p2 = (p2 + 15) & ~(uintptr_t)15;
  float* WO0T = (float*)p2;            // 128*96
  float* WO1T = WO0T + 128 * 96;       // 64*96
  float* WO2T = WO1T + 64 * 96;        // 32*32

  hipMemsetAsync(cnt, 0, NN * sizeof(int), stream);
  hipMemsetAsync(o480, 0, (size_t)NN * 480 * sizeof(float), stream);
  prep_t_k<<<104, 256, 0, stream>>>(F2, L2, WO0, WO1, WO2,
                                    F2Tb, L2Tb, WO0T, WO1T, WO2T);
  hist_k<<<(EE + 255) / 256, 256, 0, stream>>>(ei, cnt);
  scan_k<<<1, 1024, 0, stream>>>(cnt, cursor);
  scat_k<<<(EE + 255) / 256, 256, 0, stream>>>(ei, cursor, order);
  node_prep_k<<<(NN + 3) / 4, 256, 0, stream>>>(x, W0p, b0p, W1p, W0n, b0n, W1n,
                                                G1, g1b, G2, g2b, L1,
                                                p1w, x0nw, x1nw, Aw, Bw);
  fused_edge_k<<<EE / TILE, 256, 0, stream>>>(edge_attr, edge_sh, ei,
                                              F1, L1, F2Tb, L2Tb,
                                              p1w, Aw, Bw, x0nw, x1nw,
                                              order, o480);
  out_wo_k<<<(NN + 3) / 4, 256, 0, stream>>>(o480, WO0T, WO1T, WO2T, bO0, out);
}

// Round 8
// 414.297 us; speedup vs baseline: 3.7663x; 1.1305x over previous
//
#include <hip/hip_runtime.h>
#include <math.h>

#define NN 10000
#define EE 320000
#define TILE 32

constexpr float INVS32  = 0.17677669529663687f;   // 1/sqrt(32)
constexpr float INVS160 = 0.07905694150420949f;   // 1/sqrt(160)
constexpr float INVS96  = 0.10206207261596575f;   // 1/sqrt(96)
constexpr float INVS3   = 0.5773502691896258f;    // 1/sqrt(3)
constexpr float INVS2   = 0.7071067811865476f;    // 1/sqrt(2)
constexpr float LN2     = 0.6931471805599453f;

typedef short bf16x8 __attribute__((ext_vector_type(8)));
typedef float f32x4  __attribute__((ext_vector_type(4)));

__device__ __forceinline__ float sspf(float v) {
  return fmaxf(v, 0.f) + log1pf(expf(-fabsf(v))) - LN2;
}
__device__ __forceinline__ ushort f2bf(float f) {
  union { float f; unsigned u; } v; v.f = f;
  unsigned r = v.u + 0x7FFF + ((v.u >> 16) & 1);   // RNE
  return (ushort)(r >> 16);
}
__device__ __forceinline__ float bf2f(ushort u) {
  return __uint_as_float(((unsigned)u) << 16);
}
__device__ __forceinline__ unsigned pk(float a, float b) {
  return (unsigned)f2bf(a) | ((unsigned)f2bf(b) << 16);
}

// ---------------- sort-by-dst ----------------
__global__ __launch_bounds__(1024) void scan_k(const int* __restrict__ cnt,
                                               int* __restrict__ cursor) {
  __shared__ int s[1024];
  const int t = threadIdx.x;
  int loc[10];
  int sum = 0;
#pragma unroll
  for (int jj = 0; jj < 10; ++jj) {
    int idx = t * 10 + jj;
    int c = (idx < NN) ? cnt[idx] : 0;
    loc[jj] = sum;
    sum += c;
  }
  s[t] = sum;
  __syncthreads();
  for (int d = 1; d < 1024; d <<= 1) {
    int v = (t >= d) ? s[t - d] : 0;
    __syncthreads();
    s[t] += v;
    __syncthreads();
  }
  const int excl = (t > 0) ? s[t - 1] : 0;
#pragma unroll
  for (int jj = 0; jj < 10; ++jj) {
    int idx = t * 10 + jj;
    if (idx < NN) cursor[idx] = excl + loc[jj];
  }
}

// ---------------- weight transforms + fused histogram ----------------
// grid 1250x256: every thread does hist for one edge; low threads also transpose.
__global__ void prep_t_k(const float* __restrict__ F2, const float* __restrict__ L2,
                         const float* __restrict__ WO0, const float* __restrict__ WO1,
                         const float* __restrict__ WO2,
                         const float* __restrict__ F1, const float* __restrict__ L1,
                         const int* __restrict__ ei, int* __restrict__ cnt,
                         ushort* __restrict__ F2Tb, ushort* __restrict__ L2Tb,
                         float* __restrict__ WO0T, float* __restrict__ WO1T,
                         float* __restrict__ WO2T,
                         ushort* __restrict__ F1Tb, ushort* __restrict__ L1cTb) {
  int i = blockIdx.x * 256 + threadIdx.x;
  if (i < EE) atomicAdd(&cnt[ei[i]], 1);
  if (i < 7168) {                         // F2T/L2T: [c][k] bf16
    int c = i >> 5, k = i & 31;
    float sc = (c < 64)  ? (1.f / 32.f)
             : (c < 128) ? (INVS3 / 32.f)
             : (c < 160) ? (1.f / 32.f)
             : (c < 192) ? (INVS3 / 32.f)
                         : (INVS2 / 32.f);
    F2Tb[i] = f2bf(F2[k * 224 + c] * sc);
    L2Tb[i] = f2bf(L2[k * 224 + c]);
  } else if (i < 7168 + 12288) {          // WO0T [128][96], scale folded
    int j = i - 7168; int k = j / 96, u = j - k * 96;
    WO0T[j] = WO0[u * 128 + k] * INVS96;
  } else if (i < 7168 + 12288 + 6144) {   // WO1T [64][96]
    int j = i - 7168 - 12288; int v = j / 96, u = j - v * 96;
    WO1T[j] = WO1[u * 64 + v] * INVS96;
  } else if (i < 7168 + 12288 + 6144 + 1024) {  // WO2T [32][32]
    int j = i - 7168 - 12288 - 6144; int v = j >> 5, u = j & 31;
    WO2T[j] = WO2[u * 32 + v] * INVS32;
  } else if (i < 26624 + 1024) {          // F1T [32n][32k] bf16, INVS32 folded
    int j = i - 26624; int n = j >> 5, k = j & 31;
    F1Tb[j] = f2bf(F1[k * 32 + n] * INVS32);
  } else if (i < 27648 + 1024) {          // L1cT [32n][32k] bf16, INVS160 folded
    int j = i - 27648; int n = j >> 5, k = j & 31;
    L1cTb[j] = f2bf(L1[(128 + k) * 32 + n] * INVS160);
  }
}

// ---------------- node-level precompute + fused scatter ----------------
__global__ __launch_bounds__(256) void node_prep_k(
    const float* __restrict__ x,
    const float* __restrict__ W0p, const float* __restrict__ b0p,
    const float* __restrict__ W1p,
    const float* __restrict__ W0n, const float* __restrict__ b0n,
    const float* __restrict__ W1n,
    const float* __restrict__ G1, const float* __restrict__ g1b,
    const float* __restrict__ G2, const float* __restrict__ g2b,
    const float* __restrict__ L1,
    const int* __restrict__ ei, int* __restrict__ cursor, int* __restrict__ order,
    float* __restrict__ p1w, float* __restrict__ x0nw, float* __restrict__ x1nw,
    float* __restrict__ Aw, float* __restrict__ Bw)
{
  {  // fused scat: 2500x256 = 640K threads covers EE
    int gid = blockIdx.x * 256 + threadIdx.x;
    if (gid < EE) {
      int p = atomicAdd(&cursor[ei[gid]], 1);
      order[p] = gid;
    }
  }

  const int wv   = threadIdx.x >> 6;
  const int lane = threadIdx.x & 63;
  const int n    = blockIdx.x * 4 + wv;
  const bool nv  = (n < NN);

  __shared__ float sX[4][160];
  __shared__ float sP0[4][64];
  __shared__ float sF0[4][96];
  __shared__ float sH1[4][96];
  __shared__ float sG[4][96];

  if (nv) {
    sX[wv][lane]      = x[n * 160 + lane];
    sX[wv][lane + 64] = x[n * 160 + lane + 64];
    if (lane < 32) sX[wv][lane + 128] = x[n * 160 + lane + 128];
  }
  __syncthreads();

  if (nv) {
    {
      float d0 = 0.f, d1 = 0.f, d2 = 0.f, d3 = 0.f;
      for (int i = 0; i < 64; i += 4) {
        d0 = fmaf(sX[wv][i],     W0p[i * 64 + lane],       d0);
        d1 = fmaf(sX[wv][i + 1], W0p[(i + 1) * 64 + lane], d1);
        d2 = fmaf(sX[wv][i + 2], W0p[(i + 2) * 64 + lane], d2);
        d3 = fmaf(sX[wv][i + 3], W0p[(i + 3) * 64 + lane], d3);
      }
      sP0[wv][lane] = ((d0 + d1) + (d2 + d3)) * 0.125f + b0p[lane];
      sF0[wv][lane] = sX[wv][lane];
    }
    for (int o = lane; o < 96; o += 64) {
      const int v = o / 3, i_ = o % 3;
      float d0 = 0.f, d1 = 0.f;
      for (int u = 0; u < 32; u += 2) {
        d0 = fmaf(sX[wv][64 + u * 3 + i_],       W1p[u * 32 + v],       d0);
        d1 = fmaf(sX[wv][64 + (u + 1) * 3 + i_], W1p[(u + 1) * 32 + v], d1);
      }
      p1w[n * 96 + o] = (d0 + d1) * INVS32;
    }
    if (lane < 32) {
      float s2 = 1e-12f;
#pragma unroll
      for (int i = 0; i < 3; ++i) { float t = sX[wv][64 + lane * 3 + i]; s2 += t * t; }
      sF0[wv][64 + lane] = sqrtf(s2);
    }
  }
  __syncthreads();

  if (nv) for (int o = lane; o < 96; o += 64) {
    float d0 = g1b[o], d1 = 0.f, d2 = 0.f, d3 = 0.f;
    for (int i = 0; i < 96; i += 4) {
      d0 = fmaf(sF0[wv][i],     G1[i * 96 + o],       d0);
      d1 = fmaf(sF0[wv][i + 1], G1[(i + 1) * 96 + o], d1);
      d2 = fmaf(sF0[wv][i + 2], G1[(i + 2) * 96 + o], d2);
      d3 = fmaf(sF0[wv][i + 3], G1[(i + 3) * 96 + o], d3);
    }
    float d = (d0 + d1) + (d2 + d3);
    sH1[wv][o] = d / (1.f + expf(-d));
  }
  __syncthreads();

  if (nv) for (int o = lane; o < 96; o += 64) {
    float d0 = g2b[o], d1 = 0.f, d2 = 0.f, d3 = 0.f;
    for (int i = 0; i < 96; i += 4) {
      d0 = fmaf(sH1[wv][i],     G2[i * 96 + o],       d0);
      d1 = fmaf(sH1[wv][i + 1], G2[(i + 1) * 96 + o], d1);
      d2 = fmaf(sH1[wv][i + 2], G2[(i + 2) * 96 + o], d2);
      d3 = fmaf(sH1[wv][i + 3], G2[(i + 3) * 96 + o], d3);
    }
    sG[wv][o] = (d0 + d1) + (d2 + d3);
  }
  __syncthreads();

  if (nv) {
    {
      float d0 = 0.f, d1 = 0.f, d2 = 0.f, d3 = 0.f;
      for (int i = 0; i < 64; i += 4) {
        d0 = fmaf(sG[wv][i],     W0n[i * 64 + lane],       d0);
        d1 = fmaf(sG[wv][i + 1], W0n[(i + 1) * 64 + lane], d1);
        d2 = fmaf(sG[wv][i + 2], W0n[(i + 2) * 64 + lane], d2);
        d3 = fmaf(sG[wv][i + 3], W0n[(i + 3) * 64 + lane], d3);
      }
      x0nw[n * 64 + lane] = ((d0 + d1) + (d2 + d3)) * 0.125f + b0n[lane];
    }
    for (int o = lane; o < 96; o += 64) {
      const int v = o / 3, i_ = o % 3;
      float d0 = 0.f, d1 = 0.f;
      for (int u = 0; u < 32; u += 2) {
        d0 = fmaf(sX[wv][64 + u * 3 + i_] * sG[wv][64 + u],
                  W1n[u * 32 + v], d0);
        d1 = fmaf(sX[wv][64 + (u + 1) * 3 + i_] * sG[wv][64 + u + 1],
                  W1n[(u + 1) * 32 + v], d1);
      }
      x1nw[n * 96 + o] = (d0 + d1) * INVS32;
    }
    if (lane < 32) {
      float a0 = 0.f, a1 = 0.f, b0 = 0.f, b1 = 0.f;
      for (int i = 0; i < 64; i += 2) {
        a0 = fmaf(sP0[wv][i],     L1[i * 32 + lane],         a0);
        a1 = fmaf(sP0[wv][i + 1], L1[(i + 1) * 32 + lane],   a1);
        b0 = fmaf(sP0[wv][i],     L1[(64 + i) * 32 + lane],  b0);
        b1 = fmaf(sP0[wv][i + 1], L1[(65 + i) * 32 + lane],  b1);
      }
      Aw[n * 32 + lane] = (a0 + a1) * INVS160;
      Bw[n * 32 + lane] = (b0 + b1) * INVS160;
    }
  }
}

// ---------------- fused per-edge: all-MFMA MLP + scatter ----------------
__global__ __launch_bounds__(256, 4) void fused_edge_k(
    const float* __restrict__ edge_attr,
    const float* __restrict__ edge_sh,
    const int* __restrict__ ei,
    const ushort* __restrict__ F1Tb, const ushort* __restrict__ L1cTb,
    const ushort* __restrict__ F2Tb, const ushort* __restrict__ L2Tb,
    const float* __restrict__ p1w, const float* __restrict__ Aw,
    const float* __restrict__ Bw,
    const float* __restrict__ x0nw, const float* __restrict__ x1nw,
    const int* __restrict__ order,
    float* __restrict__ o480)
{
  const int s0  = blockIdx.x * TILE;
  const int tid = threadIdx.x;

  // union region: sW (bf16 32x224, phase C/D) overlaps sEAb/sIPb/sAB (phase A/B)
  __shared__ __align__(16) char uMem[32 * 224 * 2];          // 14336 B
  ushort (*sW)[224] = (ushort (*)[224])uMem;
  ushort* sEAb = (ushort*)uMem;                  // 32x40 bf16 = 2560 B
  ushort* sIPb = (ushort*)(uMem + 2560);         // 32x40 bf16 = 2560 B
  float*  sAB  = (float*)(uMem + 5120);          // 32x36 f32  = 4608 B (ends 9728)

  __shared__ ushort sHF[32][40];    // bf16, 80B row stride
  __shared__ ushort sHL[32][40];
  __shared__ ushort sXS0[32][64];   // bf16
  __shared__ ushort sXS1[32][96];   // bf16
  __shared__ float  sSH[32][4];
  __shared__ int    sDst[32];

  const int g = tid >> 3, l = tid & 7;   // 8 threads per edge
  const int e   = order[s0 + g];
  const int dst = ei[e];
  const int src = ei[EE + e];
  if (l == 0) sDst[g] = dst;

  // ---- phase A: stage per-edge data (ea/ip as bf16 A-frags, AB f32) ----
  {
    float4 ea = *(const float4*)(edge_attr + (size_t)e * 32 + l * 4);
    *(unsigned*)&sEAb[g * 40 + l * 4 + 0] = pk(ea.x, ea.y);
    *(unsigned*)&sEAb[g * 40 + l * 4 + 2] = pk(ea.z, ea.w);
  }
  if (l == 1) *(float4*)&sSH[g][0] = *(const float4*)(edge_sh + (size_t)e * 4);
  {
    const float4* a4 = (const float4*)(x0nw + (size_t)src * 64 + l * 8);
    float4 v0 = a4[0], v1 = a4[1];
    *(unsigned*)&sXS0[g][l * 8 + 0] = pk(v0.x, v0.y);
    *(unsigned*)&sXS0[g][l * 8 + 2] = pk(v0.z, v0.w);
    *(unsigned*)&sXS0[g][l * 8 + 4] = pk(v1.x, v1.y);
    *(unsigned*)&sXS0[g][l * 8 + 6] = pk(v1.z, v1.w);
    const float4* b4 = (const float4*)(x1nw + (size_t)src * 96 + l * 12);
    float4 w0 = b4[0], w1 = b4[1], w2 = b4[2];
    *(unsigned*)&sXS1[g][l * 12 + 0]  = pk(w0.x, w0.y);
    *(unsigned*)&sXS1[g][l * 12 + 2]  = pk(w0.z, w0.w);
    *(unsigned*)&sXS1[g][l * 12 + 4]  = pk(w1.x, w1.y);
    *(unsigned*)&sXS1[g][l * 12 + 6]  = pk(w1.z, w1.w);
    *(unsigned*)&sXS1[g][l * 12 + 8]  = pk(w2.x, w2.y);
    *(unsigned*)&sXS1[g][l * 12 + 10] = pk(w2.z, w2.w);
  }
  {
    const float4* pd = (const float4*)(p1w + (size_t)dst * 96 + l * 12);
    const float4* ps = (const float4*)(p1w + (size_t)src * 96 + l * 12);
    float dp[12], sp[12];
#pragma unroll
    for (int k = 0; k < 3; ++k) {
      float4 v = pd[k]; dp[4*k] = v.x; dp[4*k+1] = v.y; dp[4*k+2] = v.z; dp[4*k+3] = v.w;
      float4 u = ps[k]; sp[4*k] = u.x; sp[4*k+1] = u.y; sp[4*k+2] = u.z; sp[4*k+3] = u.w;
    }
    float ip[4];
#pragma unroll
    for (int vv = 0; vv < 4; ++vv) {
      const int b = 3 * vv;
      ip[vv] = (dp[b] * sp[b] + dp[b+1] * sp[b+1] + dp[b+2] * sp[b+2]) * INVS3;
    }
    *(unsigned*)&sIPb[g * 40 + l * 4 + 0] = pk(ip[0], ip[1]);
    *(unsigned*)&sIPb[g * 40 + l * 4 + 2] = pk(ip[2], ip[3]);
  }
  {
    float4 av = *(const float4*)(Aw + (size_t)dst * 32 + l * 4);
    float4 bv = *(const float4*)(Bw + (size_t)src * 32 + l * 4);
    f32x4 ab;
    ab[0] = av.x + bv.x; ab[1] = av.y + bv.y;
    ab[2] = av.z + bv.z; ab[3] = av.w + bv.w;
    *(f32x4*)&sAB[g * 36 + l * 4] = ab;
  }
  __syncthreads();

  // ---- phase B (MFMA): hf = ea@F1T, hl = ip@L1cT + AB; -> sspf -> bf16 LDS ----
  {
    const int wvi  = tid >> 6;
    const int lane = tid & 63;
    const int r = lane & 15;
    const int h = lane >> 4;
    const int qt = wvi & 1;              // q-tile: edges qt*16..qt*16+15
    const bool isHL = (wvi >= 2);
    const ushort* aBase = isHL ? sIPb : sEAb;
    const ushort* bW    = isHL ? L1cTb : F1Tb;
    ushort* outB = isHL ? &sHL[0][0] : &sHF[0][0];
    bf16x8 afr = *(const bf16x8*)&aBase[(qt * 16 + r) * 40 + h * 8];
#pragma unroll
    for (int ct = 0; ct < 2; ++ct) {
      const int c = ct * 16 + r;
      bf16x8 bfr = *(const bf16x8*)&bW[c * 32 + h * 8];
      f32x4 z = {0.f, 0.f, 0.f, 0.f};
      f32x4 o = __builtin_amdgcn_mfma_f32_16x16x32_bf16(afr, bfr, z, 0, 0, 0);
#pragma unroll
      for (int i = 0; i < 4; ++i) {
        const int q = qt * 16 + h * 4 + i;
        float v = o[i];
        if (isHL) v += sAB[q * 36 + c];
        outB[q * 40 + c] = f2bf(sspf(v));
      }
    }
  }
  __syncthreads();

  // ---- phase C: MFMA w-GEMMs: [32x32]@[32x224] x2, w = Wf.*Wl (bf16 out) ----
  {
    const int wv   = tid >> 6;
    const int lane = tid & 63;
    const int r = lane & 15;   // A row / B col within tile
    const int h = lane >> 4;   // k-offset h*8
    bf16x8 aF0 = *(const bf16x8*)&sHF[r][h * 8];
    bf16x8 aF1 = *(const bf16x8*)&sHF[16 + r][h * 8];
    bf16x8 aL0 = *(const bf16x8*)&sHL[r][h * 8];
    bf16x8 aL1 = *(const bf16x8*)&sHL[16 + r][h * 8];
    const int ct0 = (wv < 2) ? wv * 4 : 8 + (wv - 2) * 3;
    const int nct = (wv < 2) ? 4 : 3;
    for (int t = 0; t < nct; ++t) {
      const int ct = ct0 + t;
      const int c  = ct * 16 + r;
      bf16x8 bF = *(const bf16x8*)&F2Tb[c * 32 + h * 8];
      bf16x8 bL = *(const bf16x8*)&L2Tb[c * 32 + h * 8];
      f32x4 z = {0.f, 0.f, 0.f, 0.f};
      f32x4 wf0 = __builtin_amdgcn_mfma_f32_16x16x32_bf16(aF0, bF, z, 0, 0, 0);
      f32x4 wl0 = __builtin_amdgcn_mfma_f32_16x16x32_bf16(aL0, bL, z, 0, 0, 0);
      f32x4 wf1 = __builtin_amdgcn_mfma_f32_16x16x32_bf16(aF1, bF, z, 0, 0, 0);
      f32x4 wl1 = __builtin_amdgcn_mfma_f32_16x16x32_bf16(aL1, bL, z, 0, 0, 0);
#pragma unroll
      for (int i = 0; i < 4; ++i) {
        sW[h * 4 + i][c]      = f2bf(wf0[i] * wl0[i]);
        sW[16 + h * 4 + i][c] = f2bf(wf1[i] * wl1[i]);
      }
    }
  }
  __syncthreads();

  // ---- phase D: walk 32 sorted edges, accumulate, flush at dst boundaries ----
  {
    auto chan = [&](int q, int k) -> float {
      if (k < 64) {
        return bf2f(sW[q][k]) * bf2f(sXS0[q][k]) * sSH[q][0];
      } else if (k < 96) {
        const int c = k - 64;
        const float d = bf2f(sXS1[q][c*3+0]) * sSH[q][1]
                      + bf2f(sXS1[q][c*3+1]) * sSH[q][2]
                      + bf2f(sXS1[q][c*3+2]) * sSH[q][3];
        return bf2f(sW[q][160 + c]) * d;
      } else if (k < 288) {
        const int kk = k - 96; const int u = kk / 3; const int i = kk - 3 * u;
        return bf2f(sW[q][64 + u]) * bf2f(sXS0[q][u]) * sSH[q][1 + i];
      } else if (k < 384) {
        const int kk = k - 288; const int u = kk / 3; const int i = kk - 3 * u;
        return bf2f(sW[q][128 + u]) * bf2f(sXS1[q][u * 3 + i]) * sSH[q][0];
      } else {
        const int kk = k - 384; const int u = kk / 3; const int i = kk - 3 * u;
        const int i1 = (i + 1) % 3, i2 = (i + 2) % 3;
        const float cr = bf2f(sXS1[q][u * 3 + i1]) * sSH[q][1 + i2]
                       - bf2f(sXS1[q][u * 3 + i2]) * sSH[q][1 + i1];
        return bf2f(sW[q][192 + u]) * cr;
      }
    };

    float acc0 = 0.f, acc1 = 0.f;
    for (int q = 0; q < TILE; ++q) {
      acc0 += chan(q, tid);
      if (tid < 224) acc1 += chan(q, tid + 256);
      const bool boundary = (q == TILE - 1) || (sDst[q + 1] != sDst[q]);
      if (boundary) {
        float* dp = o480 + (size_t)sDst[q] * 480;
        atomicAdd(dp + tid, acc0);
        if (tid < 224) atomicAdd(dp + tid + 256, acc1);
        acc0 = 0.f; acc1 = 0.f;
      }
    }
  }
}

// ---------------- final output linears (transposed weights, 4-partial dots) ----------------
__global__ __launch_bounds__(256) void out_wo_k(
    const float* __restrict__ o480,
    const float* __restrict__ WO0T, const float* __restrict__ WO1T,
    const float* __restrict__ WO2T, const float* __restrict__ bO0,
    float* __restrict__ out)
{
  const int wv = threadIdx.x >> 6, lane = threadIdx.x & 63;
  const int n = blockIdx.x * 4 + wv;
  __shared__ float sO[4][480];
  if (n < NN) {
    const float4* src = (const float4*)(o480 + (size_t)n * 480);
    for (int idx = lane; idx < 120; idx += 64)
      *(float4*)&sO[wv][idx * 4] = src[idx];
  }
  __syncthreads();
  if (n >= NN) return;
  const float* so = sO[wv];
  for (int k = lane; k < 416; k += 64) {
    float y;
    if (k < 128) {
      const float4* wr4 = (const float4*)(WO0T + k * 96);
      float a0 = 0.f, a1 = 0.f, a2 = 0.f, a3 = 0.f;
#pragma unroll
      for (int ch = 0; ch < 24; ch += 4) {
        float4 w0 = wr4[ch], w1 = wr4[ch+1], w2 = wr4[ch+2], w3 = wr4[ch+3];
        a0 = fmaf(w0.x, so[ch*4+0], fmaf(w0.y, so[ch*4+1], fmaf(w0.z, so[ch*4+2], fmaf(w0.w, so[ch*4+3], a0))));
        a1 = fmaf(w1.x, so[ch*4+4], fmaf(w1.y, so[ch*4+5], fmaf(w1.z, so[ch*4+6], fmaf(w1.w, so[ch*4+7], a1))));
        a2 = fmaf(w2.x, so[ch*4+8], fmaf(w2.y, so[ch*4+9], fmaf(w2.z, so[ch*4+10], fmaf(w2.w, so[ch*4+11], a2))));
        a3 = fmaf(w3.x, so[ch*4+12], fmaf(w3.y, so[ch*4+13], fmaf(w3.z, so[ch*4+14], fmaf(w3.w, so[ch*4+15], a3))));
      }
      y = ((a0 + a1) + (a2 + a3)) + bO0[k];
    } else if (k < 320) {
      const int kk = k - 128; const int v = kk / 3; const int i = kk - 3 * v;
      const float* wr = WO1T + v * 96;
      const float* sb = so + 96 + i;
      float a0 = 0.f, a1 = 0.f, a2 = 0.f, a3 = 0.f;
#pragma unroll
      for (int u = 0; u < 96; u += 4) {
        a0 = fmaf(wr[u],     sb[u * 3],       a0);
        a1 = fmaf(wr[u + 1], sb[(u + 1) * 3], a1);
        a2 = fmaf(wr[u + 2], sb[(u + 2) * 3], a2);
        a3 = fmaf(wr[u + 3], sb[(u + 3) * 3], a3);
      }
      y = (a0 + a1) + (a2 + a3);
    } else {
      const int kk = k - 320; const int v = kk / 3; const int i = kk - 3 * v;
      const float* wr = WO2T + v * 32;
      const float* sb = so + 384 + i;
      float a0 = 0.f, a1 = 0.f, a2 = 0.f, a3 = 0.f;
#pragma unroll
      for (int u = 0; u < 32; u += 4) {
        a0 = fmaf(wr[u],     sb[u * 3],       a0);
        a1 = fmaf(wr[u + 1], sb[(u + 1) * 3], a1);
        a2 = fmaf(wr[u + 2], sb[(u + 2) * 3], a2);
        a3 = fmaf(wr[u + 3], sb[(u + 3) * 3], a3);
      }
      y = (a0 + a1) + (a2 + a3);
    }
    out[(size_t)n * 416 + k] = y;
  }
}

// ---------------- host ----------------
extern "C" void kernel_launch(void* const* d_in, const int* in_sizes, int n_in,
                              void* d_out, int out_size, void* d_ws, size_t ws_size,
                              hipStream_t stream) {
  const float* x         = (const float*)d_in[0];
  const float* edge_sh   = (const float*)d_in[1];
  const float* edge_attr = (const float*)d_in[2];
  const float* W0p       = (const float*)d_in[3];
  const float* b0p       = (const float*)d_in[4];
  const float* W1p       = (const float*)d_in[5];
  const float* W0n       = (const float*)d_in[6];
  const float* b0n       = (const float*)d_in[7];
  const float* W1n       = (const float*)d_in[8];
  const float* G1        = (const float*)d_in[9];
  const float* g1b       = (const float*)d_in[10];
  const float* G2        = (const float*)d_in[11];
  const float* g2b       = (const float*)d_in[12];
  const float* F1        = (const float*)d_in[13];
  const float* F2        = (const float*)d_in[14];
  const float* L1        = (const float*)d_in[15];
  const float* L2        = (const float*)d_in[16];
  const float* WO0       = (const float*)d_in[17];
  const float* bO0       = (const float*)d_in[18];
  const float* WO1       = (const float*)d_in[19];
  const float* WO2       = (const float*)d_in[20];
  const int*   ei        = (const int*)d_in[21];
  float* out = (float*)d_out;

  float* p1w  = (float*)d_ws;          // N*96
  float* x0nw = p1w  + NN * 96;        // N*64
  float* x1nw = x0nw + NN * 64;        // N*96
  float* Aw   = x1nw + NN * 96;        // N*32
  float* Bw   = Aw   + NN * 32;        // N*32
  float* o480 = Bw   + NN * 32;        // N*480
  int* cnt    = (int*)(o480 + (size_t)NN * 480);
  int* cursor = cnt    + NN;
  int* order  = cursor + NN;           // E
  uintptr_t p = (uintptr_t)(order + EE);
  p = (p + 15) & ~(uintptr_t)15;
  ushort* F2Tb  = (ushort*)p;          // 224*32 bf16
  ushort* L2Tb  = F2Tb + 224 * 32;
  ushort* F1Tb  = L2Tb + 224 * 32;     // 32*32 bf16
  ushort* L1cTb = F1Tb + 32 * 32;      // 32*32 bf16
  uintptr_t p2 = (uintptr_t)(L1cTb + 32 * 32);
  p2 = (p2 + 15) & ~(uintptr_t)15;
  float* WO0T = (float*)p2;            // 128*96
  float* WO1T = WO0T + 128 * 96;       // 64*96
  float* WO2T = WO1T + 64 * 96;        // 32*32

  hipMemsetAsync(cnt, 0, NN * sizeof(int), stream);
  hipMemsetAsync(o480, 0, (size_t)NN * 480 * sizeof(float), stream);
  prep_t_k<<<(EE + 255) / 256, 256, 0, stream>>>(F2, L2, WO0, WO1, WO2, F1, L1,
                                                 ei, cnt,
                                                 F2Tb, L2Tb, WO0T, WO1T, WO2T,
                                                 F1Tb, L1cTb);
  scan_k<<<1, 1024, 0, stream>>>(cnt, cursor);
  node_prep_k<<<(NN + 3) / 4, 256, 0, stream>>>(x, W0p, b0p, W1p, W0n, b0n, W1n,
                                                G1, g1b, G2, g2b, L1,
                                                ei, cursor, order,
                                                p1w, x0nw, x1nw, Aw, Bw);
  fused_edge_k<<<EE / TILE, 256, 0, stream>>>(edge_attr, edge_sh, ei,
                                              F1Tb, L1cTb, F2Tb, L2Tb,
                                              p1w, Aw, Bw, x0nw, x1nw,
                                              order, o480);
  out_wo_k<<<(NN + 3) / 4, 256, 0, stream>>>(o480, WO0T, WO1T, WO2T, bO0, out);
}

// Round 9
// 325.559 us; speedup vs baseline: 4.7928x; 1.2726x over previous
//
#include <hip/hip_runtime.h>
#include <math.h>

#define NN 10000
#define EE 320000
#define TILE 32

constexpr float INVS32  = 0.17677669529663687f;   // 1/sqrt(32)
constexpr float INVS160 = 0.07905694150420949f;   // 1/sqrt(160)
constexpr float INVS96  = 0.10206207261596575f;   // 1/sqrt(96)
constexpr float INVS3   = 0.5773502691896258f;    // 1/sqrt(3)
constexpr float INVS2   = 0.7071067811865476f;    // 1/sqrt(2)
constexpr float LN2     = 0.6931471805599453f;

typedef short bf16x8 __attribute__((ext_vector_type(8)));
typedef float f32x4  __attribute__((ext_vector_type(4)));

__device__ __forceinline__ float sspf(float v) {
  return fmaxf(v, 0.f) + log1pf(expf(-fabsf(v))) - LN2;
}
__device__ __forceinline__ ushort f2bf(float f) {
  union { float f; unsigned u; } v; v.f = f;
  unsigned r = v.u + 0x7FFF + ((v.u >> 16) & 1);   // RNE
  return (ushort)(r >> 16);
}
__device__ __forceinline__ float bf2f(ushort u) {
  return __uint_as_float(((unsigned)u) << 16);
}
__device__ __forceinline__ unsigned pk(float a, float b) {
  return (unsigned)f2bf(a) | ((unsigned)f2bf(b) << 16);
}

// ---------------- sort-by-dst ----------------
__global__ __launch_bounds__(1024) void scan_k(const int* __restrict__ cnt,
                                               int* __restrict__ cursor) {
  __shared__ int s[1024];
  const int t = threadIdx.x;
  int loc[10];
  int sum = 0;
#pragma unroll
  for (int jj = 0; jj < 10; ++jj) {
    int idx = t * 10 + jj;
    int c = (idx < NN) ? cnt[idx] : 0;
    loc[jj] = sum;
    sum += c;
  }
  s[t] = sum;
  __syncthreads();
  for (int d = 1; d < 1024; d <<= 1) {
    int v = (t >= d) ? s[t - d] : 0;
    __syncthreads();
    s[t] += v;
    __syncthreads();
  }
  const int excl = (t > 0) ? s[t - 1] : 0;
#pragma unroll
  for (int jj = 0; jj < 10; ++jj) {
    int idx = t * 10 + jj;
    if (idx < NN) cursor[idx] = excl + loc[jj];
  }
}

// ---------------- weight transforms + fused histogram ----------------
__global__ void prep_t_k(const float* __restrict__ F2, const float* __restrict__ L2,
                         const float* __restrict__ WO0, const float* __restrict__ WO1,
                         const float* __restrict__ WO2,
                         const float* __restrict__ F1, const float* __restrict__ L1,
                         const int* __restrict__ ei, int* __restrict__ cnt,
                         ushort* __restrict__ F2Tb, ushort* __restrict__ L2Tb,
                         float* __restrict__ WO0T, float* __restrict__ WO1T,
                         float* __restrict__ WO2T,
                         ushort* __restrict__ F1Tb, ushort* __restrict__ L1cTb) {
  int i = blockIdx.x * 256 + threadIdx.x;
  if (i < EE) atomicAdd(&cnt[ei[i]], 1);
  if (i < 7168) {                         // F2T/L2T: [c][k] bf16
    int c = i >> 5, k = i & 31;
    float sc = (c < 64)  ? (1.f / 32.f)
             : (c < 128) ? (INVS3 / 32.f)
             : (c < 160) ? (1.f / 32.f)
             : (c < 192) ? (INVS3 / 32.f)
                         : (INVS2 / 32.f);
    F2Tb[i] = f2bf(F2[k * 224 + c] * sc);
    L2Tb[i] = f2bf(L2[k * 224 + c]);
  } else if (i < 7168 + 12288) {          // WO0T [128][96], scale folded
    int j = i - 7168; int k = j / 96, u = j - k * 96;
    WO0T[j] = WO0[u * 128 + k] * INVS96;
  } else if (i < 7168 + 12288 + 6144) {   // WO1T [64][96]
    int j = i - 7168 - 12288; int v = j / 96, u = j - v * 96;
    WO1T[j] = WO1[u * 64 + v] * INVS96;
  } else if (i < 7168 + 12288 + 6144 + 1024) {  // WO2T [32][32]
    int j = i - 7168 - 12288 - 6144; int v = j >> 5, u = j & 31;
    WO2T[j] = WO2[u * 32 + v] * INVS32;
  } else if (i < 26624 + 1024) {          // F1T [32n][32k] bf16, INVS32 folded
    int j = i - 26624; int n = j >> 5, k = j & 31;
    F1Tb[j] = f2bf(F1[k * 32 + n] * INVS32);
  } else if (i < 27648 + 1024) {          // L1cT [32n][32k] bf16, INVS160 folded
    int j = i - 27648; int n = j >> 5, k = j & 31;
    L1cTb[j] = f2bf(L1[(128 + k) * 32 + n] * INVS160);
  }
}

// ---------------- node precompute: 1 wave, 4 nodes, weight-reuse x4, no barriers ----------------
__global__ __launch_bounds__(64) void node_prep_k(
    const float* __restrict__ x,
    const float* __restrict__ W0p, const float* __restrict__ b0p,
    const float* __restrict__ W1p,
    const float* __restrict__ W0n, const float* __restrict__ b0n,
    const float* __restrict__ W1n,
    const float* __restrict__ G1, const float* __restrict__ g1b,
    const float* __restrict__ G2, const float* __restrict__ g2b,
    const float* __restrict__ L1,
    const int* __restrict__ ei, int* __restrict__ cursor, int* __restrict__ order,
    float* __restrict__ p1w, float* __restrict__ x0nw, float* __restrict__ x1nw,
    float* __restrict__ Aw, float* __restrict__ Bw)
{
  {  // fused scat: 2500 blocks x 64 = 160000 threads; 2 edges each
    int gid = blockIdx.x * 64 + threadIdx.x;
#pragma unroll
    for (int r = 0; r < 2; ++r) {
      int e = gid + r * 160000;
      int p = atomicAdd(&cursor[ei[e]], 1);
      order[p] = e;
    }
  }

  const int lane = threadIdx.x;
  const int nb = blockIdx.x * 4;       // 2500*4 == NN exactly

  __shared__ float sX[4][160];
  __shared__ float sP0[4][64];
  __shared__ float sF0[4][96];
  __shared__ float sH1[4][96];
  __shared__ float sG[4][96];

#pragma unroll
  for (int j = 0; j < 4; ++j) {
    const int n = nb + j;
    sX[j][lane]      = x[n * 160 + lane];
    sX[j][lane + 64] = x[n * 160 + lane + 64];
    if (lane < 32) sX[j][lane + 128] = x[n * 160 + lane + 128];
  }
  // single wave: LDS writes ordered by waitcnt; no __syncthreads needed anywhere

  // ---- p0 = x0 @ W0p/8 + b0p ; also f0 low half ----
  {
    float a0 = 0.f, a1 = 0.f, a2 = 0.f, a3 = 0.f;
    for (int i = 0; i < 64; ++i) {
      const float w = W0p[i * 64 + lane];
      a0 = fmaf(sX[0][i], w, a0); a1 = fmaf(sX[1][i], w, a1);
      a2 = fmaf(sX[2][i], w, a2); a3 = fmaf(sX[3][i], w, a3);
    }
    const float b = b0p[lane];
    sP0[0][lane] = a0 * 0.125f + b; sP0[1][lane] = a1 * 0.125f + b;
    sP0[2][lane] = a2 * 0.125f + b; sP0[3][lane] = a3 * 0.125f + b;
#pragma unroll
    for (int j = 0; j < 4; ++j) sF0[j][lane] = sX[j][lane];
  }

  // ---- p1[v,i] = sum_u x1[u,i] W1p[u,v] /sqrt(32) ----
  {
    const int o = lane; const int v = o / 3, i_ = o - 3 * v;
    float a0 = 0.f, a1 = 0.f, a2 = 0.f, a3 = 0.f;
    for (int u = 0; u < 32; ++u) {
      const float w = W1p[u * 32 + v];
      a0 = fmaf(sX[0][64 + u * 3 + i_], w, a0);
      a1 = fmaf(sX[1][64 + u * 3 + i_], w, a1);
      a2 = fmaf(sX[2][64 + u * 3 + i_], w, a2);
      a3 = fmaf(sX[3][64 + u * 3 + i_], w, a3);
    }
    p1w[(size_t)(nb + 0) * 96 + o] = a0 * INVS32;
    p1w[(size_t)(nb + 1) * 96 + o] = a1 * INVS32;
    p1w[(size_t)(nb + 2) * 96 + o] = a2 * INVS32;
    p1w[(size_t)(nb + 3) * 96 + o] = a3 * INVS32;
  }
  if (lane < 32) {
    const int o = 64 + lane; const int v = o / 3, i_ = o - 3 * v;
    float a0 = 0.f, a1 = 0.f, a2 = 0.f, a3 = 0.f;
    for (int u = 0; u < 32; ++u) {
      const float w = W1p[u * 32 + v];
      a0 = fmaf(sX[0][64 + u * 3 + i_], w, a0);
      a1 = fmaf(sX[1][64 + u * 3 + i_], w, a1);
      a2 = fmaf(sX[2][64 + u * 3 + i_], w, a2);
      a3 = fmaf(sX[3][64 + u * 3 + i_], w, a3);
    }
    p1w[(size_t)(nb + 0) * 96 + o] = a0 * INVS32;
    p1w[(size_t)(nb + 1) * 96 + o] = a1 * INVS32;
    p1w[(size_t)(nb + 2) * 96 + o] = a2 * INVS32;
    p1w[(size_t)(nb + 3) * 96 + o] = a3 * INVS32;
  }

  // ---- n1 ----
  if (lane < 32) {
#pragma unroll
    for (int j = 0; j < 4; ++j) {
      float s2 = 1e-12f;
#pragma unroll
      for (int i = 0; i < 3; ++i) { float t = sX[j][64 + lane * 3 + i]; s2 += t * t; }
      sF0[j][64 + lane] = sqrtf(s2);
    }
  }

  // ---- g1 = silu(f0 @ G1 + g1b) ----
  {
    const float b = g1b[lane];
    float a0 = b, a1 = b, a2 = b, a3 = b;
    for (int i = 0; i < 96; ++i) {
      const float w = G1[i * 96 + lane];
      a0 = fmaf(sF0[0][i], w, a0); a1 = fmaf(sF0[1][i], w, a1);
      a2 = fmaf(sF0[2][i], w, a2); a3 = fmaf(sF0[3][i], w, a3);
    }
    sH1[0][lane] = a0 / (1.f + expf(-a0));
    sH1[1][lane] = a1 / (1.f + expf(-a1));
    sH1[2][lane] = a2 / (1.f + expf(-a2));
    sH1[3][lane] = a3 / (1.f + expf(-a3));
  }
  if (lane < 32) {
    const int o = 64 + lane;
    const float b = g1b[o];
    float a0 = b, a1 = b, a2 = b, a3 = b;
    for (int i = 0; i < 96; ++i) {
      const float w = G1[i * 96 + o];
      a0 = fmaf(sF0[0][i], w, a0); a1 = fmaf(sF0[1][i], w, a1);
      a2 = fmaf(sF0[2][i], w, a2); a3 = fmaf(sF0[3][i], w, a3);
    }
    sH1[0][o] = a0 / (1.f + expf(-a0));
    sH1[1][o] = a1 / (1.f + expf(-a1));
    sH1[2][o] = a2 / (1.f + expf(-a2));
    sH1[3][o] = a3 / (1.f + expf(-a3));
  }

  // ---- g = h1 @ G2 + g2b ----
  {
    const float b = g2b[lane];
    float a0 = b, a1 = b, a2 = b, a3 = b;
    for (int i = 0; i < 96; ++i) {
      const float w = G2[i * 96 + lane];
      a0 = fmaf(sH1[0][i], w, a0); a1 = fmaf(sH1[1][i], w, a1);
      a2 = fmaf(sH1[2][i], w, a2); a3 = fmaf(sH1[3][i], w, a3);
    }
    sG[0][lane] = a0; sG[1][lane] = a1; sG[2][lane] = a2; sG[3][lane] = a3;
  }
  if (lane < 32) {
    const int o = 64 + lane;
    const float b = g2b[o];
    float a0 = b, a1 = b, a2 = b, a3 = b;
    for (int i = 0; i < 96; ++i) {
      const float w = G2[i * 96 + o];
      a0 = fmaf(sH1[0][i], w, a0); a1 = fmaf(sH1[1][i], w, a1);
      a2 = fmaf(sH1[2][i], w, a2); a3 = fmaf(sH1[3][i], w, a3);
    }
    sG[0][o] = a0; sG[1][o] = a1; sG[2][o] = a2; sG[3][o] = a3;
  }

  // ---- x0n = g[:64] @ W0n/8 + b0n ----
  {
    float a0 = 0.f, a1 = 0.f, a2 = 0.f, a3 = 0.f;
    for (int i = 0; i < 64; ++i) {
      const float w = W0n[i * 64 + lane];
      a0 = fmaf(sG[0][i], w, a0); a1 = fmaf(sG[1][i], w, a1);
      a2 = fmaf(sG[2][i], w, a2); a3 = fmaf(sG[3][i], w, a3);
    }
    const float b = b0n[lane];
    x0nw[(size_t)(nb + 0) * 64 + lane] = a0 * 0.125f + b;
    x0nw[(size_t)(nb + 1) * 64 + lane] = a1 * 0.125f + b;
    x0nw[(size_t)(nb + 2) * 64 + lane] = a2 * 0.125f + b;
    x0nw[(size_t)(nb + 3) * 64 + lane] = a3 * 0.125f + b;
  }

  // ---- x1n[v,i] = sum_u x1[u,i] g[64+u] W1n[u,v] /sqrt(32) ----
  {
    const int o = lane; const int v = o / 3, i_ = o - 3 * v;
    float a0 = 0.f, a1 = 0.f, a2 = 0.f, a3 = 0.f;
    for (int u = 0; u < 32; ++u) {
      const float w = W1n[u * 32 + v];
      a0 = fmaf(sX[0][64 + u * 3 + i_] * sG[0][64 + u], w, a0);
      a1 = fmaf(sX[1][64 + u * 3 + i_] * sG[1][64 + u], w, a1);
      a2 = fmaf(sX[2][64 + u * 3 + i_] * sG[2][64 + u], w, a2);
      a3 = fmaf(sX[3][64 + u * 3 + i_] * sG[3][64 + u], w, a3);
    }
    x1nw[(size_t)(nb + 0) * 96 + o] = a0 * INVS32;
    x1nw[(size_t)(nb + 1) * 96 + o] = a1 * INVS32;
    x1nw[(size_t)(nb + 2) * 96 + o] = a2 * INVS32;
    x1nw[(size_t)(nb + 3) * 96 + o] = a3 * INVS32;
  }
  if (lane < 32) {
    const int o = 64 + lane; const int v = o / 3, i_ = o - 3 * v;
    float a0 = 0.f, a1 = 0.f, a2 = 0.f, a3 = 0.f;
    for (int u = 0; u < 32; ++u) {
      const float w = W1n[u * 32 + v];
      a0 = fmaf(sX[0][64 + u * 3 + i_] * sG[0][64 + u], w, a0);
      a1 = fmaf(sX[1][64 + u * 3 + i_] * sG[1][64 + u], w, a1);
      a2 = fmaf(sX[2][64 + u * 3 + i_] * sG[2][64 + u], w, a2);
      a3 = fmaf(sX[3][64 + u * 3 + i_] * sG[3][64 + u], w, a3);
    }
    x1nw[(size_t)(nb + 0) * 96 + o] = a0 * INVS32;
    x1nw[(size_t)(nb + 1) * 96 + o] = a1 * INVS32;
    x1nw[(size_t)(nb + 2) * 96 + o] = a2 * INVS32;
    x1nw[(size_t)(nb + 3) * 96 + o] = a3 * INVS32;
  }

  // ---- A = p0 @ L1[0:64]/sqrt160 ; B = p0 @ L1[64:128]/sqrt160 ----
  if (lane < 32) {
    float a0 = 0.f, a1 = 0.f, a2 = 0.f, a3 = 0.f;
    float c0 = 0.f, c1 = 0.f, c2 = 0.f, c3 = 0.f;
    for (int i = 0; i < 64; ++i) {
      const float wa = L1[i * 32 + lane];
      const float wb = L1[(64 + i) * 32 + lane];
      a0 = fmaf(sP0[0][i], wa, a0); a1 = fmaf(sP0[1][i], wa, a1);
      a2 = fmaf(sP0[2][i], wa, a2); a3 = fmaf(sP0[3][i], wa, a3);
      c0 = fmaf(sP0[0][i], wb, c0); c1 = fmaf(sP0[1][i], wb, c1);
      c2 = fmaf(sP0[2][i], wb, c2); c3 = fmaf(sP0[3][i], wb, c3);
    }
    Aw[(size_t)(nb + 0) * 32 + lane] = a0 * INVS160;
    Aw[(size_t)(nb + 1) * 32 + lane] = a1 * INVS160;
    Aw[(size_t)(nb + 2) * 32 + lane] = a2 * INVS160;
    Aw[(size_t)(nb + 3) * 32 + lane] = a3 * INVS160;
    Bw[(size_t)(nb + 0) * 32 + lane] = c0 * INVS160;
    Bw[(size_t)(nb + 1) * 32 + lane] = c1 * INVS160;
    Bw[(size_t)(nb + 2) * 32 + lane] = c2 * INVS160;
    Bw[(size_t)(nb + 3) * 32 + lane] = c3 * INVS160;
  }
}

// ---------------- fused per-edge: all-MFMA MLP + scatter (unchanged from R8) ----------------
__global__ __launch_bounds__(256, 4) void fused_edge_k(
    const float* __restrict__ edge_attr,
    const float* __restrict__ edge_sh,
    const int* __restrict__ ei,
    const ushort* __restrict__ F1Tb, const ushort* __restrict__ L1cTb,
    const ushort* __restrict__ F2Tb, const ushort* __restrict__ L2Tb,
    const float* __restrict__ p1w, const float* __restrict__ Aw,
    const float* __restrict__ Bw,
    const float* __restrict__ x0nw, const float* __restrict__ x1nw,
    const int* __restrict__ order,
    float* __restrict__ o480)
{
  const int s0  = blockIdx.x * TILE;
  const int tid = threadIdx.x;

  __shared__ __align__(16) char uMem[32 * 224 * 2];          // 14336 B
  ushort (*sW)[224] = (ushort (*)[224])uMem;
  ushort* sEAb = (ushort*)uMem;                  // 32x40 bf16
  ushort* sIPb = (ushort*)(uMem + 2560);         // 32x40 bf16
  float*  sAB  = (float*)(uMem + 5120);          // 32x36 f32

  __shared__ ushort sHF[32][40];
  __shared__ ushort sHL[32][40];
  __shared__ ushort sXS0[32][64];
  __shared__ ushort sXS1[32][96];
  __shared__ float  sSH[32][4];
  __shared__ int    sDst[32];

  const int g = tid >> 3, l = tid & 7;
  const int e   = order[s0 + g];
  const int dst = ei[e];
  const int src = ei[EE + e];
  if (l == 0) sDst[g] = dst;

  // ---- phase A ----
  {
    float4 ea = *(const float4*)(edge_attr + (size_t)e * 32 + l * 4);
    *(unsigned*)&sEAb[g * 40 + l * 4 + 0] = pk(ea.x, ea.y);
    *(unsigned*)&sEAb[g * 40 + l * 4 + 2] = pk(ea.z, ea.w);
  }
  if (l == 1) *(float4*)&sSH[g][0] = *(const float4*)(edge_sh + (size_t)e * 4);
  {
    const float4* a4 = (const float4*)(x0nw + (size_t)src * 64 + l * 8);
    float4 v0 = a4[0], v1 = a4[1];
    *(unsigned*)&sXS0[g][l * 8 + 0] = pk(v0.x, v0.y);
    *(unsigned*)&sXS0[g][l * 8 + 2] = pk(v0.z, v0.w);
    *(unsigned*)&sXS0[g][l * 8 + 4] = pk(v1.x, v1.y);
    *(unsigned*)&sXS0[g][l * 8 + 6] = pk(v1.z, v1.w);
    const float4* b4 = (const float4*)(x1nw + (size_t)src * 96 + l * 12);
    float4 w0 = b4[0], w1 = b4[1], w2 = b4[2];
    *(unsigned*)&sXS1[g][l * 12 + 0]  = pk(w0.x, w0.y);
    *(unsigned*)&sXS1[g][l * 12 + 2]  = pk(w0.z, w0.w);
    *(unsigned*)&sXS1[g][l * 12 + 4]  = pk(w1.x, w1.y);
    *(unsigned*)&sXS1[g][l * 12 + 6]  = pk(w1.z, w1.w);
    *(unsigned*)&sXS1[g][l * 12 + 8]  = pk(w2.x, w2.y);
    *(unsigned*)&sXS1[g][l * 12 + 10] = pk(w2.z, w2.w);
  }
  {
    const float4* pd = (const float4*)(p1w + (size_t)dst * 96 + l * 12);
    const float4* ps = (const float4*)(p1w + (size_t)src * 96 + l * 12);
    float dp[12], sp[12];
#pragma unroll
    for (int k = 0; k < 3; ++k) {
      float4 v = pd[k]; dp[4*k] = v.x; dp[4*k+1] = v.y; dp[4*k+2] = v.z; dp[4*k+3] = v.w;
      float4 u = ps[k]; sp[4*k] = u.x; sp[4*k+1] = u.y; sp[4*k+2] = u.z; sp[4*k+3] = u.w;
    }
    float ip[4];
#pragma unroll
    for (int vv = 0; vv < 4; ++vv) {
      const int b = 3 * vv;
      ip[vv] = (dp[b] * sp[b] + dp[b+1] * sp[b+1] + dp[b+2] * sp[b+2]) * INVS3;
    }
    *(unsigned*)&sIPb[g * 40 + l * 4 + 0] = pk(ip[0], ip[1]);
    *(unsigned*)&sIPb[g * 40 + l * 4 + 2] = pk(ip[2], ip[3]);
  }
  {
    float4 av = *(const float4*)(Aw + (size_t)dst * 32 + l * 4);
    float4 bv = *(const float4*)(Bw + (size_t)src * 32 + l * 4);
    f32x4 ab;
    ab[0] = av.x + bv.x; ab[1] = av.y + bv.y;
    ab[2] = av.z + bv.z; ab[3] = av.w + bv.w;
    *(f32x4*)&sAB[g * 36 + l * 4] = ab;
  }
  __syncthreads();

  // ---- phase B (MFMA) ----
  {
    const int wvi  = tid >> 6;
    const int lane = tid & 63;
    const int r = lane & 15;
    const int h = lane >> 4;
    const int qt = wvi & 1;
    const bool isHL = (wvi >= 2);
    const ushort* aBase = isHL ? sIPb : sEAb;
    const ushort* bW    = isHL ? L1cTb : F1Tb;
    ushort* outB = isHL ? &sHL[0][0] : &sHF[0][0];
    bf16x8 afr = *(const bf16x8*)&aBase[(qt * 16 + r) * 40 + h * 8];
#pragma unroll
    for (int ct = 0; ct < 2; ++ct) {
      const int c = ct * 16 + r;
      bf16x8 bfr = *(const bf16x8*)&bW[c * 32 + h * 8];
      f32x4 z = {0.f, 0.f, 0.f, 0.f};
      f32x4 o = __builtin_amdgcn_mfma_f32_16x16x32_bf16(afr, bfr, z, 0, 0, 0);
#pragma unroll
      for (int i = 0; i < 4; ++i) {
        const int q = qt * 16 + h * 4 + i;
        float v = o[i];
        if (isHL) v += sAB[q * 36 + c];
        outB[q * 40 + c] = f2bf(sspf(v));
      }
    }
  }
  __syncthreads();

  // ---- phase C: MFMA w-GEMMs ----
  {
    const int wv   = tid >> 6;
    const int lane = tid & 63;
    const int r = lane & 15;
    const int h = lane >> 4;
    bf16x8 aF0 = *(const bf16x8*)&sHF[r][h * 8];
    bf16x8 aF1 = *(const bf16x8*)&sHF[16 + r][h * 8];
    bf16x8 aL0 = *(const bf16x8*)&sHL[r][h * 8];
    bf16x8 aL1 = *(const bf16x8*)&sHL[16 + r][h * 8];
    const int ct0 = (wv < 2) ? wv * 4 : 8 + (wv - 2) * 3;
    const int nct = (wv < 2) ? 4 : 3;
    for (int t = 0; t < nct; ++t) {
      const int ct = ct0 + t;
      const int c  = ct * 16 + r;
      bf16x8 bF = *(const bf16x8*)&F2Tb[c * 32 + h * 8];
      bf16x8 bL = *(const bf16x8*)&L2Tb[c * 32 + h * 8];
      f32x4 z = {0.f, 0.f, 0.f, 0.f};
      f32x4 wf0 = __builtin_amdgcn_mfma_f32_16x16x32_bf16(aF0, bF, z, 0, 0, 0);
      f32x4 wl0 = __builtin_amdgcn_mfma_f32_16x16x32_bf16(aL0, bL, z, 0, 0, 0);
      f32x4 wf1 = __builtin_amdgcn_mfma_f32_16x16x32_bf16(aF1, bF, z, 0, 0, 0);
      f32x4 wl1 = __builtin_amdgcn_mfma_f32_16x16x32_bf16(aL1, bL, z, 0, 0, 0);
#pragma unroll
      for (int i = 0; i < 4; ++i) {
        sW[h * 4 + i][c]      = f2bf(wf0[i] * wl0[i]);
        sW[16 + h * 4 + i][c] = f2bf(wf1[i] * wl1[i]);
      }
    }
  }
  __syncthreads();

  // ---- phase D ----
  {
    auto chan = [&](int q, int k) -> float {
      if (k < 64) {
        return bf2f(sW[q][k]) * bf2f(sXS0[q][k]) * sSH[q][0];
      } else if (k < 96) {
        const int c = k - 64;
        const float d = bf2f(sXS1[q][c*3+0]) * sSH[q][1]
                      + bf2f(sXS1[q][c*3+1]) * sSH[q][2]
                      + bf2f(sXS1[q][c*3+2]) * sSH[q][3];
        return bf2f(sW[q][160 + c]) * d;
      } else if (k < 288) {
        const int kk = k - 96; const int u = kk / 3; const int i = kk - 3 * u;
        return bf2f(sW[q][64 + u]) * bf2f(sXS0[q][u]) * sSH[q][1 + i];
      } else if (k < 384) {
        const int kk = k - 288; const int u = kk / 3; const int i = kk - 3 * u;
        return bf2f(sW[q][128 + u]) * bf2f(sXS1[q][u * 3 + i]) * sSH[q][0];
      } else {
        const int kk = k - 384; const int u = kk / 3; const int i = kk - 3 * u;
        const int i1 = (i + 1) % 3, i2 = (i + 2) % 3;
        const float cr = bf2f(sXS1[q][u * 3 + i1]) * sSH[q][1 + i2]
                       - bf2f(sXS1[q][u * 3 + i2]) * sSH[q][1 + i1];
        return bf2f(sW[q][192 + u]) * cr;
      }
    };

    float acc0 = 0.f, acc1 = 0.f;
    for (int q = 0; q < TILE; ++q) {
      acc0 += chan(q, tid);
      if (tid < 224) acc1 += chan(q, tid + 256);
      const bool boundary = (q == TILE - 1) || (sDst[q + 1] != sDst[q]);
      if (boundary) {
        float* dp = o480 + (size_t)sDst[q] * 480;
        atomicAdd(dp + tid, acc0);
        if (tid < 224) atomicAdd(dp + tid + 256, acc1);
        acc0 = 0.f; acc1 = 0.f;
      }
    }
  }
}

// ---------------- output linears: 1 wave, 4 nodes, weight-reuse x4 ----------------
__global__ __launch_bounds__(64) void out_wo_k(
    const float* __restrict__ o480,
    const float* __restrict__ WO0T, const float* __restrict__ WO1T,
    const float* __restrict__ WO2T, const float* __restrict__ bO0,
    float* __restrict__ out)
{
  const int lane = threadIdx.x;
  const int nb = blockIdx.x * 4;
  __shared__ float sO[4][480];
#pragma unroll
  for (int j = 0; j < 4; ++j) {
    const float4* src = (const float4*)(o480 + (size_t)(nb + j) * 480);
    for (int idx = lane; idx < 120; idx += 64)
      *(float4*)&sO[j][idx * 4] = src[idx];
  }
  // single wave: no barrier needed

  for (int k = lane; k < 416; k += 64) {
    float y0, y1, y2, y3;
    if (k < 128) {
      const float* wr = WO0T + k * 96;
      float a0 = 0.f, a1 = 0.f, a2 = 0.f, a3 = 0.f;
      for (int u = 0; u < 96; ++u) {
        const float w = wr[u];
        a0 = fmaf(w, sO[0][u], a0); a1 = fmaf(w, sO[1][u], a1);
        a2 = fmaf(w, sO[2][u], a2); a3 = fmaf(w, sO[3][u], a3);
      }
      const float b = bO0[k];
      y0 = a0 + b; y1 = a1 + b; y2 = a2 + b; y3 = a3 + b;
    } else if (k < 320) {
      const int kk = k - 128; const int v = kk / 3; const int i = kk - 3 * v;
      const float* wr = WO1T + v * 96;
      float a0 = 0.f, a1 = 0.f, a2 = 0.f, a3 = 0.f;
      for (int u = 0; u < 96; ++u) {
        const float w = wr[u];
        a0 = fmaf(w, sO[0][96 + u * 3 + i], a0);
        a1 = fmaf(w, sO[1][96 + u * 3 + i], a1);
        a2 = fmaf(w, sO[2][96 + u * 3 + i], a2);
        a3 = fmaf(w, sO[3][96 + u * 3 + i], a3);
      }
      y0 = a0; y1 = a1; y2 = a2; y3 = a3;
    } else {
      const int kk = k - 320; const int v = kk / 3; const int i = kk - 3 * v;
      const float* wr = WO2T + v * 32;
      float a0 = 0.f, a1 = 0.f, a2 = 0.f, a3 = 0.f;
      for (int u = 0; u < 32; ++u) {
        const float w = wr[u];
        a0 = fmaf(w, sO[0][384 + u * 3 + i], a0);
        a1 = fmaf(w, sO[1][384 + u * 3 + i], a1);
        a2 = fmaf(w, sO[2][384 + u * 3 + i], a2);
        a3 = fmaf(w, sO[3][384 + u * 3 + i], a3);
      }
      y0 = a0; y1 = a1; y2 = a2; y3 = a3;
    }
    out[(size_t)(nb + 0) * 416 + k] = y0;
    out[(size_t)(nb + 1) * 416 + k] = y1;
    out[(size_t)(nb + 2) * 416 + k] = y2;
    out[(size_t)(nb + 3) * 416 + k] = y3;
  }
}

// ---------------- host ----------------
extern "C" void kernel_launch(void* const* d_in, const int* in_sizes, int n_in,
                              void* d_out, int out_size, void* d_ws, size_t ws_size,
                              hipStream_t stream) {
  const float* x         = (const float*)d_in[0];
  const float* edge_sh   = (const float*)d_in[1];
  const float* edge_attr = (const float*)d_in[2];
  const float* W0p       = (const float*)d_in[3];
  const float* b0p       = (const float*)d_in[4];
  const float* W1p       = (const float*)d_in[5];
  const float* W0n       = (const float*)d_in[6];
  const float* b0n       = (const float*)d_in[7];
  const float* W1n       = (const float*)d_in[8];
  const float* G1        = (const float*)d_in[9];
  const float* g1b       = (const float*)d_in[10];
  const float* G2        = (const float*)d_in[11];
  const float* g2b       = (const float*)d_in[12];
  const float* F1        = (const float*)d_in[13];
  const float* F2        = (const float*)d_in[14];
  const float* L1        = (const float*)d_in[15];
  const float* L2        = (const float*)d_in[16];
  const float* WO0       = (const float*)d_in[17];
  const float* bO0       = (const float*)d_in[18];
  const float* WO1       = (const float*)d_in[19];
  const float* WO2       = (const float*)d_in[20];
  const int*   ei        = (const int*)d_in[21];
  float* out = (float*)d_out;

  float* p1w  = (float*)d_ws;          // N*96
  float* x0nw = p1w  + NN * 96;        // N*64
  float* x1nw = x0nw + NN * 64;        // N*96
  float* Aw   = x1nw + NN * 96;        // N*32
  float* Bw   = Aw   + NN * 32;        // N*32
  float* o480 = Bw   + NN * 32;        // N*480
  int* cnt    = (int*)(o480 + (size_t)NN * 480);
  int* cursor = cnt    + NN;
  int* order  = cursor + NN;           // E
  uintptr_t p = (uintptr_t)(order + EE);
  p = (p + 15) & ~(uintptr_t)15;
  ushort* F2Tb  = (ushort*)p;          // 224*32 bf16
  ushort* L2Tb  = F2Tb + 224 * 32;
  ushort* F1Tb  = L2Tb + 224 * 32;     // 32*32 bf16
  ushort* L1cTb = F1Tb + 32 * 32;      // 32*32 bf16
  uintptr_t p2 = (uintptr_t)(L1cTb + 32 * 32);
  p2 = (p2 + 15) & ~(uintptr_t)15;
  float* WO0T = (float*)p2;            // 128*96
  float* WO1T = WO0T + 128 * 96;       // 64*96
  float* WO2T = WO1T + 64 * 96;        // 32*32

  hipMemsetAsync(cnt, 0, NN * sizeof(int), stream);
  hipMemsetAsync(o480, 0, (size_t)NN * 480 * sizeof(float), stream);
  prep_t_k<<<(EE + 255) / 256, 256, 0, stream>>>(F2, L2, WO0, WO1, WO2, F1, L1,
                                                 ei, cnt,
                                                 F2Tb, L2Tb, WO0T, WO1T, WO2T,
                                                 F1Tb, L1cTb);
  scan_k<<<1, 1024, 0, stream>>>(cnt, cursor);
  node_prep_k<<<NN / 4, 64, 0, stream>>>(x, W0p, b0p, W1p, W0n, b0n, W1n,
                                         G1, g1b, G2, g2b, L1,
                                         ei, cursor, order,
                                         p1w, x0nw, x1nw, Aw, Bw);
  fused_edge_k<<<EE / TILE, 256, 0, stream>>>(edge_attr, edge_sh, ei,
                                              F1Tb, L1cTb, F2Tb, L2Tb,
                                              p1w, Aw, Bw, x0nw, x1nw,
                                              order, o480);
  out_wo_k<<<NN / 4, 64, 0, stream>>>(o480, WO0T, WO1T, WO2T, bO0, out);
}

// Round 10
// 324.073 us; speedup vs baseline: 4.8148x; 1.0046x over previous
//
#include <hip/hip_runtime.h>
#include <math.h>

#define NN 10000
#define EE 320000
#define TILE 32

constexpr float INVS32  = 0.17677669529663687f;   // 1/sqrt(32)
constexpr float INVS160 = 0.07905694150420949f;   // 1/sqrt(160)
constexpr float INVS96  = 0.10206207261596575f;   // 1/sqrt(96)
constexpr float INVS3   = 0.5773502691896258f;    // 1/sqrt(3)
constexpr float INVS2   = 0.7071067811865476f;    // 1/sqrt(2)
constexpr float LN2     = 0.6931471805599453f;

typedef short bf16x8 __attribute__((ext_vector_type(8)));
typedef float f32x4  __attribute__((ext_vector_type(4)));

__device__ __forceinline__ float sspf(float v) {
  // softplus(v)-ln2 = max(v,0) + log(1+exp(-|v|)) - ln2, hw transcendentals
  return fmaxf(v, 0.f) + __logf(1.f + __expf(-fabsf(v))) - LN2;
}
__device__ __forceinline__ ushort f2bf(float f) {
  union { float f; unsigned u; } v; v.f = f;
  unsigned r = v.u + 0x7FFF + ((v.u >> 16) & 1);   // RNE
  return (ushort)(r >> 16);
}
__device__ __forceinline__ float bf2f(ushort u) {
  return __uint_as_float(((unsigned)u) << 16);
}
__device__ __forceinline__ unsigned pk(float a, float b) {
  return (unsigned)f2bf(a) | ((unsigned)f2bf(b) << 16);
}

// ---------------- sort-by-dst ----------------
__global__ __launch_bounds__(1024) void scan_k(const int* __restrict__ cnt,
                                               int* __restrict__ cursor) {
  __shared__ int s[1024];
  const int t = threadIdx.x;
  int loc[10];
  int sum = 0;
#pragma unroll
  for (int jj = 0; jj < 10; ++jj) {
    int idx = t * 10 + jj;
    int c = (idx < NN) ? cnt[idx] : 0;
    loc[jj] = sum;
    sum += c;
  }
  s[t] = sum;
  __syncthreads();
  for (int d = 1; d < 1024; d <<= 1) {
    int v = (t >= d) ? s[t - d] : 0;
    __syncthreads();
    s[t] += v;
    __syncthreads();
  }
  const int excl = (t > 0) ? s[t - 1] : 0;
#pragma unroll
  for (int jj = 0; jj < 10; ++jj) {
    int idx = t * 10 + jj;
    if (idx < NN) cursor[idx] = excl + loc[jj];
  }
}

// ---------------- weight transforms + fused histogram ----------------
__global__ void prep_t_k(const float* __restrict__ F2, const float* __restrict__ L2,
                         const float* __restrict__ WO0, const float* __restrict__ WO1,
                         const float* __restrict__ WO2,
                         const float* __restrict__ F1, const float* __restrict__ L1,
                         const int* __restrict__ ei, int* __restrict__ cnt,
                         ushort* __restrict__ F2Tb, ushort* __restrict__ L2Tb,
                         float* __restrict__ WO0T, float* __restrict__ WO1T,
                         float* __restrict__ WO2T,
                         ushort* __restrict__ F1Tb, ushort* __restrict__ L1cTb) {
  int i = blockIdx.x * 256 + threadIdx.x;
  if (i < EE) atomicAdd(&cnt[ei[i]], 1);
  if (i < 7168) {                         // F2T/L2T: [c][k] bf16
    int c = i >> 5, k = i & 31;
    float sc = (c < 64)  ? (1.f / 32.f)
             : (c < 128) ? (INVS3 / 32.f)
             : (c < 160) ? (1.f / 32.f)
             : (c < 192) ? (INVS3 / 32.f)
                         : (INVS2 / 32.f);
    F2Tb[i] = f2bf(F2[k * 224 + c] * sc);
    L2Tb[i] = f2bf(L2[k * 224 + c]);
  } else if (i < 7168 + 12288) {          // WO0T [128][96], scale folded
    int j = i - 7168; int k = j / 96, u = j - k * 96;
    WO0T[j] = WO0[u * 128 + k] * INVS96;
  } else if (i < 7168 + 12288 + 6144) {   // WO1T [64][96]
    int j = i - 7168 - 12288; int v = j / 96, u = j - v * 96;
    WO1T[j] = WO1[u * 64 + v] * INVS96;
  } else if (i < 7168 + 12288 + 6144 + 1024) {  // WO2T [32][32]
    int j = i - 7168 - 12288 - 6144; int v = j >> 5, u = j & 31;
    WO2T[j] = WO2[u * 32 + v] * INVS32;
  } else if (i < 26624 + 1024) {          // F1T [32n][32k] bf16, INVS32 folded
    int j = i - 26624; int n = j >> 5, k = j & 31;
    F1Tb[j] = f2bf(F1[k * 32 + n] * INVS32);
  } else if (i < 27648 + 1024) {          // L1cT [32n][32k] bf16, INVS160 folded
    int j = i - 27648; int n = j >> 5, k = j & 31;
    L1cTb[j] = f2bf(L1[(128 + k) * 32 + n] * INVS160);
  }
}

// ---------------- node precompute: 1 wave, 4 nodes, weight-reuse x4, no barriers ----------------
__global__ __launch_bounds__(64) void node_prep_k(
    const float* __restrict__ x,
    const float* __restrict__ W0p, const float* __restrict__ b0p,
    const float* __restrict__ W1p,
    const float* __restrict__ W0n, const float* __restrict__ b0n,
    const float* __restrict__ W1n,
    const float* __restrict__ G1, const float* __restrict__ g1b,
    const float* __restrict__ G2, const float* __restrict__ g2b,
    const float* __restrict__ L1,
    const int* __restrict__ ei, int* __restrict__ cursor, int* __restrict__ order,
    float* __restrict__ p1w, ushort* __restrict__ x0nb, ushort* __restrict__ x1nb,
    float* __restrict__ Aw, float* __restrict__ Bw)
{
  {  // fused scat: 2500 blocks x 64 = 160000 threads; 2 edges each
    int gid = blockIdx.x * 64 + threadIdx.x;
#pragma unroll
    for (int r = 0; r < 2; ++r) {
      int e = gid + r * 160000;
      int p = atomicAdd(&cursor[ei[e]], 1);
      order[p] = e;
    }
  }

  const int lane = threadIdx.x;
  const int nb = blockIdx.x * 4;       // 2500*4 == NN exactly

  __shared__ float sX[4][160];
  __shared__ float sP0[4][64];
  __shared__ float sF0[4][96];
  __shared__ float sH1[4][96];
  __shared__ float sG[4][96];

#pragma unroll
  for (int j = 0; j < 4; ++j) {
    const int n = nb + j;
    sX[j][lane]      = x[n * 160 + lane];
    sX[j][lane + 64] = x[n * 160 + lane + 64];
    if (lane < 32) sX[j][lane + 128] = x[n * 160 + lane + 128];
  }
  // single wave: no __syncthreads needed anywhere

  // ---- p0 = x0 @ W0p/8 + b0p ----
  {
    float a0 = 0.f, a1 = 0.f, a2 = 0.f, a3 = 0.f;
    for (int i = 0; i < 64; ++i) {
      const float w = W0p[i * 64 + lane];
      a0 = fmaf(sX[0][i], w, a0); a1 = fmaf(sX[1][i], w, a1);
      a2 = fmaf(sX[2][i], w, a2); a3 = fmaf(sX[3][i], w, a3);
    }
    const float b = b0p[lane];
    sP0[0][lane] = a0 * 0.125f + b; sP0[1][lane] = a1 * 0.125f + b;
    sP0[2][lane] = a2 * 0.125f + b; sP0[3][lane] = a3 * 0.125f + b;
#pragma unroll
    for (int j = 0; j < 4; ++j) sF0[j][lane] = sX[j][lane];
  }

  // ---- p1[v,i] ----
  {
    const int o = lane; const int v = o / 3, i_ = o - 3 * v;
    float a0 = 0.f, a1 = 0.f, a2 = 0.f, a3 = 0.f;
    for (int u = 0; u < 32; ++u) {
      const float w = W1p[u * 32 + v];
      a0 = fmaf(sX[0][64 + u * 3 + i_], w, a0);
      a1 = fmaf(sX[1][64 + u * 3 + i_], w, a1);
      a2 = fmaf(sX[2][64 + u * 3 + i_], w, a2);
      a3 = fmaf(sX[3][64 + u * 3 + i_], w, a3);
    }
    p1w[(size_t)(nb + 0) * 96 + o] = a0 * INVS32;
    p1w[(size_t)(nb + 1) * 96 + o] = a1 * INVS32;
    p1w[(size_t)(nb + 2) * 96 + o] = a2 * INVS32;
    p1w[(size_t)(nb + 3) * 96 + o] = a3 * INVS32;
  }
  if (lane < 32) {
    const int o = 64 + lane; const int v = o / 3, i_ = o - 3 * v;
    float a0 = 0.f, a1 = 0.f, a2 = 0.f, a3 = 0.f;
    for (int u = 0; u < 32; ++u) {
      const float w = W1p[u * 32 + v];
      a0 = fmaf(sX[0][64 + u * 3 + i_], w, a0);
      a1 = fmaf(sX[1][64 + u * 3 + i_], w, a1);
      a2 = fmaf(sX[2][64 + u * 3 + i_], w, a2);
      a3 = fmaf(sX[3][64 + u * 3 + i_], w, a3);
    }
    p1w[(size_t)(nb + 0) * 96 + o] = a0 * INVS32;
    p1w[(size_t)(nb + 1) * 96 + o] = a1 * INVS32;
    p1w[(size_t)(nb + 2) * 96 + o] = a2 * INVS32;
    p1w[(size_t)(nb + 3) * 96 + o] = a3 * INVS32;
  }

  // ---- n1 ----
  if (lane < 32) {
#pragma unroll
    for (int j = 0; j < 4; ++j) {
      float s2 = 1e-12f;
#pragma unroll
      for (int i = 0; i < 3; ++i) { float t = sX[j][64 + lane * 3 + i]; s2 += t * t; }
      sF0[j][64 + lane] = sqrtf(s2);
    }
  }

  // ---- g1 = silu(f0 @ G1 + g1b) ----
  {
    const float b = g1b[lane];
    float a0 = b, a1 = b, a2 = b, a3 = b;
    for (int i = 0; i < 96; ++i) {
      const float w = G1[i * 96 + lane];
      a0 = fmaf(sF0[0][i], w, a0); a1 = fmaf(sF0[1][i], w, a1);
      a2 = fmaf(sF0[2][i], w, a2); a3 = fmaf(sF0[3][i], w, a3);
    }
    sH1[0][lane] = a0 / (1.f + __expf(-a0));
    sH1[1][lane] = a1 / (1.f + __expf(-a1));
    sH1[2][lane] = a2 / (1.f + __expf(-a2));
    sH1[3][lane] = a3 / (1.f + __expf(-a3));
  }
  if (lane < 32) {
    const int o = 64 + lane;
    const float b = g1b[o];
    float a0 = b, a1 = b, a2 = b, a3 = b;
    for (int i = 0; i < 96; ++i) {
      const float w = G1[i * 96 + o];
      a0 = fmaf(sF0[0][i], w, a0); a1 = fmaf(sF0[1][i], w, a1);
      a2 = fmaf(sF0[2][i], w, a2); a3 = fmaf(sF0[3][i], w, a3);
    }
    sH1[0][o] = a0 / (1.f + __expf(-a0));
    sH1[1][o] = a1 / (1.f + __expf(-a1));
    sH1[2][o] = a2 / (1.f + __expf(-a2));
    sH1[3][o] = a3 / (1.f + __expf(-a3));
  }

  // ---- g = h1 @ G2 + g2b ----
  {
    const float b = g2b[lane];
    float a0 = b, a1 = b, a2 = b, a3 = b;
    for (int i = 0; i < 96; ++i) {
      const float w = G2[i * 96 + lane];
      a0 = fmaf(sH1[0][i], w, a0); a1 = fmaf(sH1[1][i], w, a1);
      a2 = fmaf(sH1[2][i], w, a2); a3 = fmaf(sH1[3][i], w, a3);
    }
    sG[0][lane] = a0; sG[1][lane] = a1; sG[2][lane] = a2; sG[3][lane] = a3;
  }
  if (lane < 32) {
    const int o = 64 + lane;
    const float b = g2b[o];
    float a0 = b, a1 = b, a2 = b, a3 = b;
    for (int i = 0; i < 96; ++i) {
      const float w = G2[i * 96 + o];
      a0 = fmaf(sH1[0][i], w, a0); a1 = fmaf(sH1[1][i], w, a1);
      a2 = fmaf(sH1[2][i], w, a2); a3 = fmaf(sH1[3][i], w, a3);
    }
    sG[0][o] = a0; sG[1][o] = a1; sG[2][o] = a2; sG[3][o] = a3;
  }

  // ---- x0n (bf16 out) ----
  {
    float a0 = 0.f, a1 = 0.f, a2 = 0.f, a3 = 0.f;
    for (int i = 0; i < 64; ++i) {
      const float w = W0n[i * 64 + lane];
      a0 = fmaf(sG[0][i], w, a0); a1 = fmaf(sG[1][i], w, a1);
      a2 = fmaf(sG[2][i], w, a2); a3 = fmaf(sG[3][i], w, a3);
    }
    const float b = b0n[lane];
    x0nb[(size_t)(nb + 0) * 64 + lane] = f2bf(a0 * 0.125f + b);
    x0nb[(size_t)(nb + 1) * 64 + lane] = f2bf(a1 * 0.125f + b);
    x0nb[(size_t)(nb + 2) * 64 + lane] = f2bf(a2 * 0.125f + b);
    x0nb[(size_t)(nb + 3) * 64 + lane] = f2bf(a3 * 0.125f + b);
  }

  // ---- x1n (bf16 out) ----
  {
    const int o = lane; const int v = o / 3, i_ = o - 3 * v;
    float a0 = 0.f, a1 = 0.f, a2 = 0.f, a3 = 0.f;
    for (int u = 0; u < 32; ++u) {
      const float w = W1n[u * 32 + v];
      a0 = fmaf(sX[0][64 + u * 3 + i_] * sG[0][64 + u], w, a0);
      a1 = fmaf(sX[1][64 + u * 3 + i_] * sG[1][64 + u], w, a1);
      a2 = fmaf(sX[2][64 + u * 3 + i_] * sG[2][64 + u], w, a2);
      a3 = fmaf(sX[3][64 + u * 3 + i_] * sG[3][64 + u], w, a3);
    }
    x1nb[(size_t)(nb + 0) * 96 + o] = f2bf(a0 * INVS32);
    x1nb[(size_t)(nb + 1) * 96 + o] = f2bf(a1 * INVS32);
    x1nb[(size_t)(nb + 2) * 96 + o] = f2bf(a2 * INVS32);
    x1nb[(size_t)(nb + 3) * 96 + o] = f2bf(a3 * INVS32);
  }
  if (lane < 32) {
    const int o = 64 + lane; const int v = o / 3, i_ = o - 3 * v;
    float a0 = 0.f, a1 = 0.f, a2 = 0.f, a3 = 0.f;
    for (int u = 0; u < 32; ++u) {
      const float w = W1n[u * 32 + v];
      a0 = fmaf(sX[0][64 + u * 3 + i_] * sG[0][64 + u], w, a0);
      a1 = fmaf(sX[1][64 + u * 3 + i_] * sG[1][64 + u], w, a1);
      a2 = fmaf(sX[2][64 + u * 3 + i_] * sG[2][64 + u], w, a2);
      a3 = fmaf(sX[3][64 + u * 3 + i_] * sG[3][64 + u], w, a3);
    }
    x1nb[(size_t)(nb + 0) * 96 + o] = f2bf(a0 * INVS32);
    x1nb[(size_t)(nb + 1) * 96 + o] = f2bf(a1 * INVS32);
    x1nb[(size_t)(nb + 2) * 96 + o] = f2bf(a2 * INVS32);
    x1nb[(size_t)(nb + 3) * 96 + o] = f2bf(a3 * INVS32);
  }

  // ---- A, B ----
  if (lane < 32) {
    float a0 = 0.f, a1 = 0.f, a2 = 0.f, a3 = 0.f;
    float c0 = 0.f, c1 = 0.f, c2 = 0.f, c3 = 0.f;
    for (int i = 0; i < 64; ++i) {
      const float wa = L1[i * 32 + lane];
      const float wb = L1[(64 + i) * 32 + lane];
      a0 = fmaf(sP0[0][i], wa, a0); a1 = fmaf(sP0[1][i], wa, a1);
      a2 = fmaf(sP0[2][i], wa, a2); a3 = fmaf(sP0[3][i], wa, a3);
      c0 = fmaf(sP0[0][i], wb, c0); c1 = fmaf(sP0[1][i], wb, c1);
      c2 = fmaf(sP0[2][i], wb, c2); c3 = fmaf(sP0[3][i], wb, c3);
    }
    Aw[(size_t)(nb + 0) * 32 + lane] = a0 * INVS160;
    Aw[(size_t)(nb + 1) * 32 + lane] = a1 * INVS160;
    Aw[(size_t)(nb + 2) * 32 + lane] = a2 * INVS160;
    Aw[(size_t)(nb + 3) * 32 + lane] = a3 * INVS160;
    Bw[(size_t)(nb + 0) * 32 + lane] = c0 * INVS160;
    Bw[(size_t)(nb + 1) * 32 + lane] = c1 * INVS160;
    Bw[(size_t)(nb + 2) * 32 + lane] = c2 * INVS160;
    Bw[(size_t)(nb + 3) * 32 + lane] = c3 * INVS160;
  }
}

// ---------------- fused per-edge: all-MFMA MLP + u-grouped scatter ----------------
__global__ __launch_bounds__(256, 4) void fused_edge_k(
    const float* __restrict__ edge_attr,
    const float* __restrict__ edge_sh,
    const int* __restrict__ ei,
    const ushort* __restrict__ F1Tb, const ushort* __restrict__ L1cTb,
    const ushort* __restrict__ F2Tb, const ushort* __restrict__ L2Tb,
    const float* __restrict__ p1w, const float* __restrict__ Aw,
    const float* __restrict__ Bw,
    const ushort* __restrict__ x0nb, const ushort* __restrict__ x1nb,
    const int* __restrict__ order,
    float* __restrict__ o480)
{
  const int s0  = blockIdx.x * TILE;
  const int tid = threadIdx.x;

  __shared__ __align__(16) char uMem[32 * 224 * 2];          // 14336 B
  ushort (*sW)[224] = (ushort (*)[224])uMem;
  ushort* sEAb = (ushort*)uMem;                  // 32x40 bf16
  ushort* sIPb = (ushort*)(uMem + 2560);         // 32x40 bf16
  float*  sAB  = (float*)(uMem + 5120);          // 32x36 f32

  __shared__ ushort sHF[32][40];
  __shared__ ushort sHL[32][40];
  __shared__ ushort sXS0[32][64];
  __shared__ ushort sXS1[32][96];
  __shared__ __align__(16) float sSH[32][4];
  __shared__ int    sDst[32];

  const int g = tid >> 3, l = tid & 7;
  const int e   = order[s0 + g];
  const int dst = ei[e];
  const int src = ei[EE + e];
  if (l == 0) sDst[g] = dst;

  // ---- phase A: stage (xs already bf16: straight copies) ----
  {
    float4 ea = *(const float4*)(edge_attr + (size_t)e * 32 + l * 4);
    *(unsigned*)&sEAb[g * 40 + l * 4 + 0] = pk(ea.x, ea.y);
    *(unsigned*)&sEAb[g * 40 + l * 4 + 2] = pk(ea.z, ea.w);
  }
  if (l == 1) *(float4*)&sSH[g][0] = *(const float4*)(edge_sh + (size_t)e * 4);
  {
    uint4 v = *(const uint4*)(x0nb + (size_t)src * 64 + l * 8);
    *(uint4*)&sXS0[g][l * 8] = v;
    const uint2* b2 = (const uint2*)(x1nb + (size_t)src * 96 + l * 12);
    uint2 w0 = b2[0], w1 = b2[1], w2 = b2[2];
    *(uint2*)&sXS1[g][l * 12 + 0] = w0;
    *(uint2*)&sXS1[g][l * 12 + 4] = w1;
    *(uint2*)&sXS1[g][l * 12 + 8] = w2;
  }
  {
    const float4* pd = (const float4*)(p1w + (size_t)dst * 96 + l * 12);
    const float4* ps = (const float4*)(p1w + (size_t)src * 96 + l * 12);
    float dp[12], sp[12];
#pragma unroll
    for (int k = 0; k < 3; ++k) {
      float4 v = pd[k]; dp[4*k] = v.x; dp[4*k+1] = v.y; dp[4*k+2] = v.z; dp[4*k+3] = v.w;
      float4 u = ps[k]; sp[4*k] = u.x; sp[4*k+1] = u.y; sp[4*k+2] = u.z; sp[4*k+3] = u.w;
    }
    float ip[4];
#pragma unroll
    for (int vv = 0; vv < 4; ++vv) {
      const int b = 3 * vv;
      ip[vv] = (dp[b] * sp[b] + dp[b+1] * sp[b+1] + dp[b+2] * sp[b+2]) * INVS3;
    }
    *(unsigned*)&sIPb[g * 40 + l * 4 + 0] = pk(ip[0], ip[1]);
    *(unsigned*)&sIPb[g * 40 + l * 4 + 2] = pk(ip[2], ip[3]);
  }
  {
    float4 av = *(const float4*)(Aw + (size_t)dst * 32 + l * 4);
    float4 bv = *(const float4*)(Bw + (size_t)src * 32 + l * 4);
    f32x4 ab;
    ab[0] = av.x + bv.x; ab[1] = av.y + bv.y;
    ab[2] = av.z + bv.z; ab[3] = av.w + bv.w;
    *(f32x4*)&sAB[g * 36 + l * 4] = ab;
  }
  __syncthreads();

  // ---- phase B (MFMA): hf = ea@F1T, hl = ip@L1cT + AB ----
  {
    const int wvi  = tid >> 6;
    const int lane = tid & 63;
    const int r = lane & 15;
    const int h = lane >> 4;
    const int qt = wvi & 1;
    const bool isHL = (wvi >= 2);
    const ushort* aBase = isHL ? sIPb : sEAb;
    const ushort* bW    = isHL ? L1cTb : F1Tb;
    ushort* outB = isHL ? &sHL[0][0] : &sHF[0][0];
    bf16x8 afr = *(const bf16x8*)&aBase[(qt * 16 + r) * 40 + h * 8];
#pragma unroll
    for (int ct = 0; ct < 2; ++ct) {
      const int c = ct * 16 + r;
      bf16x8 bfr = *(const bf16x8*)&bW[c * 32 + h * 8];
      f32x4 z = {0.f, 0.f, 0.f, 0.f};
      f32x4 o = __builtin_amdgcn_mfma_f32_16x16x32_bf16(afr, bfr, z, 0, 0, 0);
#pragma unroll
      for (int i = 0; i < 4; ++i) {
        const int q = qt * 16 + h * 4 + i;
        float v = o[i];
        if (isHL) v += sAB[q * 36 + c];
        outB[q * 40 + c] = f2bf(sspf(v));
      }
    }
  }
  __syncthreads();

  // ---- phase C: MFMA w-GEMMs ----
  {
    const int wv   = tid >> 6;
    const int lane = tid & 63;
    const int r = lane & 15;
    const int h = lane >> 4;
    bf16x8 aF0 = *(const bf16x8*)&sHF[r][h * 8];
    bf16x8 aF1 = *(const bf16x8*)&sHF[16 + r][h * 8];
    bf16x8 aL0 = *(const bf16x8*)&sHL[r][h * 8];
    bf16x8 aL1 = *(const bf16x8*)&sHL[16 + r][h * 8];
    const int ct0 = (wv < 2) ? wv * 4 : 8 + (wv - 2) * 3;
    const int nct = (wv < 2) ? 4 : 3;
    for (int t = 0; t < nct; ++t) {
      const int ct = ct0 + t;
      const int c  = ct * 16 + r;
      bf16x8 bF = *(const bf16x8*)&F2Tb[c * 32 + h * 8];
      bf16x8 bL = *(const bf16x8*)&L2Tb[c * 32 + h * 8];
      f32x4 z = {0.f, 0.f, 0.f, 0.f};
      f32x4 wf0 = __builtin_amdgcn_mfma_f32_16x16x32_bf16(aF0, bF, z, 0, 0, 0);
      f32x4 wl0 = __builtin_amdgcn_mfma_f32_16x16x32_bf16(aL0, bL, z, 0, 0, 0);
      f32x4 wf1 = __builtin_amdgcn_mfma_f32_16x16x32_bf16(aF1, bF, z, 0, 0, 0);
      f32x4 wl1 = __builtin_amdgcn_mfma_f32_16x16x32_bf16(aL1, bL, z, 0, 0, 0);
#pragma unroll
      for (int i = 0; i < 4; ++i) {
        sW[h * 4 + i][c]      = f2bf(wf0[i] * wl0[i]);
        sW[16 + h * 4 + i][c] = f2bf(wf1[i] * wl1[i]);
      }
    }
  }
  __syncthreads();

  // ---- phase D: u-grouped walk; 2 groups of 128 threads x 16 edges ----
  {
    const int h  = tid >> 7;          // which 16-edge half
    const int tl = tid & 127;
    const int q0 = h * 16;
    float a0 = 0.f, a1 = 0.f, a2 = 0.f, a3 = 0.f;

    for (int q = q0; q < q0 + 16; ++q) {
      const float4 sh = *(const float4*)&sSH[q][0];   // broadcast b128
      if (tl < 64) {
        // o0a[tl] + o1a[u=tl][0..2]; shares xs0[tl]
        const float x0 = bf2f(sXS0[q][tl]);
        const float w0 = bf2f(sW[q][tl]);
        const float w1 = bf2f(sW[q][64 + tl]);
        a0 = fmaf(w0 * x0, sh.x, a0);
        const float t = w1 * x0;
        a1 = fmaf(t, sh.y, a1);
        a2 = fmaf(t, sh.z, a2);
        a3 = fmaf(t, sh.w, a3);
      } else if (tl < 96) {
        // o0b[c] + o1b[u=c][0..2]; shares xs1[3c..3c+2]
        const int c = tl - 64;
        const float x0v = bf2f(sXS1[q][3 * c + 0]);
        const float x1v = bf2f(sXS1[q][3 * c + 1]);
        const float x2v = bf2f(sXS1[q][3 * c + 2]);
        const float wb = bf2f(sW[q][160 + c]);
        const float wd = bf2f(sW[q][128 + c]);
        const float d = fmaf(x2v, sh.w, fmaf(x1v, sh.z, x0v * sh.y));
        a0 = fmaf(wb, d, a0);
        const float t = wd * sh.x;
        a1 = fmaf(t, x0v, a1);
        a2 = fmaf(t, x1v, a2);
        a3 = fmaf(t, x2v, a3);
      } else {
        // o1c[u][0..2]
        const int u = tl - 96;
        const float x0v = bf2f(sXS1[q][3 * u + 0]);
        const float x1v = bf2f(sXS1[q][3 * u + 1]);
        const float x2v = bf2f(sXS1[q][3 * u + 2]);
        const float wc = bf2f(sW[q][192 + u]);
        a0 = fmaf(wc, fmaf(x1v, sh.w, -(x2v * sh.z)), a0);
        a1 = fmaf(wc, fmaf(x2v, sh.y, -(x0v * sh.w)), a1);
        a2 = fmaf(wc, fmaf(x0v, sh.z, -(x1v * sh.y)), a2);
      }
      const int d = sDst[q];
      const bool fl = (q == q0 + 15) || (sDst[q + 1] != d);
      if (fl) {
        float* dp = o480 + (size_t)d * 480;
        if (tl < 64) {
          atomicAdd(dp + tl, a0);
          atomicAdd(dp + 96 + 3 * tl + 0, a1);
          atomicAdd(dp + 96 + 3 * tl + 1, a2);
          atomicAdd(dp + 96 + 3 * tl + 2, a3);
        } else if (tl < 96) {
          const int c = tl - 64;
          atomicAdd(dp + 64 + c, a0);
          atomicAdd(dp + 288 + 3 * c + 0, a1);
          atomicAdd(dp + 288 + 3 * c + 1, a2);
          atomicAdd(dp + 288 + 3 * c + 2, a3);
        } else {
          const int u = tl - 96;
          atomicAdd(dp + 384 + 3 * u + 0, a0);
          atomicAdd(dp + 384 + 3 * u + 1, a1);
          atomicAdd(dp + 384 + 3 * u + 2, a2);
        }
        a0 = 0.f; a1 = 0.f; a2 = 0.f; a3 = 0.f;
      }
    }
  }
}

// ---------------- output linears: 1 wave, 4 nodes, weight-reuse x4 ----------------
__global__ __launch_bounds__(64) void out_wo_k(
    const float* __restrict__ o480,
    const float* __restrict__ WO0T, const float* __restrict__ WO1T,
    const float* __restrict__ WO2T, const float* __restrict__ bO0,
    float* __restrict__ out)
{
  const int lane = threadIdx.x;
  const int nb = blockIdx.x * 4;
  __shared__ float sO[4][480];
#pragma unroll
  for (int j = 0; j < 4; ++j) {
    const float4* src = (const float4*)(o480 + (size_t)(nb + j) * 480);
    for (int idx = lane; idx < 120; idx += 64)
      *(float4*)&sO[j][idx * 4] = src[idx];
  }

  for (int k = lane; k < 416; k += 64) {
    float y0, y1, y2, y3;
    if (k < 128) {
      const float* wr = WO0T + k * 96;
      float a0 = 0.f, a1 = 0.f, a2 = 0.f, a3 = 0.f;
      for (int u = 0; u < 96; ++u) {
        const float w = wr[u];
        a0 = fmaf(w, sO[0][u], a0); a1 = fmaf(w, sO[1][u], a1);
        a2 = fmaf(w, sO[2][u], a2); a3 = fmaf(w, sO[3][u], a3);
      }
      const float b = bO0[k];
      y0 = a0 + b; y1 = a1 + b; y2 = a2 + b; y3 = a3 + b;
    } else if (k < 320) {
      const int kk = k - 128; const int v = kk / 3; const int i = kk - 3 * v;
      const float* wr = WO1T + v * 96;
      float a0 = 0.f, a1 = 0.f, a2 = 0.f, a3 = 0.f;
      for (int u = 0; u < 96; ++u) {
        const float w = wr[u];
        a0 = fmaf(w, sO[0][96 + u * 3 + i], a0);
        a1 = fmaf(w, sO[1][96 + u * 3 + i], a1);
        a2 = fmaf(w, sO[2][96 + u * 3 + i], a2);
        a3 = fmaf(w, sO[3][96 + u * 3 + i], a3);
      }
      y0 = a0; y1 = a1; y2 = a2; y3 = a3;
    } else {
      const int kk = k - 320; const int v = kk / 3; const int i = kk - 3 * v;
      const float* wr = WO2T + v * 32;
      float a0 = 0.f, a1 = 0.f, a2 = 0.f, a3 = 0.f;
      for (int u = 0; u < 32; ++u) {
        const float w = wr[u];
        a0 = fmaf(w, sO[0][384 + u * 3 + i], a0);
        a1 = fmaf(w, sO[1][384 + u * 3 + i], a1);
        a2 = fmaf(w, sO[2][384 + u * 3 + i], a2);
        a3 = fmaf(w, sO[3][384 + u * 3 + i], a3);
      }
      y0 = a0; y1 = a1; y2 = a2; y3 = a3;
    }
    out[(size_t)(nb + 0) * 416 + k] = y0;
    out[(size_t)(nb + 1) * 416 + k] = y1;
    out[(size_t)(nb + 2) * 416 + k] = y2;
    out[(size_t)(nb + 3) * 416 + k] = y3;
  }
}

// ---------------- host ----------------
extern "C" void kernel_launch(void* const* d_in, const int* in_sizes, int n_in,
                              void* d_out, int out_size, void* d_ws, size_t ws_size,
                              hipStream_t stream) {
  const float* x         = (const float*)d_in[0];
  const float* edge_sh   = (const float*)d_in[1];
  const float* edge_attr = (const float*)d_in[2];
  const float* W0p       = (const float*)d_in[3];
  const float* b0p       = (const float*)d_in[4];
  const float* W1p       = (const float*)d_in[5];
  const float* W0n       = (const float*)d_in[6];
  const float* b0n       = (const float*)d_in[7];
  const float* W1n       = (const float*)d_in[8];
  const float* G1        = (const float*)d_in[9];
  const float* g1b       = (const float*)d_in[10];
  const float* G2        = (const float*)d_in[11];
  const float* g2b       = (const float*)d_in[12];
  const float* F1        = (const float*)d_in[13];
  const float* F2        = (const float*)d_in[14];
  const float* L1        = (const float*)d_in[15];
  const float* L2        = (const float*)d_in[16];
  const float* WO0       = (const float*)d_in[17];
  const float* bO0       = (const float*)d_in[18];
  const float* WO1       = (const float*)d_in[19];
  const float* WO2       = (const float*)d_in[20];
  const int*   ei        = (const int*)d_in[21];
  float* out = (float*)d_out;

  float*  p1w  = (float*)d_ws;            // N*96 f32
  ushort* x0nb = (ushort*)(p1w + NN * 96);   // N*64 bf16
  ushort* x1nb = x0nb + NN * 64;             // N*96 bf16
  float*  Aw   = (float*)(x1nb + NN * 96);   // N*32 f32 (2B*160N even -> 4B aligned)
  float*  Bw   = Aw + NN * 32;               // N*32
  float*  o480 = Bw + NN * 32;               // N*480
  int* cnt    = (int*)(o480 + (size_t)NN * 480);
  int* cursor = cnt    + NN;
  int* order  = cursor + NN;           // E
  uintptr_t p = (uintptr_t)(order + EE);
  p = (p + 15) & ~(uintptr_t)15;
  ushort* F2Tb  = (ushort*)p;          // 224*32 bf16
  ushort* L2Tb  = F2Tb + 224 * 32;
  ushort* F1Tb  = L2Tb + 224 * 32;     // 32*32 bf16
  ushort* L1cTb = F1Tb + 32 * 32;      // 32*32 bf16
  uintptr_t p2 = (uintptr_t)(L1cTb + 32 * 32);
  p2 = (p2 + 15) & ~(uintptr_t)15;
  float* WO0T = (float*)p2;            // 128*96
  float* WO1T = WO0T + 128 * 96;       // 64*96
  float* WO2T = WO1T + 64 * 96;        // 32*32

  hipMemsetAsync(cnt, 0, NN * sizeof(int), stream);
  hipMemsetAsync(o480, 0, (size_t)NN * 480 * sizeof(float), stream);
  prep_t_k<<<(EE + 255) / 256, 256, 0, stream>>>(F2, L2, WO0, WO1, WO2, F1, L1,
                                                 ei, cnt,
                                                 F2Tb, L2Tb, WO0T, WO1T, WO2T,
                                                 F1Tb, L1cTb);
  scan_k<<<1, 1024, 0, stream>>>(cnt, cursor);
  node_prep_k<<<NN / 4, 64, 0, stream>>>(x, W0p, b0p, W1p, W0n, b0n, W1n,
                                         G1, g1b, G2, g2b, L1,
                                         ei, cursor, order,
                                         p1w, x0nb, x1nb, Aw, Bw);
  fused_edge_k<<<EE / TILE, 256, 0, stream>>>(edge_attr, edge_sh, ei,
                                              F1Tb, L1cTb, F2Tb, L2Tb,
                                              p1w, Aw, Bw, x0nb, x1nb,
                                              order, o480);
  out_wo_k<<<NN / 4, 64, 0, stream>>>(o480, WO0T, WO1T, WO2T, bO0, out);
}

// Round 11
// 285.405 us; speedup vs baseline: 5.4671x; 1.1355x over previous
//
#include <hip/hip_runtime.h>
#include <math.h>

#define NN 10000
#define EE 320000
#define TILE 32

constexpr float INVS32  = 0.17677669529663687f;   // 1/sqrt(32)
constexpr float INVS160 = 0.07905694150420949f;   // 1/sqrt(160)
constexpr float INVS96  = 0.10206207261596575f;   // 1/sqrt(96)
constexpr float INVS3   = 0.5773502691896258f;    // 1/sqrt(3)
constexpr float INVS2   = 0.7071067811865476f;    // 1/sqrt(2)
constexpr float LN2     = 0.6931471805599453f;

typedef short bf16x8 __attribute__((ext_vector_type(8)));
typedef float f32x4  __attribute__((ext_vector_type(4)));

__device__ __forceinline__ float sspf(float v) {
  return fmaxf(v, 0.f) + __logf(1.f + __expf(-fabsf(v))) - LN2;
}
__device__ __forceinline__ ushort f2bf(float f) {
  union { float f; unsigned u; } v; v.f = f;
  unsigned r = v.u + 0x7FFF + ((v.u >> 16) & 1);   // RNE
  return (ushort)(r >> 16);
}
__device__ __forceinline__ float bf2f(ushort u) {
  return __uint_as_float(((unsigned)u) << 16);
}
__device__ __forceinline__ unsigned pk(float a, float b) {
  return (unsigned)f2bf(a) | ((unsigned)f2bf(b) << 16);
}

// ---------------- sort-by-dst ----------------
__global__ __launch_bounds__(1024) void scan_k(const int* __restrict__ cnt,
                                               int* __restrict__ cursor) {
  __shared__ int s[1024];
  const int t = threadIdx.x;
  int loc[10];
  int sum = 0;
#pragma unroll
  for (int jj = 0; jj < 10; ++jj) {
    int idx = t * 10 + jj;
    int c = (idx < NN) ? cnt[idx] : 0;
    loc[jj] = sum;
    sum += c;
  }
  s[t] = sum;
  __syncthreads();
  for (int d = 1; d < 1024; d <<= 1) {
    int v = (t >= d) ? s[t - d] : 0;
    __syncthreads();
    s[t] += v;
    __syncthreads();
  }
  const int excl = (t > 0) ? s[t - 1] : 0;
#pragma unroll
  for (int jj = 0; jj < 10; ++jj) {
    int idx = t * 10 + jj;
    if (idx < NN) cursor[idx] = excl + loc[jj];
  }
}

// ---------------- weight transforms + fused histogram ----------------
__global__ void prep_t_k(const float* __restrict__ F2, const float* __restrict__ L2,
                         const float* __restrict__ WO0, const float* __restrict__ WO1,
                         const float* __restrict__ WO2,
                         const float* __restrict__ F1, const float* __restrict__ L1,
                         const int* __restrict__ ei, int* __restrict__ cnt,
                         ushort* __restrict__ F2Tb, ushort* __restrict__ L2Tb,
                         float* __restrict__ WO0T, float* __restrict__ WO1T,
                         float* __restrict__ WO2T,
                         ushort* __restrict__ F1Tb, ushort* __restrict__ L1cTb) {
  int i = blockIdx.x * 256 + threadIdx.x;
  if (i < EE) atomicAdd(&cnt[ei[i]], 1);
  if (i < 7168) {                         // F2T/L2T: [c][k] bf16
    int c = i >> 5, k = i & 31;
    float sc = (c < 64)  ? (1.f / 32.f)
             : (c < 128) ? (INVS3 / 32.f)
             : (c < 160) ? (1.f / 32.f)
             : (c < 192) ? (INVS3 / 32.f)
                         : (INVS2 / 32.f);
    F2Tb[i] = f2bf(F2[k * 224 + c] * sc);
    L2Tb[i] = f2bf(L2[k * 224 + c]);
  } else if (i < 7168 + 12288) {          // WO0T [128][96], scale folded
    int j = i - 7168; int k = j / 96, u = j - k * 96;
    WO0T[j] = WO0[u * 128 + k] * INVS96;
  } else if (i < 7168 + 12288 + 6144) {   // WO1T [64][96]
    int j = i - 7168 - 12288; int v = j / 96, u = j - v * 96;
    WO1T[j] = WO1[u * 64 + v] * INVS96;
  } else if (i < 7168 + 12288 + 6144 + 1024) {  // WO2T [32][32]
    int j = i - 7168 - 12288 - 6144; int v = j >> 5, u = j & 31;
    WO2T[j] = WO2[u * 32 + v] * INVS32;
  } else if (i < 26624 + 1024) {          // F1T [32n][32k] bf16, INVS32 folded
    int j = i - 26624; int n = j >> 5, k = j & 31;
    F1Tb[j] = f2bf(F1[k * 32 + n] * INVS32);
  } else if (i < 27648 + 1024) {          // L1cT [32n][32k] bf16, INVS160 folded
    int j = i - 27648; int n = j >> 5, k = j & 31;
    L1cTb[j] = f2bf(L1[(128 + k) * 32 + n] * INVS160);
  }
}

// ---------------- node precompute: 1 wave, 4 nodes, weight-reuse x4, no barriers ----------------
__global__ __launch_bounds__(64) void node_prep_k(
    const float* __restrict__ x,
    const float* __restrict__ W0p, const float* __restrict__ b0p,
    const float* __restrict__ W1p,
    const float* __restrict__ W0n, const float* __restrict__ b0n,
    const float* __restrict__ W1n,
    const float* __restrict__ G1, const float* __restrict__ g1b,
    const float* __restrict__ G2, const float* __restrict__ g2b,
    const float* __restrict__ L1,
    const int* __restrict__ ei, int* __restrict__ cursor, int* __restrict__ order,
    float* __restrict__ p1w, ushort* __restrict__ x0nb, ushort* __restrict__ x1nb,
    float* __restrict__ Aw, float* __restrict__ Bw)
{
  {  // fused scat
    int gid = blockIdx.x * 64 + threadIdx.x;
#pragma unroll
    for (int r = 0; r < 2; ++r) {
      int e = gid + r * 160000;
      int p = atomicAdd(&cursor[ei[e]], 1);
      order[p] = e;
    }
  }

  const int lane = threadIdx.x;
  const int nb = blockIdx.x * 4;

  __shared__ float sX[4][160];
  __shared__ float sP0[4][64];
  __shared__ float sF0[4][96];
  __shared__ float sH1[4][96];
  __shared__ float sG[4][96];

#pragma unroll
  for (int j = 0; j < 4; ++j) {
    const int n = nb + j;
    sX[j][lane]      = x[n * 160 + lane];
    sX[j][lane + 64] = x[n * 160 + lane + 64];
    if (lane < 32) sX[j][lane + 128] = x[n * 160 + lane + 128];
  }

  {
    float a0 = 0.f, a1 = 0.f, a2 = 0.f, a3 = 0.f;
    for (int i = 0; i < 64; ++i) {
      const float w = W0p[i * 64 + lane];
      a0 = fmaf(sX[0][i], w, a0); a1 = fmaf(sX[1][i], w, a1);
      a2 = fmaf(sX[2][i], w, a2); a3 = fmaf(sX[3][i], w, a3);
    }
    const float b = b0p[lane];
    sP0[0][lane] = a0 * 0.125f + b; sP0[1][lane] = a1 * 0.125f + b;
    sP0[2][lane] = a2 * 0.125f + b; sP0[3][lane] = a3 * 0.125f + b;
#pragma unroll
    for (int j = 0; j < 4; ++j) sF0[j][lane] = sX[j][lane];
  }

  {
    const int o = lane; const int v = o / 3, i_ = o - 3 * v;
    float a0 = 0.f, a1 = 0.f, a2 = 0.f, a3 = 0.f;
    for (int u = 0; u < 32; ++u) {
      const float w = W1p[u * 32 + v];
      a0 = fmaf(sX[0][64 + u * 3 + i_], w, a0);
      a1 = fmaf(sX[1][64 + u * 3 + i_], w, a1);
      a2 = fmaf(sX[2][64 + u * 3 + i_], w, a2);
      a3 = fmaf(sX[3][64 + u * 3 + i_], w, a3);
    }
    p1w[(size_t)(nb + 0) * 96 + o] = a0 * INVS32;
    p1w[(size_t)(nb + 1) * 96 + o] = a1 * INVS32;
    p1w[(size_t)(nb + 2) * 96 + o] = a2 * INVS32;
    p1w[(size_t)(nb + 3) * 96 + o] = a3 * INVS32;
  }
  if (lane < 32) {
    const int o = 64 + lane; const int v = o / 3, i_ = o - 3 * v;
    float a0 = 0.f, a1 = 0.f, a2 = 0.f, a3 = 0.f;
    for (int u = 0; u < 32; ++u) {
      const float w = W1p[u * 32 + v];
      a0 = fmaf(sX[0][64 + u * 3 + i_], w, a0);
      a1 = fmaf(sX[1][64 + u * 3 + i_], w, a1);
      a2 = fmaf(sX[2][64 + u * 3 + i_], w, a2);
      a3 = fmaf(sX[3][64 + u * 3 + i_], w, a3);
    }
    p1w[(size_t)(nb + 0) * 96 + o] = a0 * INVS32;
    p1w[(size_t)(nb + 1) * 96 + o] = a1 * INVS32;
    p1w[(size_t)(nb + 2) * 96 + o] = a2 * INVS32;
    p1w[(size_t)(nb + 3) * 96 + o] = a3 * INVS32;
  }

  if (lane < 32) {
#pragma unroll
    for (int j = 0; j < 4; ++j) {
      float s2 = 1e-12f;
#pragma unroll
      for (int i = 0; i < 3; ++i) { float t = sX[j][64 + lane * 3 + i]; s2 += t * t; }
      sF0[j][64 + lane] = sqrtf(s2);
    }
  }

  {
    const float b = g1b[lane];
    float a0 = b, a1 = b, a2 = b, a3 = b;
    for (int i = 0; i < 96; ++i) {
      const float w = G1[i * 96 + lane];
      a0 = fmaf(sF0[0][i], w, a0); a1 = fmaf(sF0[1][i], w, a1);
      a2 = fmaf(sF0[2][i], w, a2); a3 = fmaf(sF0[3][i], w, a3);
    }
    sH1[0][lane] = a0 / (1.f + __expf(-a0));
    sH1[1][lane] = a1 / (1.f + __expf(-a1));
    sH1[2][lane] = a2 / (1.f + __expf(-a2));
    sH1[3][lane] = a3 / (1.f + __expf(-a3));
  }
  if (lane < 32) {
    const int o = 64 + lane;
    const float b = g1b[o];
    float a0 = b, a1 = b, a2 = b, a3 = b;
    for (int i = 0; i < 96; ++i) {
      const float w = G1[i * 96 + o];
      a0 = fmaf(sF0[0][i], w, a0); a1 = fmaf(sF0[1][i], w, a1);
      a2 = fmaf(sF0[2][i], w, a2); a3 = fmaf(sF0[3][i], w, a3);
    }
    sH1[0][o] = a0 / (1.f + __expf(-a0));
    sH1[1][o] = a1 / (1.f + __expf(-a1));
    sH1[2][o] = a2 / (1.f + __expf(-a2));
    sH1[3][o] = a3 / (1.f + __expf(-a3));
  }

  {
    const float b = g2b[lane];
    float a0 = b, a1 = b, a2 = b, a3 = b;
    for (int i = 0; i < 96; ++i) {
      const float w = G2[i * 96 + lane];
      a0 = fmaf(sH1[0][i], w, a0); a1 = fmaf(sH1[1][i], w, a1);
      a2 = fmaf(sH1[2][i], w, a2); a3 = fmaf(sH1[3][i], w, a3);
    }
    sG[0][lane] = a0; sG[1][lane] = a1; sG[2][lane] = a2; sG[3][lane] = a3;
  }
  if (lane < 32) {
    const int o = 64 + lane;
    const float b = g2b[o];
    float a0 = b, a1 = b, a2 = b, a3 = b;
    for (int i = 0; i < 96; ++i) {
      const float w = G2[i * 96 + o];
      a0 = fmaf(sH1[0][i], w, a0); a1 = fmaf(sH1[1][i], w, a1);
      a2 = fmaf(sH1[2][i], w, a2); a3 = fmaf(sH1[3][i], w, a3);
    }
    sG[0][o] = a0; sG[1][o] = a1; sG[2][o] = a2; sG[3][o] = a3;
  }

  {
    float a0 = 0.f, a1 = 0.f, a2 = 0.f, a3 = 0.f;
    for (int i = 0; i < 64; ++i) {
      const float w = W0n[i * 64 + lane];
      a0 = fmaf(sG[0][i], w, a0); a1 = fmaf(sG[1][i], w, a1);
      a2 = fmaf(sG[2][i], w, a2); a3 = fmaf(sG[3][i], w, a3);
    }
    const float b = b0n[lane];
    x0nb[(size_t)(nb + 0) * 64 + lane] = f2bf(a0 * 0.125f + b);
    x0nb[(size_t)(nb + 1) * 64 + lane] = f2bf(a1 * 0.125f + b);
    x0nb[(size_t)(nb + 2) * 64 + lane] = f2bf(a2 * 0.125f + b);
    x0nb[(size_t)(nb + 3) * 64 + lane] = f2bf(a3 * 0.125f + b);
  }

  {
    const int o = lane; const int v = o / 3, i_ = o - 3 * v;
    float a0 = 0.f, a1 = 0.f, a2 = 0.f, a3 = 0.f;
    for (int u = 0; u < 32; ++u) {
      const float w = W1n[u * 32 + v];
      a0 = fmaf(sX[0][64 + u * 3 + i_] * sG[0][64 + u], w, a0);
      a1 = fmaf(sX[1][64 + u * 3 + i_] * sG[1][64 + u], w, a1);
      a2 = fmaf(sX[2][64 + u * 3 + i_] * sG[2][64 + u], w, a2);
      a3 = fmaf(sX[3][64 + u * 3 + i_] * sG[3][64 + u], w, a3);
    }
    x1nb[(size_t)(nb + 0) * 96 + o] = f2bf(a0 * INVS32);
    x1nb[(size_t)(nb + 1) * 96 + o] = f2bf(a1 * INVS32);
    x1nb[(size_t)(nb + 2) * 96 + o] = f2bf(a2 * INVS32);
    x1nb[(size_t)(nb + 3) * 96 + o] = f2bf(a3 * INVS32);
  }
  if (lane < 32) {
    const int o = 64 + lane; const int v = o / 3, i_ = o - 3 * v;
    float a0 = 0.f, a1 = 0.f, a2 = 0.f, a3 = 0.f;
    for (int u = 0; u < 32; ++u) {
      const float w = W1n[u * 32 + v];
      a0 = fmaf(sX[0][64 + u * 3 + i_] * sG[0][64 + u], w, a0);
      a1 = fmaf(sX[1][64 + u * 3 + i_] * sG[1][64 + u], w, a1);
      a2 = fmaf(sX[2][64 + u * 3 + i_] * sG[2][64 + u], w, a2);
      a3 = fmaf(sX[3][64 + u * 3 + i_] * sG[3][64 + u], w, a3);
    }
    x1nb[(size_t)(nb + 0) * 96 + o] = f2bf(a0 * INVS32);
    x1nb[(size_t)(nb + 1) * 96 + o] = f2bf(a1 * INVS32);
    x1nb[(size_t)(nb + 2) * 96 + o] = f2bf(a2 * INVS32);
    x1nb[(size_t)(nb + 3) * 96 + o] = f2bf(a3 * INVS32);
  }

  if (lane < 32) {
    float a0 = 0.f, a1 = 0.f, a2 = 0.f, a3 = 0.f;
    float c0 = 0.f, c1 = 0.f, c2 = 0.f, c3 = 0.f;
    for (int i = 0; i < 64; ++i) {
      const float wa = L1[i * 32 + lane];
      const float wb = L1[(64 + i) * 32 + lane];
      a0 = fmaf(sP0[0][i], wa, a0); a1 = fmaf(sP0[1][i], wa, a1);
      a2 = fmaf(sP0[2][i], wa, a2); a3 = fmaf(sP0[3][i], wa, a3);
      c0 = fmaf(sP0[0][i], wb, c0); c1 = fmaf(sP0[1][i], wb, c1);
      c2 = fmaf(sP0[2][i], wb, c2); c3 = fmaf(sP0[3][i], wb, c3);
    }
    Aw[(size_t)(nb + 0) * 32 + lane] = a0 * INVS160;
    Aw[(size_t)(nb + 1) * 32 + lane] = a1 * INVS160;
    Aw[(size_t)(nb + 2) * 32 + lane] = a2 * INVS160;
    Aw[(size_t)(nb + 3) * 32 + lane] = a3 * INVS160;
    Bw[(size_t)(nb + 0) * 32 + lane] = c0 * INVS160;
    Bw[(size_t)(nb + 1) * 32 + lane] = c1 * INVS160;
    Bw[(size_t)(nb + 2) * 32 + lane] = c2 * INVS160;
    Bw[(size_t)(nb + 3) * 32 + lane] = c3 * INVS160;
  }
}

// ---------------- fused per-edge: all-MFMA MLP + coalesced acc-major scatter ----------------
// o480p layout (per dst row, 480 floats): slot = acc*128 + job, where
// job<64: o0a[job] (acc0) + o1a[job][i] (acc 1+i)
// job 64..95: o0b[c] (acc0) + o1b[c][i] (acc 1+i), c=job-64
// job 96..127: o1c[u][i] (acc i), u=job-96
__global__ __launch_bounds__(256, 4) void fused_edge_k(
    const float* __restrict__ edge_attr,
    const float* __restrict__ edge_sh,
    const int* __restrict__ ei,
    const ushort* __restrict__ F1Tb, const ushort* __restrict__ L1cTb,
    const ushort* __restrict__ F2Tb, const ushort* __restrict__ L2Tb,
    const float* __restrict__ p1w, const float* __restrict__ Aw,
    const float* __restrict__ Bw,
    const ushort* __restrict__ x0nb, const ushort* __restrict__ x1nb,
    const int* __restrict__ order,
    float* __restrict__ o480p)
{
  const int s0  = blockIdx.x * TILE;
  const int tid = threadIdx.x;

  __shared__ __align__(16) char uMem[32 * 224 * 2];          // 14336 B
  ushort (*sW)[224] = (ushort (*)[224])uMem;
  ushort* sEAb = (ushort*)uMem;                  // 32x40 bf16
  ushort* sIPb = (ushort*)(uMem + 2560);         // 32x40 bf16
  float*  sAB  = (float*)(uMem + 5120);          // 32x36 f32

  __shared__ ushort sHF[32][40];
  __shared__ ushort sHL[32][40];
  __shared__ ushort sXS0[32][64];
  __shared__ ushort sXS1[32][96];
  __shared__ __align__(16) float sSH[32][4];
  __shared__ int    sDst[32];

  const int g = tid >> 3, l = tid & 7;
  const int e   = order[s0 + g];
  const int dst = ei[e];
  const int src = ei[EE + e];
  if (l == 0) sDst[g] = dst;

  // ---- phase A ----
  {
    float4 ea = *(const float4*)(edge_attr + (size_t)e * 32 + l * 4);
    *(unsigned*)&sEAb[g * 40 + l * 4 + 0] = pk(ea.x, ea.y);
    *(unsigned*)&sEAb[g * 40 + l * 4 + 2] = pk(ea.z, ea.w);
  }
  if (l == 1) *(float4*)&sSH[g][0] = *(const float4*)(edge_sh + (size_t)e * 4);
  {
    uint4 v = *(const uint4*)(x0nb + (size_t)src * 64 + l * 8);
    *(uint4*)&sXS0[g][l * 8] = v;
    const uint2* b2 = (const uint2*)(x1nb + (size_t)src * 96 + l * 12);
    uint2 w0 = b2[0], w1 = b2[1], w2 = b2[2];
    *(uint2*)&sXS1[g][l * 12 + 0] = w0;
    *(uint2*)&sXS1[g][l * 12 + 4] = w1;
    *(uint2*)&sXS1[g][l * 12 + 8] = w2;
  }
  {
    const float4* pd = (const float4*)(p1w + (size_t)dst * 96 + l * 12);
    const float4* ps = (const float4*)(p1w + (size_t)src * 96 + l * 12);
    float dp[12], sp[12];
#pragma unroll
    for (int k = 0; k < 3; ++k) {
      float4 v = pd[k]; dp[4*k] = v.x; dp[4*k+1] = v.y; dp[4*k+2] = v.z; dp[4*k+3] = v.w;
      float4 u = ps[k]; sp[4*k] = u.x; sp[4*k+1] = u.y; sp[4*k+2] = u.z; sp[4*k+3] = u.w;
    }
    float ip[4];
#pragma unroll
    for (int vv = 0; vv < 4; ++vv) {
      const int b = 3 * vv;
      ip[vv] = (dp[b] * sp[b] + dp[b+1] * sp[b+1] + dp[b+2] * sp[b+2]) * INVS3;
    }
    *(unsigned*)&sIPb[g * 40 + l * 4 + 0] = pk(ip[0], ip[1]);
    *(unsigned*)&sIPb[g * 40 + l * 4 + 2] = pk(ip[2], ip[3]);
  }
  {
    float4 av = *(const float4*)(Aw + (size_t)dst * 32 + l * 4);
    float4 bv = *(const float4*)(Bw + (size_t)src * 32 + l * 4);
    f32x4 ab;
    ab[0] = av.x + bv.x; ab[1] = av.y + bv.y;
    ab[2] = av.z + bv.z; ab[3] = av.w + bv.w;
    *(f32x4*)&sAB[g * 36 + l * 4] = ab;
  }
  __syncthreads();

  // ---- phase B (MFMA) ----
  {
    const int wvi  = tid >> 6;
    const int lane = tid & 63;
    const int r = lane & 15;
    const int h = lane >> 4;
    const int qt = wvi & 1;
    const bool isHL = (wvi >= 2);
    const ushort* aBase = isHL ? sIPb : sEAb;
    const ushort* bW    = isHL ? L1cTb : F1Tb;
    ushort* outB = isHL ? &sHL[0][0] : &sHF[0][0];
    bf16x8 afr = *(const bf16x8*)&aBase[(qt * 16 + r) * 40 + h * 8];
#pragma unroll
    for (int ct = 0; ct < 2; ++ct) {
      const int c = ct * 16 + r;
      bf16x8 bfr = *(const bf16x8*)&bW[c * 32 + h * 8];
      f32x4 z = {0.f, 0.f, 0.f, 0.f};
      f32x4 o = __builtin_amdgcn_mfma_f32_16x16x32_bf16(afr, bfr, z, 0, 0, 0);
#pragma unroll
      for (int i = 0; i < 4; ++i) {
        const int q = qt * 16 + h * 4 + i;
        float v = o[i];
        if (isHL) v += sAB[q * 36 + c];
        outB[q * 40 + c] = f2bf(sspf(v));
      }
    }
  }
  __syncthreads();

  // ---- phase C: MFMA w-GEMMs ----
  {
    const int wv   = tid >> 6;
    const int lane = tid & 63;
    const int r = lane & 15;
    const int h = lane >> 4;
    bf16x8 aF0 = *(const bf16x8*)&sHF[r][h * 8];
    bf16x8 aF1 = *(const bf16x8*)&sHF[16 + r][h * 8];
    bf16x8 aL0 = *(const bf16x8*)&sHL[r][h * 8];
    bf16x8 aL1 = *(const bf16x8*)&sHL[16 + r][h * 8];
    const int ct0 = (wv < 2) ? wv * 4 : 8 + (wv - 2) * 3;
    const int nct = (wv < 2) ? 4 : 3;
    for (int t = 0; t < nct; ++t) {
      const int ct = ct0 + t;
      const int c  = ct * 16 + r;
      bf16x8 bF = *(const bf16x8*)&F2Tb[c * 32 + h * 8];
      bf16x8 bL = *(const bf16x8*)&L2Tb[c * 32 + h * 8];
      f32x4 z = {0.f, 0.f, 0.f, 0.f};
      f32x4 wf0 = __builtin_amdgcn_mfma_f32_16x16x32_bf16(aF0, bF, z, 0, 0, 0);
      f32x4 wl0 = __builtin_amdgcn_mfma_f32_16x16x32_bf16(aL0, bL, z, 0, 0, 0);
      f32x4 wf1 = __builtin_amdgcn_mfma_f32_16x16x32_bf16(aF1, bF, z, 0, 0, 0);
      f32x4 wl1 = __builtin_amdgcn_mfma_f32_16x16x32_bf16(aL1, bL, z, 0, 0, 0);
#pragma unroll
      for (int i = 0; i < 4; ++i) {
        sW[h * 4 + i][c]      = f2bf(wf0[i] * wl0[i]);
        sW[16 + h * 4 + i][c] = f2bf(wf1[i] * wl1[i]);
      }
    }
  }
  __syncthreads();

  // ---- phase D: 128 active threads, u-grouped jobs over all 32 edges ----
  if (tid < 128) {
    const int tl = tid;
    float a0 = 0.f, a1 = 0.f, a2 = 0.f, a3 = 0.f;

    for (int q = 0; q < TILE; ++q) {
      const float4 sh = *(const float4*)&sSH[q][0];   // broadcast b128
      if (tl < 64) {
        const float x0 = bf2f(sXS0[q][tl]);
        const float w0 = bf2f(sW[q][tl]);
        const float w1 = bf2f(sW[q][64 + tl]);
        a0 = fmaf(w0 * x0, sh.x, a0);
        const float t = w1 * x0;
        a1 = fmaf(t, sh.y, a1);
        a2 = fmaf(t, sh.z, a2);
        a3 = fmaf(t, sh.w, a3);
      } else if (tl < 96) {
        const int c = tl - 64;
        const float x0v = bf2f(sXS1[q][3 * c + 0]);
        const float x1v = bf2f(sXS1[q][3 * c + 1]);
        const float x2v = bf2f(sXS1[q][3 * c + 2]);
        const float wb = bf2f(sW[q][160 + c]);
        const float wd = bf2f(sW[q][128 + c]);
        const float d = fmaf(x2v, sh.w, fmaf(x1v, sh.z, x0v * sh.y));
        a0 = fmaf(wb, d, a0);
        const float t = wd * sh.x;
        a1 = fmaf(t, x0v, a1);
        a2 = fmaf(t, x1v, a2);
        a3 = fmaf(t, x2v, a3);
      } else {
        const int u = tl - 96;
        const float x0v = bf2f(sXS1[q][3 * u + 0]);
        const float x1v = bf2f(sXS1[q][3 * u + 1]);
        const float x2v = bf2f(sXS1[q][3 * u + 2]);
        const float wc = bf2f(sW[q][192 + u]);
        a0 = fmaf(wc, fmaf(x1v, sh.w, -(x2v * sh.z)), a0);
        a1 = fmaf(wc, fmaf(x2v, sh.y, -(x0v * sh.w)), a1);
        a2 = fmaf(wc, fmaf(x0v, sh.z, -(x1v * sh.y)), a2);
      }
      const int d = sDst[q];
      const bool fl = (q == TILE - 1) || (sDst[q + 1] != d);
      if (fl) {
        float* dp = o480p + (size_t)d * 480;
        atomicAdd(dp + tl, a0);                    // lane-contiguous
        atomicAdd(dp + 128 + tl, a1);
        atomicAdd(dp + 256 + tl, a2);
        if (tl < 96) atomicAdd(dp + 384 + tl, a3);
        a0 = 0.f; a1 = 0.f; a2 = 0.f; a3 = 0.f;
      }
    }
  }
}

// ---------------- output linears: 1 wave, 4 nodes, acc-major o480p reads ----------------
// t0 orig u<96 -> slot u; t1[u][i] -> slot 128+128i+u; t2[u][i] -> slot 96+128i+u.
__global__ __launch_bounds__(64) void out_wo_k(
    const float* __restrict__ o480p,
    const float* __restrict__ WO0T, const float* __restrict__ WO1T,
    const float* __restrict__ WO2T, const float* __restrict__ bO0,
    float* __restrict__ out)
{
  const int lane = threadIdx.x;
  const int nb = blockIdx.x * 4;
  __shared__ float sO[4][480];
#pragma unroll
  for (int j = 0; j < 4; ++j) {
    const float4* src = (const float4*)(o480p + (size_t)(nb + j) * 480);
    for (int idx = lane; idx < 120; idx += 64)
      *(float4*)&sO[j][idx * 4] = src[idx];
  }

  for (int k = lane; k < 416; k += 64) {
    float y0, y1, y2, y3;
    if (k < 128) {
      const float* wr = WO0T + k * 96;
      float a0 = 0.f, a1 = 0.f, a2 = 0.f, a3 = 0.f;
      for (int u = 0; u < 96; ++u) {
        const float w = wr[u];
        a0 = fmaf(w, sO[0][u], a0); a1 = fmaf(w, sO[1][u], a1);
        a2 = fmaf(w, sO[2][u], a2); a3 = fmaf(w, sO[3][u], a3);
      }
      const float b = bO0[k];
      y0 = a0 + b; y1 = a1 + b; y2 = a2 + b; y3 = a3 + b;
    } else if (k < 320) {
      const int kk = k - 128; const int v = kk / 3; const int i = kk - 3 * v;
      const float* wr = WO1T + v * 96;
      const int base = 128 + 128 * i;
      float a0 = 0.f, a1 = 0.f, a2 = 0.f, a3 = 0.f;
      for (int u = 0; u < 96; ++u) {
        const float w = wr[u];
        a0 = fmaf(w, sO[0][base + u], a0);
        a1 = fmaf(w, sO[1][base + u], a1);
        a2 = fmaf(w, sO[2][base + u], a2);
        a3 = fmaf(w, sO[3][base + u], a3);
      }
      y0 = a0; y1 = a1; y2 = a2; y3 = a3;
    } else {
      const int kk = k - 320; const int v = kk / 3; const int i = kk - 3 * v;
      const float* wr = WO2T + v * 32;
      const int base = 96 + 128 * i;
      float a0 = 0.f, a1 = 0.f, a2 = 0.f, a3 = 0.f;
      for (int u = 0; u < 32; ++u) {
        const float w = wr[u];
        a0 = fmaf(w, sO[0][base + u], a0);
        a1 = fmaf(w, sO[1][base + u], a1);
        a2 = fmaf(w, sO[2][base + u], a2);
        a3 = fmaf(w, sO[3][base + u], a3);
      }
      y0 = a0; y1 = a1; y2 = a2; y3 = a3;
    }
    out[(size_t)(nb + 0) * 416 + k] = y0;
    out[(size_t)(nb + 1) * 416 + k] = y1;
    out[(size_t)(nb + 2) * 416 + k] = y2;
    out[(size_t)(nb + 3) * 416 + k] = y3;
  }
}

// ---------------- host ----------------
extern "C" void kernel_launch(void* const* d_in, const int* in_sizes, int n_in,
                              void* d_out, int out_size, void* d_ws, size_t ws_size,
                              hipStream_t stream) {
  const float* x         = (const float*)d_in[0];
  const float* edge_sh   = (const float*)d_in[1];
  const float* edge_attr = (const float*)d_in[2];
  const float* W0p       = (const float*)d_in[3];
  const float* b0p       = (const float*)d_in[4];
  const float* W1p       = (const float*)d_in[5];
  const float* W0n       = (const float*)d_in[6];
  const float* b0n       = (const float*)d_in[7];
  const float* W1n       = (const float*)d_in[8];
  const float* G1        = (const float*)d_in[9];
  const float* g1b       = (const float*)d_in[10];
  const float* G2        = (const float*)d_in[11];
  const float* g2b       = (const float*)d_in[12];
  const float* F1        = (const float*)d_in[13];
  const float* F2        = (const float*)d_in[14];
  const float* L1        = (const float*)d_in[15];
  const float* L2        = (const float*)d_in[16];
  const float* WO0       = (const float*)d_in[17];
  const float* bO0       = (const float*)d_in[18];
  const float* WO1       = (const float*)d_in[19];
  const float* WO2       = (const float*)d_in[20];
  const int*   ei        = (const int*)d_in[21];
  float* out = (float*)d_out;

  float*  p1w  = (float*)d_ws;            // N*96 f32
  ushort* x0nb = (ushort*)(p1w + NN * 96);   // N*64 bf16
  ushort* x1nb = x0nb + NN * 64;             // N*96 bf16
  float*  Aw   = (float*)(x1nb + NN * 96);   // N*32 f32
  float*  Bw   = Aw + NN * 32;               // N*32
  float*  o480 = Bw + NN * 32;               // N*480 (acc-major permuted)
  int* cnt    = (int*)(o480 + (size_t)NN * 480);
  int* cursor = cnt    + NN;
  int* order  = cursor + NN;           // E
  uintptr_t p = (uintptr_t)(order + EE);
  p = (p + 15) & ~(uintptr_t)15;
  ushort* F2Tb  = (ushort*)p;          // 224*32 bf16
  ushort* L2Tb  = F2Tb + 224 * 32;
  ushort* F1Tb  = L2Tb + 224 * 32;     // 32*32 bf16
  ushort* L1cTb = F1Tb + 32 * 32;      // 32*32 bf16
  uintptr_t p2 = (uintptr_t)(L1cTb + 32 * 32);
  p2 = (p2 + 15) & ~(uintptr_t)15;
  float* WO0T = (float*)p2;            // 128*96
  float* WO1T = WO0T + 128 * 96;       // 64*96
  float* WO2T = WO1T + 64 * 96;        // 32*32

  hipMemsetAsync(cnt, 0, NN * sizeof(int), stream);
  hipMemsetAsync(o480, 0, (size_t)NN * 480 * sizeof(float), stream);
  prep_t_k<<<(EE + 255) / 256, 256, 0, stream>>>(F2, L2, WO0, WO1, WO2, F1, L1,
                                                 ei, cnt,
                                                 F2Tb, L2Tb, WO0T, WO1T, WO2T,
                                                 F1Tb, L1cTb);
  scan_k<<<1, 1024, 0, stream>>>(cnt, cursor);
  node_prep_k<<<NN / 4, 64, 0, stream>>>(x, W0p, b0p, W1p, W0n, b0n, W1n,
                                         G1, g1b, G2, g2b, L1,
                                         ei, cursor, order,
                                         p1w, x0nb, x1nb, Aw, Bw);
  fused_edge_k<<<EE / TILE, 256, 0, stream>>>(edge_attr, edge_sh, ei,
                                              F1Tb, L1cTb, F2Tb, L2Tb,
                                              p1w, Aw, Bw, x0nb, x1nb,
                                              order, o480);
  out_wo_k<<<NN / 4, 64, 0, stream>>>(o480, WO0T, WO1T, WO2T, bO0, out);
}

// Round 12
// 259.871 us; speedup vs baseline: 6.0043x; 1.0983x over previous
//
#include <hip/hip_runtime.h>
#include <math.h>

#define NN 10000
#define EE 320000
#define TILE 32

constexpr float INVS32  = 0.17677669529663687f;   // 1/sqrt(32)
constexpr float INVS160 = 0.07905694150420949f;   // 1/sqrt(160)
constexpr float INVS96  = 0.10206207261596575f;   // 1/sqrt(96)
constexpr float INVS3   = 0.5773502691896258f;    // 1/sqrt(3)
constexpr float INVS2   = 0.7071067811865476f;    // 1/sqrt(2)
constexpr float LN2     = 0.6931471805599453f;

typedef short bf16x8 __attribute__((ext_vector_type(8)));
typedef float f32x4  __attribute__((ext_vector_type(4)));

__device__ __forceinline__ float sspf(float v) {
  return fmaxf(v, 0.f) + __logf(1.f + __expf(-fabsf(v))) - LN2;
}
__device__ __forceinline__ ushort f2bf(float f) {
  union { float f; unsigned u; } v; v.f = f;
  unsigned r = v.u + 0x7FFF + ((v.u >> 16) & 1);   // RNE
  return (ushort)(r >> 16);
}
__device__ __forceinline__ float bf2f(ushort u) {
  return __uint_as_float(((unsigned)u) << 16);
}
__device__ __forceinline__ float bflo(unsigned w) {
  return __uint_as_float(w << 16);
}
__device__ __forceinline__ float bfhi(unsigned w) {
  return __uint_as_float(w & 0xFFFF0000u);
}
__device__ __forceinline__ unsigned pk(float a, float b) {
  return (unsigned)f2bf(a) | ((unsigned)f2bf(b) << 16);
}

// ---------------- sort-by-dst ----------------
__global__ __launch_bounds__(1024) void scan_k(const int* __restrict__ cnt,
                                               int* __restrict__ cursor) {
  __shared__ int s[1024];
  const int t = threadIdx.x;
  int loc[10];
  int sum = 0;
#pragma unroll
  for (int jj = 0; jj < 10; ++jj) {
    int idx = t * 10 + jj;
    int c = (idx < NN) ? cnt[idx] : 0;
    loc[jj] = sum;
    sum += c;
  }
  s[t] = sum;
  __syncthreads();
  for (int d = 1; d < 1024; d <<= 1) {
    int v = (t >= d) ? s[t - d] : 0;
    __syncthreads();
    s[t] += v;
    __syncthreads();
  }
  const int excl = (t > 0) ? s[t - 1] : 0;
#pragma unroll
  for (int jj = 0; jj < 10; ++jj) {
    int idx = t * 10 + jj;
    if (idx < NN) cursor[idx] = excl + loc[jj];
  }
}

// ---------------- weight transforms + fused histogram ----------------
__global__ void prep_t_k(const float* __restrict__ F2, const float* __restrict__ L2,
                         const float* __restrict__ WO0, const float* __restrict__ WO1,
                         const float* __restrict__ WO2,
                         const float* __restrict__ F1, const float* __restrict__ L1,
                         const int* __restrict__ ei, int* __restrict__ cnt,
                         ushort* __restrict__ F2Tb, ushort* __restrict__ L2Tb,
                         float* __restrict__ WO0T, float* __restrict__ WO1T,
                         float* __restrict__ WO2T,
                         ushort* __restrict__ F1Tb, ushort* __restrict__ L1cTb) {
  int i = blockIdx.x * 256 + threadIdx.x;
  if (i < EE) atomicAdd(&cnt[ei[i]], 1);
  if (i < 7168) {                         // F2T/L2T: [c][k] bf16
    int c = i >> 5, k = i & 31;
    float sc = (c < 64)  ? (1.f / 32.f)
             : (c < 128) ? (INVS3 / 32.f)
             : (c < 160) ? (1.f / 32.f)
             : (c < 192) ? (INVS3 / 32.f)
                         : (INVS2 / 32.f);
    F2Tb[i] = f2bf(F2[k * 224 + c] * sc);
    L2Tb[i] = f2bf(L2[k * 224 + c]);
  } else if (i < 7168 + 12288) {          // WO0T [128][96], scale folded
    int j = i - 7168; int k = j / 96, u = j - k * 96;
    WO0T[j] = WO0[u * 128 + k] * INVS96;
  } else if (i < 7168 + 12288 + 6144) {   // WO1T [64][96]
    int j = i - 7168 - 12288; int v = j / 96, u = j - v * 96;
    WO1T[j] = WO1[u * 64 + v] * INVS96;
  } else if (i < 7168 + 12288 + 6144 + 1024) {  // WO2T [32][32]
    int j = i - 7168 - 12288 - 6144; int v = j >> 5, u = j & 31;
    WO2T[j] = WO2[u * 32 + v] * INVS32;
  } else if (i < 26624 + 1024) {          // F1T [32n][32k] bf16, INVS32 folded
    int j = i - 26624; int n = j >> 5, k = j & 31;
    F1Tb[j] = f2bf(F1[k * 32 + n] * INVS32);
  } else if (i < 27648 + 1024) {          // L1cT [32n][32k] bf16, INVS160 folded
    int j = i - 27648; int n = j >> 5, k = j & 31;
    L1cTb[j] = f2bf(L1[(128 + k) * 32 + n] * INVS160);
  }
}

// ---------------- node precompute: 1 wave, 4 nodes, weight-reuse x4 ----------------
__global__ __launch_bounds__(64) void node_prep_k(
    const float* __restrict__ x,
    const float* __restrict__ W0p, const float* __restrict__ b0p,
    const float* __restrict__ W1p,
    const float* __restrict__ W0n, const float* __restrict__ b0n,
    const float* __restrict__ W1n,
    const float* __restrict__ G1, const float* __restrict__ g1b,
    const float* __restrict__ G2, const float* __restrict__ g2b,
    const float* __restrict__ L1,
    const int* __restrict__ ei, int* __restrict__ cursor, int* __restrict__ order,
    ushort* __restrict__ p1b, ushort* __restrict__ x0nb, ushort* __restrict__ x1nb,
    float* __restrict__ Aw, float* __restrict__ Bw)
{
  {  // fused scat
    int gid = blockIdx.x * 64 + threadIdx.x;
#pragma unroll
    for (int r = 0; r < 2; ++r) {
      int e = gid + r * 160000;
      int p = atomicAdd(&cursor[ei[e]], 1);
      order[p] = e;
    }
  }

  const int lane = threadIdx.x;
  const int nb = blockIdx.x * 4;

  __shared__ float sX[4][160];
  __shared__ float sP0[4][64];
  __shared__ float sF0[4][96];
  __shared__ float sH1[4][96];
  __shared__ float sG[4][96];

#pragma unroll
  for (int j = 0; j < 4; ++j) {
    const int n = nb + j;
    sX[j][lane]      = x[n * 160 + lane];
    sX[j][lane + 64] = x[n * 160 + lane + 64];
    if (lane < 32) sX[j][lane + 128] = x[n * 160 + lane + 128];
  }

  {
    float a0 = 0.f, a1 = 0.f, a2 = 0.f, a3 = 0.f;
    for (int i = 0; i < 64; ++i) {
      const float w = W0p[i * 64 + lane];
      a0 = fmaf(sX[0][i], w, a0); a1 = fmaf(sX[1][i], w, a1);
      a2 = fmaf(sX[2][i], w, a2); a3 = fmaf(sX[3][i], w, a3);
    }
    const float b = b0p[lane];
    sP0[0][lane] = a0 * 0.125f + b; sP0[1][lane] = a1 * 0.125f + b;
    sP0[2][lane] = a2 * 0.125f + b; sP0[3][lane] = a3 * 0.125f + b;
#pragma unroll
    for (int j = 0; j < 4; ++j) sF0[j][lane] = sX[j][lane];
  }

  {
    const int o = lane; const int v = o / 3, i_ = o - 3 * v;
    float a0 = 0.f, a1 = 0.f, a2 = 0.f, a3 = 0.f;
    for (int u = 0; u < 32; ++u) {
      const float w = W1p[u * 32 + v];
      a0 = fmaf(sX[0][64 + u * 3 + i_], w, a0);
      a1 = fmaf(sX[1][64 + u * 3 + i_], w, a1);
      a2 = fmaf(sX[2][64 + u * 3 + i_], w, a2);
      a3 = fmaf(sX[3][64 + u * 3 + i_], w, a3);
    }
    p1b[(size_t)(nb + 0) * 96 + o] = f2bf(a0 * INVS32);
    p1b[(size_t)(nb + 1) * 96 + o] = f2bf(a1 * INVS32);
    p1b[(size_t)(nb + 2) * 96 + o] = f2bf(a2 * INVS32);
    p1b[(size_t)(nb + 3) * 96 + o] = f2bf(a3 * INVS32);
  }
  if (lane < 32) {
    const int o = 64 + lane; const int v = o / 3, i_ = o - 3 * v;
    float a0 = 0.f, a1 = 0.f, a2 = 0.f, a3 = 0.f;
    for (int u = 0; u < 32; ++u) {
      const float w = W1p[u * 32 + v];
      a0 = fmaf(sX[0][64 + u * 3 + i_], w, a0);
      a1 = fmaf(sX[1][64 + u * 3 + i_], w, a1);
      a2 = fmaf(sX[2][64 + u * 3 + i_], w, a2);
      a3 = fmaf(sX[3][64 + u * 3 + i_], w, a3);
    }
    p1b[(size_t)(nb + 0) * 96 + o] = f2bf(a0 * INVS32);
    p1b[(size_t)(nb + 1) * 96 + o] = f2bf(a1 * INVS32);
    p1b[(size_t)(nb + 2) * 96 + o] = f2bf(a2 * INVS32);
    p1b[(size_t)(nb + 3) * 96 + o] = f2bf(a3 * INVS32);
  }

  if (lane < 32) {
#pragma unroll
    for (int j = 0; j < 4; ++j) {
      float s2 = 1e-12f;
#pragma unroll
      for (int i = 0; i < 3; ++i) { float t = sX[j][64 + lane * 3 + i]; s2 += t * t; }
      sF0[j][64 + lane] = sqrtf(s2);
    }
  }

  {
    const float b = g1b[lane];
    float a0 = b, a1 = b, a2 = b, a3 = b;
    for (int i = 0; i < 96; ++i) {
      const float w = G1[i * 96 + lane];
      a0 = fmaf(sF0[0][i], w, a0); a1 = fmaf(sF0[1][i], w, a1);
      a2 = fmaf(sF0[2][i], w, a2); a3 = fmaf(sF0[3][i], w, a3);
    }
    sH1[0][lane] = a0 / (1.f + __expf(-a0));
    sH1[1][lane] = a1 / (1.f + __expf(-a1));
    sH1[2][lane] = a2 / (1.f + __expf(-a2));
    sH1[3][lane] = a3 / (1.f + __expf(-a3));
  }
  if (lane < 32) {
    const int o = 64 + lane;
    const float b = g1b[o];
    float a0 = b, a1 = b, a2 = b, a3 = b;
    for (int i = 0; i < 96; ++i) {
      const float w = G1[i * 96 + o];
      a0 = fmaf(sF0[0][i], w, a0); a1 = fmaf(sF0[1][i], w, a1);
      a2 = fmaf(sF0[2][i], w, a2); a3 = fmaf(sF0[3][i], w, a3);
    }
    sH1[0][o] = a0 / (1.f + __expf(-a0));
    sH1[1][o] = a1 / (1.f + __expf(-a1));
    sH1[2][o] = a2 / (1.f + __expf(-a2));
    sH1[3][o] = a3 / (1.f + __expf(-a3));
  }

  {
    const float b = g2b[lane];
    float a0 = b, a1 = b, a2 = b, a3 = b;
    for (int i = 0; i < 96; ++i) {
      const float w = G2[i * 96 + lane];
      a0 = fmaf(sH1[0][i], w, a0); a1 = fmaf(sH1[1][i], w, a1);
      a2 = fmaf(sH1[2][i], w, a2); a3 = fmaf(sH1[3][i], w, a3);
    }
    sG[0][lane] = a0; sG[1][lane] = a1; sG[2][lane] = a2; sG[3][lane] = a3;
  }
  if (lane < 32) {
    const int o = 64 + lane;
    const float b = g2b[o];
    float a0 = b, a1 = b, a2 = b, a3 = b;
    for (int i = 0; i < 96; ++i) {
      const float w = G2[i * 96 + o];
      a0 = fmaf(sH1[0][i], w, a0); a1 = fmaf(sH1[1][i], w, a1);
      a2 = fmaf(sH1[2][i], w, a2); a3 = fmaf(sH1[3][i], w, a3);
    }
    sG[0][o] = a0; sG[1][o] = a1; sG[2][o] = a2; sG[3][o] = a3;
  }

  {
    float a0 = 0.f, a1 = 0.f, a2 = 0.f, a3 = 0.f;
    for (int i = 0; i < 64; ++i) {
      const float w = W0n[i * 64 + lane];
      a0 = fmaf(sG[0][i], w, a0); a1 = fmaf(sG[1][i], w, a1);
      a2 = fmaf(sG[2][i], w, a2); a3 = fmaf(sG[3][i], w, a3);
    }
    const float b = b0n[lane];
    x0nb[(size_t)(nb + 0) * 64 + lane] = f2bf(a0 * 0.125f + b);
    x0nb[(size_t)(nb + 1) * 64 + lane] = f2bf(a1 * 0.125f + b);
    x0nb[(size_t)(nb + 2) * 64 + lane] = f2bf(a2 * 0.125f + b);
    x0nb[(size_t)(nb + 3) * 64 + lane] = f2bf(a3 * 0.125f + b);
  }

  {
    const int o = lane; const int v = o / 3, i_ = o - 3 * v;
    float a0 = 0.f, a1 = 0.f, a2 = 0.f, a3 = 0.f;
    for (int u = 0; u < 32; ++u) {
      const float w = W1n[u * 32 + v];
      a0 = fmaf(sX[0][64 + u * 3 + i_] * sG[0][64 + u], w, a0);
      a1 = fmaf(sX[1][64 + u * 3 + i_] * sG[1][64 + u], w, a1);
      a2 = fmaf(sX[2][64 + u * 3 + i_] * sG[2][64 + u], w, a2);
      a3 = fmaf(sX[3][64 + u * 3 + i_] * sG[3][64 + u], w, a3);
    }
    x1nb[(size_t)(nb + 0) * 96 + o] = f2bf(a0 * INVS32);
    x1nb[(size_t)(nb + 1) * 96 + o] = f2bf(a1 * INVS32);
    x1nb[(size_t)(nb + 2) * 96 + o] = f2bf(a2 * INVS32);
    x1nb[(size_t)(nb + 3) * 96 + o] = f2bf(a3 * INVS32);
  }
  if (lane < 32) {
    const int o = 64 + lane; const int v = o / 3, i_ = o - 3 * v;
    float a0 = 0.f, a1 = 0.f, a2 = 0.f, a3 = 0.f;
    for (int u = 0; u < 32; ++u) {
      const float w = W1n[u * 32 + v];
      a0 = fmaf(sX[0][64 + u * 3 + i_] * sG[0][64 + u], w, a0);
      a1 = fmaf(sX[1][64 + u * 3 + i_] * sG[1][64 + u], w, a1);
      a2 = fmaf(sX[2][64 + u * 3 + i_] * sG[2][64 + u], w, a2);
      a3 = fmaf(sX[3][64 + u * 3 + i_] * sG[3][64 + u], w, a3);
    }
    x1nb[(size_t)(nb + 0) * 96 + o] = f2bf(a0 * INVS32);
    x1nb[(size_t)(nb + 1) * 96 + o] = f2bf(a1 * INVS32);
    x1nb[(size_t)(nb + 2) * 96 + o] = f2bf(a2 * INVS32);
    x1nb[(size_t)(nb + 3) * 96 + o] = f2bf(a3 * INVS32);
  }

  if (lane < 32) {
    float a0 = 0.f, a1 = 0.f, a2 = 0.f, a3 = 0.f;
    float c0 = 0.f, c1 = 0.f, c2 = 0.f, c3 = 0.f;
    for (int i = 0; i < 64; ++i) {
      const float wa = L1[i * 32 + lane];
      const float wb = L1[(64 + i) * 32 + lane];
      a0 = fmaf(sP0[0][i], wa, a0); a1 = fmaf(sP0[1][i], wa, a1);
      a2 = fmaf(sP0[2][i], wa, a2); a3 = fmaf(sP0[3][i], wa, a3);
      c0 = fmaf(sP0[0][i], wb, c0); c1 = fmaf(sP0[1][i], wb, c1);
      c2 = fmaf(sP0[2][i], wb, c2); c3 = fmaf(sP0[3][i], wb, c3);
    }
    Aw[(size_t)(nb + 0) * 32 + lane] = a0 * INVS160;
    Aw[(size_t)(nb + 1) * 32 + lane] = a1 * INVS160;
    Aw[(size_t)(nb + 2) * 32 + lane] = a2 * INVS160;
    Aw[(size_t)(nb + 3) * 32 + lane] = a3 * INVS160;
    Bw[(size_t)(nb + 0) * 32 + lane] = c0 * INVS160;
    Bw[(size_t)(nb + 1) * 32 + lane] = c1 * INVS160;
    Bw[(size_t)(nb + 2) * 32 + lane] = c2 * INVS160;
    Bw[(size_t)(nb + 3) * 32 + lane] = c3 * INVS160;
  }
}

// ---------------- fused per-edge: all-MFMA MLP + vectorized scatter ----------------
__global__ __launch_bounds__(256, 4) void fused_edge_k(
    const float* __restrict__ edge_attr,
    const float* __restrict__ edge_sh,
    const int* __restrict__ ei,
    const ushort* __restrict__ F1Tb, const ushort* __restrict__ L1cTb,
    const ushort* __restrict__ F2Tb, const ushort* __restrict__ L2Tb,
    const ushort* __restrict__ p1b, const float* __restrict__ Aw,
    const float* __restrict__ Bw,
    const ushort* __restrict__ x0nb, const ushort* __restrict__ x1nb,
    const int* __restrict__ order,
    float* __restrict__ o480p)
{
  const int s0  = blockIdx.x * TILE;
  const int tid = threadIdx.x;

  // uMem: sWT (bf16 [224][40], phase C/D) unions with sEAb/sIPb/sAB (phase A/B)
  __shared__ __align__(16) char uMem[224 * 40 * 2];          // 17920 B
  ushort* sWT  = (ushort*)uMem;                  // [c][q] stride 40
  ushort* sEAb = (ushort*)uMem;                  // 32x40 bf16
  ushort* sIPb = (ushort*)(uMem + 2560);         // 32x40 bf16
  float*  sAB  = (float*)(uMem + 5120);          // 32x36 f32

  __shared__ ushort sHF[32][40];
  __shared__ ushort sHL[32][40];
  __shared__ ushort sXS0[32][64];
  __shared__ ushort sXS1p[32 * 136];             // padded triplets [q][u*4+i]
  __shared__ __align__(16) float sSH[32][4];
  __shared__ int    sDst[32];

  const int g = tid >> 3, l = tid & 7;
  const int e   = order[s0 + g];
  const int dst = ei[e];
  const int src = ei[EE + e];
  if (l == 0) sDst[g] = dst;

  // ---- phase A ----
  {
    float4 ea = *(const float4*)(edge_attr + (size_t)e * 32 + l * 4);
    *(unsigned*)&sEAb[g * 40 + l * 4 + 0] = pk(ea.x, ea.y);
    *(unsigned*)&sEAb[g * 40 + l * 4 + 2] = pk(ea.z, ea.w);
  }
  if (l == 1) *(float4*)&sSH[g][0] = *(const float4*)(edge_sh + (size_t)e * 4);
  {
    uint4 v = *(const uint4*)(x0nb + (size_t)src * 64 + l * 8);
    *(uint4*)&sXS0[g][l * 8] = v;
    // x1: load 12 bf16, repack into 4 padded triplets
    const uint2* b2 = (const uint2*)(x1nb + (size_t)src * 96 + l * 12);
    uint2 b0 = b2[0], b1 = b2[1], b2v = b2[2];
    uint2 t0; t0.x = b0.x;                               t0.y = b0.y;
    uint2 t1; t1.x = (b0.y >> 16) | (b1.x << 16);        t1.y = b1.x >> 16;
    uint2 t2; t2.x = b1.y;                               t2.y = b2v.x;
    uint2 t3; t3.x = (b2v.x >> 16) | (b2v.y << 16);      t3.y = b2v.y >> 16;
    ushort* base = &sXS1p[g * 136 + l * 16];
    *(uint2*)&base[0]  = t0;
    *(uint2*)&base[4]  = t1;
    *(uint2*)&base[8]  = t2;
    *(uint2*)&base[12] = t3;
  }
  {
    // ip from bf16 p1 gathers (halved bytes)
    const uint2* pd2 = (const uint2*)(p1b + (size_t)dst * 96 + l * 12);
    const uint2* ps2 = (const uint2*)(p1b + (size_t)src * 96 + l * 12);
    uint2 d0 = pd2[0], d1 = pd2[1], d2 = pd2[2];
    uint2 s0v = ps2[0], s1v = ps2[1], s2v = ps2[2];
    const float dp0 = bflo(d0.x),  dp1 = bfhi(d0.x),  dp2 = bflo(d0.y),  dp3 = bfhi(d0.y);
    const float dp4 = bflo(d1.x),  dp5 = bfhi(d1.x),  dp6 = bflo(d1.y),  dp7 = bfhi(d1.y);
    const float dp8 = bflo(d2.x),  dp9 = bfhi(d2.x),  dp10 = bflo(d2.y), dp11 = bfhi(d2.y);
    const float sp0 = bflo(s0v.x), sp1 = bfhi(s0v.x), sp2 = bflo(s0v.y), sp3 = bfhi(s0v.y);
    const float sp4 = bflo(s1v.x), sp5 = bfhi(s1v.x), sp6 = bflo(s1v.y), sp7 = bfhi(s1v.y);
    const float sp8 = bflo(s2v.x), sp9 = bfhi(s2v.x), sp10 = bflo(s2v.y), sp11 = bfhi(s2v.y);
    const float ip0 = (dp0*sp0 + dp1*sp1 + dp2*sp2) * INVS3;
    const float ip1 = (dp3*sp3 + dp4*sp4 + dp5*sp5) * INVS3;
    const float ip2 = (dp6*sp6 + dp7*sp7 + dp8*sp8) * INVS3;
    const float ip3 = (dp9*sp9 + dp10*sp10 + dp11*sp11) * INVS3;
    *(unsigned*)&sIPb[g * 40 + l * 4 + 0] = pk(ip0, ip1);
    *(unsigned*)&sIPb[g * 40 + l * 4 + 2] = pk(ip2, ip3);
  }
  {
    float4 av = *(const float4*)(Aw + (size_t)dst * 32 + l * 4);
    float4 bv = *(const float4*)(Bw + (size_t)src * 32 + l * 4);
    f32x4 ab;
    ab[0] = av.x + bv.x; ab[1] = av.y + bv.y;
    ab[2] = av.z + bv.z; ab[3] = av.w + bv.w;
    *(f32x4*)&sAB[g * 36 + l * 4] = ab;
  }
  __syncthreads();

  // ---- phase B (MFMA): hf = ea@F1T, hl = ip@L1cT + AB ----
  {
    const int wvi  = tid >> 6;
    const int lane = tid & 63;
    const int r = lane & 15;
    const int h = lane >> 4;
    const int qt = wvi & 1;
    const bool isHL = (wvi >= 2);
    const ushort* aBase = isHL ? sIPb : sEAb;
    const ushort* bW    = isHL ? L1cTb : F1Tb;
    ushort* outB = isHL ? &sHL[0][0] : &sHF[0][0];
    bf16x8 afr = *(const bf16x8*)&aBase[(qt * 16 + r) * 40 + h * 8];
#pragma unroll
    for (int ct = 0; ct < 2; ++ct) {
      const int c = ct * 16 + r;
      bf16x8 bfr = *(const bf16x8*)&bW[c * 32 + h * 8];
      f32x4 z = {0.f, 0.f, 0.f, 0.f};
      f32x4 o = __builtin_amdgcn_mfma_f32_16x16x32_bf16(afr, bfr, z, 0, 0, 0);
#pragma unroll
      for (int i = 0; i < 4; ++i) {
        const int q = qt * 16 + h * 4 + i;
        float v = o[i];
        if (isHL) v += sAB[q * 36 + c];
        outB[q * 40 + c] = f2bf(sspf(v));
      }
    }
  }
  __syncthreads();

  // ---- phase C: MFMA w-GEMMs -> TRANSPOSED sWT[c][q] (uint2 row writes) ----
  {
    const int wv   = tid >> 6;
    const int lane = tid & 63;
    const int r = lane & 15;
    const int h = lane >> 4;
    bf16x8 aF0 = *(const bf16x8*)&sHF[r][h * 8];
    bf16x8 aF1 = *(const bf16x8*)&sHF[16 + r][h * 8];
    bf16x8 aL0 = *(const bf16x8*)&sHL[r][h * 8];
    bf16x8 aL1 = *(const bf16x8*)&sHL[16 + r][h * 8];
    const int ct0 = (wv < 2) ? wv * 4 : 8 + (wv - 2) * 3;
    const int nct = (wv < 2) ? 4 : 3;
    for (int t = 0; t < nct; ++t) {
      const int ct = ct0 + t;
      const int c  = ct * 16 + r;
      bf16x8 bF = *(const bf16x8*)&F2Tb[c * 32 + h * 8];
      bf16x8 bL = *(const bf16x8*)&L2Tb[c * 32 + h * 8];
      f32x4 z = {0.f, 0.f, 0.f, 0.f};
      f32x4 wf0 = __builtin_amdgcn_mfma_f32_16x16x32_bf16(aF0, bF, z, 0, 0, 0);
      f32x4 wl0 = __builtin_amdgcn_mfma_f32_16x16x32_bf16(aL0, bL, z, 0, 0, 0);
      f32x4 wf1 = __builtin_amdgcn_mfma_f32_16x16x32_bf16(aF1, bF, z, 0, 0, 0);
      f32x4 wl1 = __builtin_amdgcn_mfma_f32_16x16x32_bf16(aL1, bL, z, 0, 0, 0);
      uint2 lo; lo.x = pk(wf0[0]*wl0[0], wf0[1]*wl0[1]);
                lo.y = pk(wf0[2]*wl0[2], wf0[3]*wl0[3]);
      uint2 hi; hi.x = pk(wf1[0]*wl1[0], wf1[1]*wl1[1]);
                hi.y = pk(wf1[2]*wl1[2], wf1[3]*wl1[3]);
      *(uint2*)&sWT[c * 40 + h * 4]      = lo;   // q = h*4..h*4+3
      *(uint2*)&sWT[c * 40 + 16 + h * 4] = hi;   // q = 16+h*4..
    }
  }
  __syncthreads();

  // ---- phase D: 128 threads, vectorized w-reads (b128 per 8 edges) ----
  if (tid < 128) {
    const int tl = tid;
    float a0 = 0.f, a1 = 0.f, a2 = 0.f, a3 = 0.f;

    if (tl < 64) {
      for (int p4 = 0; p4 < 4; ++p4) {
        const int q0 = p4 * 8;
        bf16x8 w0v = *(const bf16x8*)&sWT[tl * 40 + q0];
        bf16x8 w1v = *(const bf16x8*)&sWT[(64 + tl) * 40 + q0];
#pragma unroll
        for (int j = 0; j < 8; ++j) {
          const int q = q0 + j;
          const float4 sh = *(const float4*)&sSH[q][0];
          const float x0 = bf2f(sXS0[q][tl]);
          const float w0 = bf2f((ushort)w0v[j]);
          const float w1 = bf2f((ushort)w1v[j]);
          a0 = fmaf(w0 * x0, sh.x, a0);
          const float t = w1 * x0;
          a1 = fmaf(t, sh.y, a1);
          a2 = fmaf(t, sh.z, a2);
          a3 = fmaf(t, sh.w, a3);
          const int d = sDst[q];
          if ((q == TILE - 1) || (sDst[q + 1] != d)) {
            float* dp = o480p + (size_t)d * 480;
            atomicAdd(dp + tl, a0);
            atomicAdd(dp + 128 + tl, a1);
            atomicAdd(dp + 256 + tl, a2);
            atomicAdd(dp + 384 + tl, a3);
            a0 = 0.f; a1 = 0.f; a2 = 0.f; a3 = 0.f;
          }
        }
      }
    } else if (tl < 96) {
      const int c = tl - 64;
      for (int p4 = 0; p4 < 4; ++p4) {
        const int q0 = p4 * 8;
        bf16x8 wbv = *(const bf16x8*)&sWT[(160 + c) * 40 + q0];
        bf16x8 wdv = *(const bf16x8*)&sWT[(128 + c) * 40 + q0];
#pragma unroll
        for (int j = 0; j < 8; ++j) {
          const int q = q0 + j;
          const float4 sh = *(const float4*)&sSH[q][0];
          uint2 t3 = *(const uint2*)&sXS1p[q * 136 + c * 4];
          const float x0v = bflo(t3.x);
          const float x1v = bfhi(t3.x);
          const float x2v = bflo(t3.y);
          const float wb = bf2f((ushort)wbv[j]);
          const float wd = bf2f((ushort)wdv[j]);
          const float d2 = fmaf(x2v, sh.w, fmaf(x1v, sh.z, x0v * sh.y));
          a0 = fmaf(wb, d2, a0);
          const float t = wd * sh.x;
          a1 = fmaf(t, x0v, a1);
          a2 = fmaf(t, x1v, a2);
          a3 = fmaf(t, x2v, a3);
          const int d = sDst[q];
          if ((q == TILE - 1) || (sDst[q + 1] != d)) {
            float* dp = o480p + (size_t)d * 480;
            atomicAdd(dp + tl, a0);
            atomicAdd(dp + 128 + tl, a1);
            atomicAdd(dp + 256 + tl, a2);
            atomicAdd(dp + 384 + tl, a3);
            a0 = 0.f; a1 = 0.f; a2 = 0.f; a3 = 0.f;
          }
        }
      }
    } else {
      const int u = tl - 96;
      for (int p4 = 0; p4 < 4; ++p4) {
        const int q0 = p4 * 8;
        bf16x8 wcv = *(const bf16x8*)&sWT[(192 + u) * 40 + q0];
#pragma unroll
        for (int j = 0; j < 8; ++j) {
          const int q = q0 + j;
          const float4 sh = *(const float4*)&sSH[q][0];
          uint2 t3 = *(const uint2*)&sXS1p[q * 136 + u * 4];
          const float x0v = bflo(t3.x);
          const float x1v = bfhi(t3.x);
          const float x2v = bflo(t3.y);
          const float wc = bf2f((ushort)wcv[j]);
          a0 = fmaf(wc, fmaf(x1v, sh.w, -(x2v * sh.z)), a0);
          a1 = fmaf(wc, fmaf(x2v, sh.y, -(x0v * sh.w)), a1);
          a2 = fmaf(wc, fmaf(x0v, sh.z, -(x1v * sh.y)), a2);
          const int d = sDst[q];
          if ((q == TILE - 1) || (sDst[q + 1] != d)) {
            float* dp = o480p + (size_t)d * 480;
            atomicAdd(dp + tl, a0);
            atomicAdd(dp + 128 + tl, a1);
            atomicAdd(dp + 256 + tl, a2);
            a0 = 0.f; a1 = 0.f; a2 = 0.f;
          }
        }
      }
    }
  }
}

// ---------------- output linears: 1 wave, 4 nodes, acc-major o480p reads ----------------
__global__ __launch_bounds__(64) void out_wo_k(
    const float* __restrict__ o480p,
    const float* __restrict__ WO0T, const float* __restrict__ WO1T,
    const float* __restrict__ WO2T, const float* __restrict__ bO0,
    float* __restrict__ out)
{
  const int lane = threadIdx.x;
  const int nb = blockIdx.x * 4;
  __shared__ float sO[4][480];
#pragma unroll
  for (int j = 0; j < 4; ++j) {
    const float4* src = (const float4*)(o480p + (size_t)(nb + j) * 480);
    for (int idx = lane; idx < 120; idx += 64)
      *(float4*)&sO[j][idx * 4] = src[idx];
  }

  for (int k = lane; k < 416; k += 64) {
    float y0, y1, y2, y3;
    if (k < 128) {
      const float* wr = WO0T + k * 96;
      float a0 = 0.f, a1 = 0.f, a2 = 0.f, a3 = 0.f;
      for (int u = 0; u < 96; ++u) {
        const float w = wr[u];
        a0 = fmaf(w, sO[0][u], a0); a1 = fmaf(w, sO[1][u], a1);
        a2 = fmaf(w, sO[2][u], a2); a3 = fmaf(w, sO[3][u], a3);
      }
      const float b = bO0[k];
      y0 = a0 + b; y1 = a1 + b; y2 = a2 + b; y3 = a3 + b;
    } else if (k < 320) {
      const int kk = k - 128; const int v = kk / 3; const int i = kk - 3 * v;
      const float* wr = WO1T + v * 96;
      const int base = 128 + 128 * i;
      float a0 = 0.f, a1 = 0.f, a2 = 0.f, a3 = 0.f;
      for (int u = 0; u < 96; ++u) {
        const float w = wr[u];
        a0 = fmaf(w, sO[0][base + u], a0);
        a1 = fmaf(w, sO[1][base + u], a1);
        a2 = fmaf(w, sO[2][base + u], a2);
        a3 = fmaf(w, sO[3][base + u], a3);
      }
      y0 = a0; y1 = a1; y2 = a2; y3 = a3;
    } else {
      const int kk = k - 320; const int v = kk / 3; const int i = kk - 3 * v;
      const float* wr = WO2T + v * 32;
      const int base = 96 + 128 * i;
      float a0 = 0.f, a1 = 0.f, a2 = 0.f, a3 = 0.f;
      for (int u = 0; u < 32; ++u) {
        const float w = wr[u];
        a0 = fmaf(w, sO[0][base + u], a0);
        a1 = fmaf(w, sO[1][base + u], a1);
        a2 = fmaf(w, sO[2][base + u], a2);
        a3 = fmaf(w, sO[3][base + u], a3);
      }
      y0 = a0; y1 = a1; y2 = a2; y3 = a3;
    }
    out[(size_t)(nb + 0) * 416 + k] = y0;
    out[(size_t)(nb + 1) * 416 + k] = y1;
    out[(size_t)(nb + 2) * 416 + k] = y2;
    out[(size_t)(nb + 3) * 416 + k] = y3;
  }
}

// ---------------- host ----------------
extern "C" void kernel_launch(void* const* d_in, const int* in_sizes, int n_in,
                              void* d_out, int out_size, void* d_ws, size_t ws_size,
                              hipStream_t stream) {
  const float* x         = (const float*)d_in[0];
  const float* edge_sh   = (const float*)d_in[1];
  const float* edge_attr = (const float*)d_in[2];
  const float* W0p       = (const float*)d_in[3];
  const float* b0p       = (const float*)d_in[4];
  const float* W1p       = (const float*)d_in[5];
  const float* W0n       = (const float*)d_in[6];
  const float* b0n       = (const float*)d_in[7];
  const float* W1n       = (const float*)d_in[8];
  const float* G1        = (const float*)d_in[9];
  const float* g1b       = (const float*)d_in[10];
  const float* G2        = (const float*)d_in[11];
  const float* g2b       = (const float*)d_in[12];
  const float* F1        = (const float*)d_in[13];
  const float* F2        = (const float*)d_in[14];
  const float* L1        = (const float*)d_in[15];
  const float* L2        = (const float*)d_in[16];
  const float* WO0       = (const float*)d_in[17];
  const float* bO0       = (const float*)d_in[18];
  const float* WO1       = (const float*)d_in[19];
  const float* WO2       = (const float*)d_in[20];
  const int*   ei        = (const int*)d_in[21];
  float* out = (float*)d_out;

  ushort* p1b  = (ushort*)d_ws;              // N*96 bf16
  ushort* x0nb = p1b + NN * 96;              // N*64 bf16
  ushort* x1nb = x0nb + NN * 64;             // N*96 bf16
  float*  Aw   = (float*)(x1nb + NN * 96);   // N*32 f32 (256 u16/node -> 4B aligned)
  float*  Bw   = Aw + NN * 32;               // N*32
  float*  o480 = Bw + NN * 32;               // N*480 (acc-major permuted)
  int* cnt    = (int*)(o480 + (size_t)NN * 480);
  int* cursor = cnt    + NN;
  int* order  = cursor + NN;           // E
  uintptr_t p = (uintptr_t)(order + EE);
  p = (p + 15) & ~(uintptr_t)15;
  ushort* F2Tb  = (ushort*)p;          // 224*32 bf16
  ushort* L2Tb  = F2Tb + 224 * 32;
  ushort* F1Tb  = L2Tb + 224 * 32;     // 32*32 bf16
  ushort* L1cTb = F1Tb + 32 * 32;      // 32*32 bf16
  uintptr_t p2 = (uintptr_t)(L1cTb + 32 * 32);
  p2 = (p2 + 15) & ~(uintptr_t)15;
  float* WO0T = (float*)p2;            // 128*96
  float* WO1T = WO0T + 128 * 96;       // 64*96
  float* WO2T = WO1T + 64 * 96;        // 32*32

  hipMemsetAsync(cnt, 0, NN * sizeof(int), stream);
  hipMemsetAsync(o480, 0, (size_t)NN * 480 * sizeof(float), stream);
  prep_t_k<<<(EE + 255) / 256, 256, 0, stream>>>(F2, L2, WO0, WO1, WO2, F1, L1,
                                                 ei, cnt,
                                                 F2Tb, L2Tb, WO0T, WO1T, WO2T,
                                                 F1Tb, L1cTb);
  scan_k<<<1, 1024, 0, stream>>>(cnt, cursor);
  node_prep_k<<<NN / 4, 64, 0, stream>>>(x, W0p, b0p, W1p, W0n, b0n, W1n,
                                         G1, g1b, G2, g2b, L1,
                                         ei, cursor, order,
                                         p1b, x0nb, x1nb, Aw, Bw);
  fused_edge_k<<<EE / TILE, 256, 0, stream>>>(edge_attr, edge_sh, ei,
                                              F1Tb, L1cTb, F2Tb, L2Tb,
                                              p1b, Aw, Bw, x0nb, x1nb,
                                              order, o480);
  out_wo_k<<<NN / 4, 64, 0, stream>>>(o480, WO0T, WO1T, WO2T, bO0, out);
}